// Round 2
// baseline (1299.046 us; speedup 1.0000x reference)
//
#include <hip/hip_runtime.h>
#include <hip/hip_bf16.h>
#include <math.h>

// Problem constants (fixed by the reference: H=2048, V=32000, B=8, T=256, G=4).
#define H_DIM 2048
#define V_DIM 32000
#define BT    2048            // B*T rows
#define BETA  0.1f
#define EPSR  1e-4f

// ---- fast-path GEMM geometry: 256x256 tile, BK=64, 8 waves (2M x 4N) ----
#define NT    32              // K tiles of 64 (H/64)
#define NBLK2 125             // V / 256
#define NTILE 256             // persistent: 8 outputs x 32 K-tiles per block
// ---- fallback geometry (round-1 kernel, unchanged) ----
#define TM 128
#define TN 128
#define TK 32
#define NBLK_FB 250

typedef __attribute__((ext_vector_type(8))) short bf16x8;   // 8 bf16 = 4 VGPRs
typedef __attribute__((ext_vector_type(4))) float f32x4;

// ---------------- helpers ----------------

// Pack two fp32 -> bf16x2 (round-half-up via +0x8000, take high 16 bits each).
__device__ __forceinline__ unsigned pack_bf16x2(float a, float b) {
    unsigned ua = __float_as_uint(a) + 0x8000u;
    unsigned ub = __float_as_uint(b) + 0x8000u;
    return __builtin_amdgcn_perm(ub, ua, 0x07060302u);
}

__device__ __forceinline__ void merge_ms(float& m, float& s, float m2, float s2) {
    float nm = fmaxf(m, m2);
    s = s * __expf(m - nm) + s2 * __expf(m2 - nm);
    m = nm;
}

// Async global->LDS, 16 B per lane. LDS dest = wave-uniform base + lane*16.
__device__ __forceinline__ void gl_lds16(const void* g, void* l) {
    __builtin_amdgcn_global_load_lds(
        (const __attribute__((address_space(1))) void*)g,
        (__attribute__((address_space(3))) void*)l, 16, 0, 0);
}

// ---------------- pack: fp32 [R,2048] -> bf16 slabs per (256-row, 64-K) tile ----------------
// Slab (rt,kt) is 32 KB: chunk (kk*256+row) holds src[rt*256+row][kt*64+kk*8..+8] as 8 bf16.
// This is both the GEMM LDS layout (global_load_lds = linear copy) and the MFMA fragment
// order, so GEMM ds_read_b128s are bank-uniform. One fused kernel packs all 4 arrays:
// blockIdx.x spans {x:16, w:250, rx:16, rw:250} row-tiles of 128; blockIdx.y = kt (0..31).
__global__ __launch_bounds__(256) void pack_all_kernel(
    const float* __restrict__ x,  const float* __restrict__ w,
    const float* __restrict__ rx, const float* __restrict__ rw,
    uint4* __restrict__ Ap, uint4* __restrict__ Wp,
    uint4* __restrict__ Rp, uint4* __restrict__ RWp)
{
    __shared__ float tile[128 * 68];       // stride 68 floats: float4-aligned, spread banks
    const int t  = threadIdx.x;
    const int bx = blockIdx.x, kt = blockIdx.y;

    const float* src; uint4* dst; int rb;
    if (bx < 16)       { src = x;  dst = Ap;  rb = bx; }
    else if (bx < 266) { src = w;  dst = Wp;  rb = bx - 16; }
    else if (bx < 282) { src = rx; dst = Rp;  rb = bx - 266; }
    else               { src = rw; dst = RWp; rb = bx - 282; }

    const int rh = rb & 1, rt = rb >> 1;
    const int r0 = rb * 128;

    // Coalesced read: 128 rows x 64 floats (256 B contiguous per row).
    #pragma unroll
    for (int it = 0; it < 8; it++) {
        int idx = it * 256 + t;                        // 0..2047
        int row = idx >> 4, seg = idx & 15;
        float4 v = *(const float4*)(src + (size_t)(r0 + row) * H_DIM + kt * 64 + seg * 4);
        *(float4*)(tile + row * 68 + seg * 4) = v;
    }
    __syncthreads();

    // Coalesced write: 1024 x 16B chunks into slab (rt, kt), rows rh*128..+128.
    uint4* d = dst + (((size_t)rt * NT + kt) << 11);   // 2048 uint4 per slab
    #pragma unroll
    for (int it = 0; it < 4; it++) {
        int c = it * 256 + t;                          // 0..1023
        int kk = c >> 7, row = c & 127;
        const float* p = tile + row * 68 + kk * 8;
        d[(size_t)kk * 256 + rh * 128 + row] = make_uint4(
            pack_bf16x2(p[0], p[1]), pack_bf16x2(p[2], p[3]),
            pack_bf16x2(p[4], p[5]), pack_bf16x2(p[6], p[7]));
    }
}

// ---------------- persistent 256^2 8-phase GEMM + online-softmax epilogue ----------------
// 250 blocks (1/CU). Block b owns (z = b/125, nb = b%125) and sweeps all 8 mb outputs as a
// single continuous 256-tile pipeline: the vmcnt ledger NEVER drains across outputs.
// A streams linearly through the packed array (slab index = g = mb*32+kt); B cycles its one
// slab (kt = g&31), L2/LLC-hot after the first pass.
//
// Per-phase B-frag reads are moved POST-MFMA at p4/p8 (legal: p4's vmcnt(6) completes all
// loads through p1, which includes that tile's B staged >=3 phases earlier; barrier A then
// makes them globally visible). Every phase's pre-MFMA ds-drain is a uniform 4 reads.
//
// Per-output epilogue uses a dedicated 12KB LDS scratch (beyond the 128KB tile buffers) with
// raw s_barrier + lgkmcnt(0) ONLY -- no vmcnt drain, staging stays in flight underneath.

#define MF(a,b,c) __builtin_amdgcn_mfma_f32_16x16x32_bf16(a, b, c, 0, 0, 0)

#define LDA(dst, BUF, F, KS) \
    dst = *(const bf16x8*)(smem + (BUF)*65536 + (KS)*16384 + (F)*256 + aoff)
#define LDB(dst, BUF, CF, KS) \
    dst = *(const bf16x8*)(smem + (BUF)*65536 + (KS)*16384 + (CF)*256 + boff)

#define STAGE(SG, SHT, SBUF) do { \
    const char* s_ = ((SHT) < 2 ? Bbase + ((size_t)((SG) & 31) << 15) \
                                : Abase + ((size_t)(SG) << 15)); \
    char* l_ = smem + (SBUF)*65536 + ((SHT) < 2 ? 32768 : 0); \
    gl_lds16(s_ + soff[SHT][0], l_ + soff[SHT][0]); \
    gl_lds16(s_ + soff[SHT][1], l_ + soff[SHT][1]); \
} while (0)

#define MFMA_PH(F0, A0, A1, A2, A3) do { \
    acc[F0][0]   = MF(A0, bfr[0][0], acc[F0][0]); \
    acc[F0][1]   = MF(A0, bfr[1][0], acc[F0][1]); \
    acc[F0][2]   = MF(A0, bfr[2][0], acc[F0][2]); \
    acc[F0][3]   = MF(A0, bfr[3][0], acc[F0][3]); \
    acc[F0+1][0] = MF(A2, bfr[0][0], acc[F0+1][0]); \
    acc[F0+1][1] = MF(A2, bfr[1][0], acc[F0+1][1]); \
    acc[F0+1][2] = MF(A2, bfr[2][0], acc[F0+1][2]); \
    acc[F0+1][3] = MF(A2, bfr[3][0], acc[F0+1][3]); \
    acc[F0][0]   = MF(A1, bfr[0][1], acc[F0][0]); \
    acc[F0][1]   = MF(A1, bfr[1][1], acc[F0][1]); \
    acc[F0][2]   = MF(A1, bfr[2][1], acc[F0][2]); \
    acc[F0][3]   = MF(A1, bfr[3][1], acc[F0][3]); \
    acc[F0+1][0] = MF(A3, bfr[0][1], acc[F0+1][0]); \
    acc[F0+1][1] = MF(A3, bfr[1][1], acc[F0+1][1]); \
    acc[F0+1][2] = MF(A3, bfr[2][1], acc[F0+1][2]); \
    acc[F0+1][3] = MF(A3, bfr[3][1], acc[F0+1][3]); \
} while (0)

// One phase. POSTB: after the MFMA cluster, reload the 8 B-frags from buffer PBUF for the
// NEXT 4 phases (data sealed by this phase's vmcnt(6) + barrier A).
#define PHASE(BUF, F0, SG, SHT, SBUF, VM, POSTB, PBUF) do { \
    bf16x8 a0_, a1_, a2_, a3_; \
    LDA(a0_, BUF, F0, 0);   LDA(a1_, BUF, F0, 1); \
    LDA(a2_, BUF, F0+1, 0); LDA(a3_, BUF, F0+1, 1); \
    STAGE(SG, SHT, SBUF); \
    if (VM) asm volatile("s_waitcnt vmcnt(6)" ::: "memory"); \
    asm volatile("" ::: "memory"); \
    __builtin_amdgcn_s_barrier(); \
    asm volatile("s_waitcnt lgkmcnt(0)" ::: "memory"); \
    __builtin_amdgcn_s_setprio(1); \
    MFMA_PH(F0, a0_, a1_, a2_, a3_); \
    __builtin_amdgcn_s_setprio(0); \
    if (POSTB) { \
        LDB(bfr[0][0], PBUF, 0, 0); LDB(bfr[0][1], PBUF, 0, 1); \
        LDB(bfr[1][0], PBUF, 1, 0); LDB(bfr[1][1], PBUF, 1, 1); \
        LDB(bfr[2][0], PBUF, 2, 0); LDB(bfr[2][1], PBUF, 2, 1); \
        LDB(bfr[3][0], PBUF, 3, 0); LDB(bfr[3][1], PBUF, 3, 1); \
    } \
    asm volatile("" ::: "memory"); \
    __builtin_amdgcn_s_barrier(); \
    asm volatile("" ::: "memory"); \
} while (0)

__global__ __launch_bounds__(512, 2) void gemm_lse_persist(
    const ushort* __restrict__ Ap, const ushort* __restrict__ Wp,
    const ushort* __restrict__ Rp, const ushort* __restrict__ RWp,
    float4* __restrict__ part, float4* __restrict__ part2)
{
    __shared__ __align__(16) char smem_raw[131072 + 12288];  // tiles | epilogue scratch
    char* smem = smem_raw;
    float* redM = (float*)(smem_raw + 131072);               // 256 rows x 4 wn-segments
    float* redS = (float*)(smem_raw + 131072 + 4096);
    int*   redC = (int*)  (smem_raw + 131072 + 8192);

    const int tid  = threadIdx.x;
    const int lane = tid & 63;
    const int wv   = tid >> 6;                          // 0..7
    const int wm   = wv >> 2, wn = wv & 3;              // 2 x 4 wave grid: 128x64 per wave
    const int q    = lane >> 4, cl = lane & 15;

    const int bid = blockIdx.x;
    const int z   = bid / 125, nb = bid % 125;
    const char* Abase = (const char*)(z ? Rp  : Ap);    // streams g = 0..255 linearly
    const char* Bbase = (const char*)(z ? RWp : Wp) + ((size_t)(nb * NT) << 15);
    float4* pp = z ? part2 : part;

    // Fragment-read base offsets (within a 64 KB tile-buffer).
    const int aoff = q * 4096 + (wm * 128 + cl) * 16;
    const int boff = 32768 + q * 4096 + (wn * 64 + cl) * 16;

    // Staging offsets: chunk c = wv*2 + l covers (kk, row-group), 64 rows/lane.
    int soff[4][2];
    #pragma unroll
    for (int l = 0; l < 2; l++) {
        int c = wv * 2 + l;
        int kko = (((c >> 3) << 2) + ((c >> 1) & 3)) * 4096;
        int rg = c & 1;
        soff[0][l] = kko + (rg * 64 + lane) * 16;            // B rows 0..128
        soff[1][l] = kko + (128 + rg * 64 + lane) * 16;      // B rows 128..256
        soff[2][l] = kko + (rg * 128 + lane) * 16;           // A rows {0-64, 128-192}
        soff[3][l] = kko + (rg * 128 + 64 + lane) * 16;      // A rows {64-128, 192-256}
    }

    f32x4 acc[8][4];
    const f32x4 zero = {0.f, 0.f, 0.f, 0.f};
    #pragma unroll
    for (int i = 0; i < 8; i++)
        #pragma unroll
        for (int j = 0; j < 4; j++) acc[i][j] = zero;

    bf16x8 bfr[4][2];

    // Prologue: tile0 (4 HTs) -> buf0, tile1 (ht0..2) -> buf1; 14 loads, keep 6 in flight.
    STAGE(0, 0, 0); STAGE(0, 1, 0); STAGE(0, 2, 0); STAGE(0, 3, 0);
    STAGE(1, 0, 1); STAGE(1, 1, 1); STAGE(1, 2, 1);
    asm volatile("s_waitcnt vmcnt(6)" ::: "memory");
    __builtin_amdgcn_s_barrier();
    asm volatile("" ::: "memory");
    // Initial B frags (tile 0, buf0); drained by p1's lgkmcnt(0).
    LDB(bfr[0][0], 0, 0, 0); LDB(bfr[0][1], 0, 0, 1);
    LDB(bfr[1][0], 0, 1, 0); LDB(bfr[1][1], 0, 1, 1);
    LDB(bfr[2][0], 0, 2, 0); LDB(bfr[2][1], 0, 2, 1);
    LDB(bfr[3][0], 0, 3, 0); LDB(bfr[3][1], 0, 3, 1);

    #pragma unroll 1
    for (int mb = 0; mb < 8; mb++) {
        const int base = mb * 32;
        #pragma unroll 1
        for (int ii = 0; ii < 16; ii++) {
            int t1 = base + 2 * ii + 1;
            int t2 = base + 2 * ii + 2; if (t2 > NTILE - 1) t2 = NTILE - 1;  // tail: dummy
            int t3 = base + 2 * ii + 3; if (t3 > NTILE - 1) t3 = NTILE - 1;  // (valid) stages
            PHASE(0, 0, t1, 3, 1, 0, 0, 0);
            PHASE(0, 2, t2, 0, 0, 0, 0, 0);
            PHASE(0, 4, t2, 1, 0, 0, 0, 0);
            PHASE(0, 6, t2, 2, 0, 1, 1, 1);   // vmcnt(6); postload B(t1) from buf1
            PHASE(1, 0, t2, 3, 0, 0, 0, 0);
            PHASE(1, 2, t3, 0, 1, 0, 0, 0);
            PHASE(1, 4, t3, 1, 1, 0, 0, 0);
            PHASE(1, 6, t3, 2, 1, 1, 1, 0);   // vmcnt(6); postload B(t2) from buf0
        }

        // ---- epilogue for output row-block mb (raw barriers only; NO vmcnt drain) ----
        // C layout (m89): col = cf*16 + cl (+ wn*64), row = f*16 + q*4 + reg (+ wm*128).
        #pragma unroll
        for (int f = 0; f < 8; f++) {
            #pragma unroll
            for (int r = 0; r < 4; r++) {
                float v0 = acc[f][0][r], v1 = acc[f][1][r], v2 = acc[f][2][r], v3 = acc[f][3][r];
                float m = v0; int cj = 0;
                if (v1 > m) { m = v1; cj = 1; }
                if (v2 > m) { m = v2; cj = 2; }
                if (v3 > m) { m = v3; cj = 3; }
                float s = __expf(v0 - m) + __expf(v1 - m) + __expf(v2 - m) + __expf(v3 - m);
                int cidx = wn * 64 + cj * 16 + cl;
                #pragma unroll
                for (int off = 1; off < 16; off <<= 1) {
                    float m2 = __shfl_xor(m, off);
                    float s2 = __shfl_xor(s, off);
                    int   c2 = __shfl_xor(cidx, off);
                    float nm = fmaxf(m, m2);
                    s = s * __expf(m - nm) + s2 * __expf(m2 - nm);
                    if (m2 > m || (m2 == m && c2 < cidx)) cidx = c2;   // first-occurrence ties
                    m = nm;
                }
                int rloc = wm * 128 + f * 16 + q * 4 + r;
                if (cl == 0) { redM[rloc*4+wn] = m; redS[rloc*4+wn] = s; redC[rloc*4+wn] = cidx; }
            }
        }
        asm volatile("s_waitcnt lgkmcnt(0)" ::: "memory");   // seal scratch writes
        __builtin_amdgcn_s_barrier();
        asm volatile("" ::: "memory");
        if (tid < 256) {
            float m = redM[tid*4+0], s = redS[tid*4+0];
            int   cc = redC[tid*4+0];
            #pragma unroll
            for (int i2 = 1; i2 < 4; i2++) {
                float m2 = redM[tid*4+i2], s2 = redS[tid*4+i2];
                int   c2 = redC[tid*4+i2];
                float nm = fmaxf(m, m2);
                s = s * __expf(m - nm) + s2 * __expf(m2 - nm);
                if (m2 > m) cc = c2;             // ascending col order; ties keep lower col
                m = nm;
            }
            pp[(size_t)(mb * 256 + tid) * NBLK2 + nb] =
                make_float4(m, s, __int_as_float(nb * 256 + cc), 0.f);
        }
        // Reset accumulators; no trailing barrier needed (next p1's barrier A resyncs;
        // scratch isn't rewritten for another 16 iterations' worth of barriers).
        #pragma unroll
        for (int i = 0; i < 8; i++)
            #pragma unroll
            for (int j = 0; j < 4; j++) acc[i][j] = zero;
    }
}

// ---------------- fallback GEMM (round-1, in-kernel convert + gather) ----------------
__global__ __launch_bounds__(256) void gemm_lse_fallback(
    const float* __restrict__ A, const float* __restrict__ Bw,
    float4* __restrict__ part, const int* __restrict__ token,
    float* __restrict__ gather_out)
{
    __shared__ char smem[TM*TK*2 + TN*TK*2];
    ushort* sA = (ushort*)smem;
    ushort* sB = (ushort*)(smem + TM*TK*2);
    float* redM   = (float*)smem;
    float* redS   = (float*)(smem + 1024);
    int*   redC   = (int*)  (smem + 2048);
    int*   tokloc = (int*)  (smem + 3072);

    const int tid  = threadIdx.x;
    const int lane = tid & 63;
    const int wv   = tid >> 6;
    const int wm   = wv >> 1, wn = wv & 1;
    const int q    = lane >> 4, cl = lane & 15;
    const int m0 = blockIdx.x * TM;
    const int n0 = blockIdx.y * TN;
    const int nb = blockIdx.y;

    const int srow = tid >> 1, sseg = tid & 1;
    const float4* gA = (const float4*)(A  + (size_t)(m0 + srow) * H_DIM) + sseg * 4;
    const float4* gB = (const float4*)(Bw + (size_t)(n0 + srow) * H_DIM) + sseg * 4;
    uint4* wA = (uint4*)sA + srow * 4 + sseg * 2;
    uint4* wB = (uint4*)sB + srow * 4 + sseg * 2;

    f32x4 acc[4][4];
    const f32x4 zero = {0.f, 0.f, 0.f, 0.f};
    #pragma unroll
    for (int i = 0; i < 4; i++)
        #pragma unroll
        for (int j = 0; j < 4; j++) acc[i][j] = zero;

    float4 ra0 = gA[0], ra1 = gA[1], ra2 = gA[2], ra3 = gA[3];
    float4 rb0 = gB[0], rb1 = gB[1], rb2 = gB[2], rb3 = gB[3];

    for (int kt = 0; kt < H_DIM; kt += TK) {
        wA[0] = make_uint4(pack_bf16x2(ra0.x,ra0.y), pack_bf16x2(ra0.z,ra0.w),
                           pack_bf16x2(ra1.x,ra1.y), pack_bf16x2(ra1.z,ra1.w));
        wA[1] = make_uint4(pack_bf16x2(ra2.x,ra2.y), pack_bf16x2(ra2.z,ra2.w),
                           pack_bf16x2(ra3.x,ra3.y), pack_bf16x2(ra3.z,ra3.w));
        wB[0] = make_uint4(pack_bf16x2(rb0.x,rb0.y), pack_bf16x2(rb0.z,rb0.w),
                           pack_bf16x2(rb1.x,rb1.y), pack_bf16x2(rb1.z,rb1.w));
        wB[1] = make_uint4(pack_bf16x2(rb2.x,rb2.y), pack_bf16x2(rb2.z,rb2.w),
                           pack_bf16x2(rb3.x,rb3.y), pack_bf16x2(rb3.z,rb3.w));
        __syncthreads();
        if (kt + TK < H_DIM) {
            int kq = (kt + TK) >> 2;
            ra0 = gA[kq]; ra1 = gA[kq+1]; ra2 = gA[kq+2]; ra3 = gA[kq+3];
            rb0 = gB[kq]; rb1 = gB[kq+1]; rb2 = gB[kq+2]; rb3 = gB[kq+3];
        }
        bf16x8 af[4], bfr[4];
        #pragma unroll
        for (int i = 0; i < 4; i++) {
            af[i]  = *(const bf16x8*)(sA + (wm*64 + i*16 + cl) * TK + q*8);
            bfr[i] = *(const bf16x8*)(sB + (wn*64 + i*16 + cl) * TK + q*8);
        }
        #pragma unroll
        for (int i = 0; i < 4; i++)
            #pragma unroll
            for (int j = 0; j < 4; j++)
                acc[i][j] = __builtin_amdgcn_mfma_f32_16x16x32_bf16(af[i], bfr[j], acc[i][j], 0, 0, 0);
        __syncthreads();
    }

    #pragma unroll
    for (int ti = 0; ti < 4; ti++) {
        #pragma unroll
        for (int r = 0; r < 4; r++) {
            float vals[4];
            #pragma unroll
            for (int j = 0; j < 4; j++) vals[j] = acc[ti][j][r];
            float m = vals[0]; int cj = 0;
            #pragma unroll
            for (int j = 1; j < 4; j++) if (vals[j] > m) { m = vals[j]; cj = j; }
            float s = 0.f;
            #pragma unroll
            for (int j = 0; j < 4; j++) s += __expf(vals[j] - m);
            int cidx = wn*64 + cj*16 + cl;
            #pragma unroll
            for (int off = 1; off < 16; off <<= 1) {
                float m2 = __shfl_xor(m, off);
                float s2 = __shfl_xor(s, off);
                int   c2 = __shfl_xor(cidx, off);
                float nm = fmaxf(m, m2);
                s = s * __expf(m - nm) + s2 * __expf(m2 - nm);
                if (m2 > m || (m2 == m && c2 < cidx)) cidx = c2;
                m = nm;
            }
            int rloc = wm*64 + ti*16 + q*4 + r;
            if (cl == 0) { redM[rloc*2+wn] = m; redS[rloc*2+wn] = s; redC[rloc*2+wn] = cidx; }
        }
    }
    __syncthreads();
    if (tid < TM) {
        float ma = redM[tid*2+0], mb = redM[tid*2+1];
        float sa = redS[tid*2+0], sb = redS[tid*2+1];
        int   ca = redC[tid*2+0], cb = redC[tid*2+1];
        float nm = fmaxf(ma, mb);
        float s  = sa * __expf(ma - nm) + sb * __expf(mb - nm);
        int   cc = (mb > ma || (mb == ma && cb < ca)) ? cb : ca;
        part[(size_t)(m0 + tid) * NBLK_FB + nb] = make_float4(nm, s, __int_as_float(n0 + cc), 0.f);
    }

    if (token != nullptr) {
        if (tid < TM) tokloc[tid] = token[m0 + tid] - n0;
        __syncthreads();
        #pragma unroll
        for (int ti = 0; ti < 4; ti++) {
            #pragma unroll
            for (int r = 0; r < 4; r++) {
                int rloc = wm*64 + ti*16 + q*4 + r;
                int tl = tokloc[rloc];
                if (tl >= 0 && tl < TN && ((tl >> 6) & 1) == wn && (tl & 15) == cl) {
                    int tjm = (tl >> 4) & 3;
                    float v = acc[ti][0][r];
                    if (tjm == 1) v = acc[ti][1][r];
                    if (tjm == 2) v = acc[ti][2][r];
                    if (tjm == 3) v = acc[ti][3][r];
                    gather_out[m0 + rloc] = v;
                }
            }
        }
    }
}

// ---------------- reductions ----------------

__global__ __launch_bounds__(256) void reduce_policy_kernel(
    const float4* __restrict__ part, int* __restrict__ token, float* __restrict__ tok_logp,
    int nblk)
{
    int row = blockIdx.x, t = threadIdx.x;
    float m = -3.0e38f, s = 0.f; int cc = 0x7fffffff;
    if (t < nblk) { float4 p = part[(size_t)row * nblk + t]; m = p.x; s = p.y; cc = __float_as_int(p.z); }
    for (int off = 1; off < 64; off <<= 1) {
        float m2 = __shfl_xor(m, off);
        float s2 = __shfl_xor(s, off);
        int   c2 = __shfl_xor(cc, off);
        float nm = fmaxf(m, m2);
        s = s * __expf(m - nm) + s2 * __expf(m2 - nm);
        if (m2 > m || (m2 == m && c2 < cc)) cc = c2;
        m = nm;
    }
    __shared__ float smM[4], smS[4]; __shared__ int smC[4];
    if ((t & 63) == 0) { smM[t>>6] = m; smS[t>>6] = s; smC[t>>6] = cc; }
    __syncthreads();
    if (t == 0) {
        m = smM[0]; s = smS[0]; cc = smC[0];
        for (int i = 1; i < 4; i++) {
            float m2 = smM[i], s2 = smS[i]; int c2 = smC[i];
            float nm = fmaxf(m, m2);
            s = s * __expf(m - nm) + s2 * __expf(m2 - nm);
            if (m2 > m || (m2 == m && c2 < cc)) cc = c2;
            m = nm;
        }
        token[row] = cc;
        tok_logp[row] = -__logf(s);    // token is argmax -> logit[token] == global max
    }
}

// gathered[row] = dot(ref_input[row], ref_weight[token[row]]) in exact fp32.
__global__ __launch_bounds__(256) void dot_gather_kernel(
    const float* __restrict__ rx, const float* __restrict__ rw,
    const int* __restrict__ token, float* __restrict__ out)
{
    int row = blockIdx.x, t = threadIdx.x;
    const float4* a = (const float4*)(rx + (size_t)row * H_DIM);
    const float4* b = (const float4*)(rw + (size_t)token[row] * H_DIM);
    float4 a0 = a[t*2], a1 = a[t*2+1], b0 = b[t*2], b1 = b[t*2+1];
    float s = a0.x*b0.x + a0.y*b0.y + a0.z*b0.z + a0.w*b0.w
            + a1.x*b1.x + a1.y*b1.y + a1.z*b1.z + a1.w*b1.w;
    for (int off = 1; off < 64; off <<= 1) s += __shfl_xor(s, off);
    __shared__ float ss[4];
    if ((t & 63) == 0) ss[t >> 6] = s;
    __syncthreads();
    if (t == 0) out[row] = ss[0] + ss[1] + ss[2] + ss[3];
}

__global__ __launch_bounds__(256) void reduce_ref_kernel(
    const float4* __restrict__ part, const float* __restrict__ tok_logp,
    const float* __restrict__ gathered, float* __restrict__ klrow, int nblk)
{
    int row = blockIdx.x, t = threadIdx.x;
    float m = -3.0e38f, s = 0.f;
    if (t < nblk) { float4 p = part[(size_t)row * nblk + t]; m = p.x; s = p.y; }
    for (int off = 1; off < 64; off <<= 1) {
        float m2 = __shfl_xor(m, off), s2 = __shfl_xor(s, off);
        merge_ms(m, s, m2, s2);
    }
    __shared__ float smM[4], smS[4];
    if ((t & 63) == 0) { smM[t>>6] = m; smS[t>>6] = s; }
    __syncthreads();
    if (t == 0) {
        m = smM[0]; s = smS[0];
        for (int i = 1; i < 4; i++) merge_ms(m, s, smM[i], smS[i]);
        float lse = m + __logf(s);
        float d = (gathered[row] - lse) - tok_logp[row];   // ref_tok_logp - tok_logp
        klrow[row] = __expf(d) - d - 1.0f;
    }
}

__global__ __launch_bounds__(256) void final_kernel(
    const int* __restrict__ amask, const float* __restrict__ rewards,
    const float* __restrict__ klrow, float* __restrict__ out)
{
    int t = threadIdx.x;
    int b = t >> 5;
    int g = b >> 2;
    float r0 = rewards[g*4+0], r1 = rewards[g*4+1], r2 = rewards[g*4+2], r3 = rewards[g*4+3];
    float mean = 0.25f * (r0 + r1 + r2 + r3);
    float var = ((r0-mean)*(r0-mean) + (r1-mean)*(r1-mean) +
                 (r2-mean)*(r2-mean) + (r3-mean)*(r3-mean)) * (1.0f/3.0f);  // ddof=1
    float adv = (rewards[b] - mean) / (sqrtf(var) + EPSR);

    float ln = 0.f, ms = 0.f, kb = 0.f, mb = 0.f;
    for (int i = 0; i < 8; i++) {
        int row = t*8 + i;
        float mk = (float)amask[row];
        float kl = klrow[row];
        ln += (adv - BETA * kl) * mk;
        ms += mk;
        kb += kl * mk;
        mb += mk;
    }
    __shared__ float sLN[256], sMS[256], sKB[256], sMB[256], sKLb[8];
    sLN[t] = ln; sMS[t] = ms; sKB[t] = kb; sMB[t] = mb;
    __syncthreads();
    if (t < 8) {
        float skb = 0.f, smb = 0.f;
        for (int i = 0; i < 32; i++) { skb += sKB[t*32+i]; smb += sMB[t*32+i]; }
        sKLb[t] = skb / smb;
    }
    __syncthreads();
    if (t == 0) {
        float lnt = 0.f, mst = 0.f;
        for (int i = 0; i < 256; i++) { lnt += sLN[i]; mst += sMS[i]; }
        float mkl = 0.f;
        for (int i = 0; i < 8; i++) mkl += sKLb[i];
        out[0] = -lnt / mst;
        out[1] = mkl * 0.125f;
    }
}

// ---------------- launch ----------------

extern "C" void kernel_launch(void* const* d_in, const int* in_sizes, int n_in,
                              void* d_out, int out_size, void* d_ws, size_t ws_size,
                              hipStream_t stream)
{
    const float* x       = (const float*)d_in[0];
    const float* w       = (const float*)d_in[1];
    const int*   amask   = (const int*)  d_in[2];
    const float* rewards = (const float*)d_in[3];
    const float* rx      = (const float*)d_in[4];
    const float* rw      = (const float*)d_in[5];
    float* out = (float*)d_out;
    char* ws = (char*)d_ws;

    const size_t W_P  = (size_t)V_DIM * H_DIM * 2;   // 131,072,000 bf16 bytes
    const size_t A_P  = (size_t)BT * H_DIM * 2;      //   8,388,608
    const size_t PART = (size_t)BT * NBLK2 * 16;     //   4,096,000
    const size_t NEED = 2*W_P + 2*A_P + 2*PART + 4*8192;

    if (ws_size >= NEED) {
        // ---- fast path: pack to bf16 slabs, persistent 8-phase GEMM, exact-dot gather ----
        ushort* Wp   = (ushort*)(ws);
        ushort* RWp  = (ushort*)(ws + W_P);
        ushort* Ap   = (ushort*)(ws + 2*W_P);
        ushort* Rp   = (ushort*)(ws + 2*W_P + A_P);
        float4* part  = (float4*)(ws + 2*W_P + 2*A_P);
        float4* part2 = (float4*)(ws + 2*W_P + 2*A_P + PART);
        char*   tail  =          ws + 2*W_P + 2*A_P + 2*PART;
        int*   token    = (int*)  (tail);
        float* tok_logp = (float*)(tail + 8192);
        float* gathered = (float*)(tail + 16384);
        float* klrow    = (float*)(tail + 24576);

        pack_all_kernel<<<dim3(532, NT), 256, 0, stream>>>(
            x, w, rx, rw, (uint4*)Ap, (uint4*)Wp, (uint4*)Rp, (uint4*)RWp);

        gemm_lse_persist<<<dim3(250), 512, 0, stream>>>(Ap, Wp, Rp, RWp, part, part2);

        reduce_policy_kernel<<<BT, 256, 0, stream>>>(part, token, tok_logp, NBLK2);
        dot_gather_kernel<<<BT, 256, 0, stream>>>(rx, rw, token, gathered);
        reduce_ref_kernel<<<BT, 256, 0, stream>>>(part2, tok_logp, gathered, klrow, NBLK2);
        final_kernel<<<1, 256, 0, stream>>>(amask, rewards, klrow, out);
    } else {
        // ---- fallback: round-1 path (ws too small for packed weights) ----
        const size_t PART_FB = (size_t)BT * NBLK_FB * 16;
        float4* part     = (float4*)ws;
        int*    token    = (int*)  (ws + PART_FB);
        float*  tok_logp = (float*)(ws + PART_FB + 8192);
        float*  gathered = (float*)(ws + PART_FB + 16384);
        float*  klrow    = (float*)(ws + PART_FB + 24576);

        dim3 g(BT / TM, NBLK_FB), blk(256);
        gemm_lse_fallback<<<g, blk, 0, stream>>>(x, w, part, nullptr, nullptr);
        reduce_policy_kernel<<<BT, 256, 0, stream>>>(part, token, tok_logp, NBLK_FB);
        gemm_lse_fallback<<<g, blk, 0, stream>>>(rx, rw, part, token, gathered);
        reduce_ref_kernel<<<BT, 256, 0, stream>>>(part, tok_logp, gathered, klrow, NBLK_FB);
        final_kernel<<<1, 256, 0, stream>>>(amask, rewards, klrow, out);
    }
}

// Round 3
// 1134.809 us; speedup vs baseline: 1.1447x; 1.1447x over previous
//
#include <hip/hip_runtime.h>
#include <hip/hip_bf16.h>
#include <math.h>

// Problem constants (fixed by the reference: H=2048, V=32000, B=8, T=256, G=4).
#define H_DIM 2048
#define V_DIM 32000
#define BT    2048            // B*T rows
#define BETA  0.1f
#define EPSR  1e-4f

// ---- fast-path GEMM geometry: 256x256 tile, BK=64, 8 waves (2M x 4N) ----
#define NT    32              // K tiles of 64 (H/64)
#define NBLK2 125             // V / 256
// ---- fallback geometry (round-1 kernel, unchanged) ----
#define TM 128
#define TN 128
#define TK 32
#define NBLK_FB 250

typedef __attribute__((ext_vector_type(8))) short bf16x8;   // 8 bf16 = 4 VGPRs
typedef __attribute__((ext_vector_type(4))) float f32x4;

// ---------------- helpers ----------------

// Pack two fp32 -> bf16x2 (round-half-up via +0x8000, take high 16 bits each).
__device__ __forceinline__ unsigned pack_bf16x2(float a, float b) {
    unsigned ua = __float_as_uint(a) + 0x8000u;
    unsigned ub = __float_as_uint(b) + 0x8000u;
    return __builtin_amdgcn_perm(ub, ua, 0x07060302u);
}

__device__ __forceinline__ void merge_ms(float& m, float& s, float m2, float s2) {
    float nm = fmaxf(m, m2);
    s = s * __expf(m - nm) + s2 * __expf(m2 - nm);
    m = nm;
}

// Async global->LDS, 16 B per lane. LDS dest = wave-uniform base + lane*16.
__device__ __forceinline__ void gl_lds16(const void* g, void* l) {
    __builtin_amdgcn_global_load_lds(
        (const __attribute__((address_space(1))) void*)g,
        (__attribute__((address_space(3))) void*)l, 16, 0, 0);
}

// ---------------- pack: fp32 [R,2048] -> bf16 slabs per (256-row, 64-K) tile ----------------
// Slab (rt,kt) is 32 KB: chunk (kk*256+row) holds src[rt*256+row][kt*64+kk*8..+8] as 8 bf16.
// This is both the GEMM LDS layout (global_load_lds = linear copy) and the MFMA fragment
// order, so GEMM ds_read_b128s are bank-uniform. One fused kernel packs all 4 arrays:
// blockIdx.x spans {x:16, w:250, rx:16, rw:250} row-tiles of 128; blockIdx.y = kt (0..31).
__global__ __launch_bounds__(256) void pack_all_kernel(
    const float* __restrict__ x,  const float* __restrict__ w,
    const float* __restrict__ rx, const float* __restrict__ rw,
    uint4* __restrict__ Ap, uint4* __restrict__ Wp,
    uint4* __restrict__ Rp, uint4* __restrict__ RWp)
{
    __shared__ float tile[128 * 68];       // stride 68 floats: float4-aligned, spread banks
    const int t  = threadIdx.x;
    const int bx = blockIdx.x, kt = blockIdx.y;

    const float* src; uint4* dst; int rb;
    if (bx < 16)       { src = x;  dst = Ap;  rb = bx; }
    else if (bx < 266) { src = w;  dst = Wp;  rb = bx - 16; }
    else if (bx < 282) { src = rx; dst = Rp;  rb = bx - 266; }
    else               { src = rw; dst = RWp; rb = bx - 282; }

    const int rh = rb & 1, rt = rb >> 1;
    const int r0 = rb * 128;

    // Coalesced read: 128 rows x 64 floats (256 B contiguous per row).
    #pragma unroll
    for (int it = 0; it < 8; it++) {
        int idx = it * 256 + t;                        // 0..2047
        int row = idx >> 4, seg = idx & 15;
        float4 v = *(const float4*)(src + (size_t)(r0 + row) * H_DIM + kt * 64 + seg * 4);
        *(float4*)(tile + row * 68 + seg * 4) = v;
    }
    __syncthreads();

    // Coalesced write: 1024 x 16B chunks into slab (rt, kt), rows rh*128..+128.
    uint4* d = dst + (((size_t)rt * NT + kt) << 11);   // 2048 uint4 per slab
    #pragma unroll
    for (int it = 0; it < 4; it++) {
        int c = it * 256 + t;                          // 0..1023
        int kk = c >> 7, row = c & 127;
        const float* p = tile + row * 68 + kk * 8;
        d[(size_t)kk * 256 + rh * 128 + row] = make_uint4(
            pack_bf16x2(p[0], p[1]), pack_bf16x2(p[2], p[3]),
            pack_bf16x2(p[4], p[5]), pack_bf16x2(p[6], p[7]));
    }
}

// ---------------- 256^2 8-phase GEMM (XCD-swizzled) + online-softmax epilogue ----------------
// 2000 blocks, 1 per CU resident (128KB tiles + 12KB scratch). Work index
// l = (bid%8)*250 + bid/8 gives each XCD a contiguous chunk; mb = l&7 varies fastest, so the
// ~32 co-resident blocks per XCD span ~4 consecutive (z,nb) B-panels (~4MB = L2 size): B
// staging is L2-served after the first toucher, which is what the phase rate is bound by.
//
// Per-phase B-frag reads run POST-MFMA at p4/p8 (legal: p4's vmcnt(6) completes all loads
// through p1, which includes that tile's B staged >=3 phases earlier; barrier then publishes
// them). Every phase's pre-MFMA ds-drain is a uniform 4 reads.
//
// Epilogue uses a dedicated 12KB LDS scratch with raw s_barrier + lgkmcnt(0) only -- no
// vmcnt(0) drain (tail dummy stages still in flight target the tile buffers, disjoint).

#define MF(a,b,c) __builtin_amdgcn_mfma_f32_16x16x32_bf16(a, b, c, 0, 0, 0)

#define LDA(dst, BUF, F, KS) \
    dst = *(const bf16x8*)(smem + (BUF)*65536 + (KS)*16384 + (F)*256 + aoff)
#define LDB(dst, BUF, CF, KS) \
    dst = *(const bf16x8*)(smem + (BUF)*65536 + (KS)*16384 + (CF)*256 + boff)

#define STAGE(SG, SHT, SBUF) do { \
    const char* s_ = ((SHT) < 2 ? Bbase : Abase) + ((size_t)(SG) << 15); \
    char* l_ = smem + (SBUF)*65536 + ((SHT) < 2 ? 32768 : 0); \
    gl_lds16(s_ + soff[SHT][0], l_ + soff[SHT][0]); \
    gl_lds16(s_ + soff[SHT][1], l_ + soff[SHT][1]); \
} while (0)

#define MFMA_PH(F0, A0, A1, A2, A3) do { \
    acc[F0][0]   = MF(A0, bfr[0][0], acc[F0][0]); \
    acc[F0][1]   = MF(A0, bfr[1][0], acc[F0][1]); \
    acc[F0][2]   = MF(A0, bfr[2][0], acc[F0][2]); \
    acc[F0][3]   = MF(A0, bfr[3][0], acc[F0][3]); \
    acc[F0+1][0] = MF(A2, bfr[0][0], acc[F0+1][0]); \
    acc[F0+1][1] = MF(A2, bfr[1][0], acc[F0+1][1]); \
    acc[F0+1][2] = MF(A2, bfr[2][0], acc[F0+1][2]); \
    acc[F0+1][3] = MF(A2, bfr[3][0], acc[F0+1][3]); \
    acc[F0][0]   = MF(A1, bfr[0][1], acc[F0][0]); \
    acc[F0][1]   = MF(A1, bfr[1][1], acc[F0][1]); \
    acc[F0][2]   = MF(A1, bfr[2][1], acc[F0][2]); \
    acc[F0][3]   = MF(A1, bfr[3][1], acc[F0][3]); \
    acc[F0+1][0] = MF(A3, bfr[0][1], acc[F0+1][0]); \
    acc[F0+1][1] = MF(A3, bfr[1][1], acc[F0+1][1]); \
    acc[F0+1][2] = MF(A3, bfr[2][1], acc[F0+1][2]); \
    acc[F0+1][3] = MF(A3, bfr[3][1], acc[F0+1][3]); \
} while (0)

// One phase. POSTB: after the MFMA cluster, reload the 8 B-frags from buffer PBUF for the
// NEXT 4 phases (data sealed by this phase's vmcnt(6) + barrier).
#define PHASE(BUF, F0, SG, SHT, SBUF, VM, POSTB, PBUF) do { \
    bf16x8 a0_, a1_, a2_, a3_; \
    LDA(a0_, BUF, F0, 0);   LDA(a1_, BUF, F0, 1); \
    LDA(a2_, BUF, F0+1, 0); LDA(a3_, BUF, F0+1, 1); \
    STAGE(SG, SHT, SBUF); \
    if (VM) asm volatile("s_waitcnt vmcnt(6)" ::: "memory"); \
    asm volatile("" ::: "memory"); \
    __builtin_amdgcn_s_barrier(); \
    asm volatile("s_waitcnt lgkmcnt(0)" ::: "memory"); \
    __builtin_amdgcn_s_setprio(1); \
    MFMA_PH(F0, a0_, a1_, a2_, a3_); \
    __builtin_amdgcn_s_setprio(0); \
    if (POSTB) { \
        LDB(bfr[0][0], PBUF, 0, 0); LDB(bfr[0][1], PBUF, 0, 1); \
        LDB(bfr[1][0], PBUF, 1, 0); LDB(bfr[1][1], PBUF, 1, 1); \
        LDB(bfr[2][0], PBUF, 2, 0); LDB(bfr[2][1], PBUF, 2, 1); \
        LDB(bfr[3][0], PBUF, 3, 0); LDB(bfr[3][1], PBUF, 3, 1); \
    } \
    asm volatile("" ::: "memory"); \
    __builtin_amdgcn_s_barrier(); \
    asm volatile("" ::: "memory"); \
} while (0)

__global__ __launch_bounds__(512, 2) void gemm_lse_swz(
    const ushort* __restrict__ Ap, const ushort* __restrict__ Wp,
    const ushort* __restrict__ Rp, const ushort* __restrict__ RWp,
    float4* __restrict__ part, float4* __restrict__ part2)
{
    __shared__ __align__(16) char smem_raw[131072 + 12288];  // tiles | epilogue scratch
    char* smem = smem_raw;
    float* redM = (float*)(smem_raw + 131072);               // 256 rows x 4 wn-segments
    float* redS = (float*)(smem_raw + 131072 + 4096);
    int*   redC = (int*)  (smem_raw + 131072 + 8192);

    const int tid  = threadIdx.x;
    const int lane = tid & 63;
    const int wv   = tid >> 6;                          // 0..7
    const int wm   = wv >> 2, wn = wv & 3;              // 2 x 4 wave grid: 128x64 per wave
    const int q    = lane >> 4, cl = lane & 15;

    // XCD-chunked work mapping: bid%8 ~ XCD (dispatch round-robin heuristic; speed-only).
    const int bid = blockIdx.x;                         // 0..1999
    const int l   = (bid & 7) * 250 + (bid >> 3);       // bijective
    const int mb  = l & 7;                              // varies fastest: 8 blocks share panel
    const int pn  = l >> 3;                             // 0..249 = (z, nb) panel
    const int z   = pn >= 125 ? 1 : 0;
    const int nb  = z ? pn - 125 : pn;

    const char* Abase = (const char*)(z ? Rp  : Ap) + ((size_t)(mb * NT) << 15);
    const char* Bbase = (const char*)(z ? RWp : Wp) + ((size_t)(nb * NT) << 15);
    float4* pp = z ? part2 : part;

    // Fragment-read base offsets (within a 64 KB tile-buffer).
    const int aoff = q * 4096 + (wm * 128 + cl) * 16;
    const int boff = 32768 + q * 4096 + (wn * 64 + cl) * 16;

    // Staging offsets: chunk c = wv*2 + l covers (kk, row-group), 64 rows/lane.
    int soff[4][2];
    #pragma unroll
    for (int li = 0; li < 2; li++) {
        int c = wv * 2 + li;
        int kko = (((c >> 3) << 2) + ((c >> 1) & 3)) * 4096;
        int rg = c & 1;
        soff[0][li] = kko + (rg * 64 + lane) * 16;            // B rows 0..128
        soff[1][li] = kko + (128 + rg * 64 + lane) * 16;      // B rows 128..256
        soff[2][li] = kko + (rg * 128 + lane) * 16;           // A rows {0-64, 128-192}
        soff[3][li] = kko + (rg * 128 + 64 + lane) * 16;      // A rows {64-128, 192-256}
    }

    f32x4 acc[8][4];
    const f32x4 zero = {0.f, 0.f, 0.f, 0.f};
    #pragma unroll
    for (int i = 0; i < 8; i++)
        #pragma unroll
        for (int j = 0; j < 4; j++) acc[i][j] = zero;

    bf16x8 bfr[4][2];

    // Prologue: tile0 (4 HTs) -> buf0, tile1 (ht0..2) -> buf1; 14 loads, keep 6 in flight.
    STAGE(0, 0, 0); STAGE(0, 1, 0); STAGE(0, 2, 0); STAGE(0, 3, 0);
    STAGE(1, 0, 1); STAGE(1, 1, 1); STAGE(1, 2, 1);
    asm volatile("s_waitcnt vmcnt(6)" ::: "memory");
    __builtin_amdgcn_s_barrier();
    asm volatile("" ::: "memory");
    // Initial B frags (tile 0, buf0); drained by p1's lgkmcnt(0).
    LDB(bfr[0][0], 0, 0, 0); LDB(bfr[0][1], 0, 0, 1);
    LDB(bfr[1][0], 0, 1, 0); LDB(bfr[1][1], 0, 1, 1);
    LDB(bfr[2][0], 0, 2, 0); LDB(bfr[2][1], 0, 2, 1);
    LDB(bfr[3][0], 0, 3, 0); LDB(bfr[3][1], 0, 3, 1);

    #pragma unroll 1
    for (int ii = 0; ii < 16; ii++) {
        int t1 = 2 * ii + 1;
        int t2 = 2 * ii + 2; if (t2 > NT - 1) t2 = NT - 1;  // tail: dummy (valid) stages,
        int t3 = 2 * ii + 3; if (t3 > NT - 1) t3 = NT - 1;  // keeps the vmcnt ledger exact
        PHASE(0, 0, t1, 3, 1, 0, 0, 0);
        PHASE(0, 2, t2, 0, 0, 0, 0, 0);
        PHASE(0, 4, t2, 1, 0, 0, 0, 0);
        PHASE(0, 6, t2, 2, 0, 1, 1, 1);   // vmcnt(6); postload B(t1) from buf1
        PHASE(1, 0, t2, 3, 0, 0, 0, 0);
        PHASE(1, 2, t3, 0, 1, 0, 0, 0);
        PHASE(1, 4, t3, 1, 1, 0, 0, 0);
        PHASE(1, 6, t3, 2, 1, 1, 1, 0);   // vmcnt(6); postload B(t2) from buf0
    }

    // ---- epilogue: per-row {max, argmax col, sumexp} over this block's 256 cols ----
    // C layout (m89): col = cf*16 + cl (+ wn*64), row = f*16 + q*4 + reg (+ wm*128).
    // Remaining in-flight dummy loads target the tile buffers (<128KB); scratch is above. Safe.
    #pragma unroll
    for (int f = 0; f < 8; f++) {
        #pragma unroll
        for (int r = 0; r < 4; r++) {
            float v0 = acc[f][0][r], v1 = acc[f][1][r], v2 = acc[f][2][r], v3 = acc[f][3][r];
            float m = v0; int cj = 0;
            if (v1 > m) { m = v1; cj = 1; }
            if (v2 > m) { m = v2; cj = 2; }
            if (v3 > m) { m = v3; cj = 3; }
            float s = __expf(v0 - m) + __expf(v1 - m) + __expf(v2 - m) + __expf(v3 - m);
            int cidx = wn * 64 + cj * 16 + cl;
            #pragma unroll
            for (int off = 1; off < 16; off <<= 1) {
                float m2 = __shfl_xor(m, off);
                float s2 = __shfl_xor(s, off);
                int   c2 = __shfl_xor(cidx, off);
                float nm = fmaxf(m, m2);
                s = s * __expf(m - nm) + s2 * __expf(m2 - nm);
                if (m2 > m || (m2 == m && c2 < cidx)) cidx = c2;   // first-occurrence ties
                m = nm;
            }
            int rloc = wm * 128 + f * 16 + q * 4 + r;
            if (cl == 0) { redM[rloc*4+wn] = m; redS[rloc*4+wn] = s; redC[rloc*4+wn] = cidx; }
        }
    }
    asm volatile("s_waitcnt lgkmcnt(0)" ::: "memory");   // seal scratch writes
    __builtin_amdgcn_s_barrier();
    asm volatile("" ::: "memory");
    if (tid < 256) {
        float m = redM[tid*4+0], s = redS[tid*4+0];
        int   cc = redC[tid*4+0];
        #pragma unroll
        for (int i2 = 1; i2 < 4; i2++) {
            float m2 = redM[tid*4+i2], s2 = redS[tid*4+i2];
            int   c2 = redC[tid*4+i2];
            float nm = fmaxf(m, m2);
            s = s * __expf(m - nm) + s2 * __expf(m2 - nm);
            if (m2 > m) cc = c2;                 // ascending col order; ties keep lower col
            m = nm;
        }
        pp[(size_t)(mb * 256 + tid) * NBLK2 + nb] =
            make_float4(m, s, __int_as_float(nb * 256 + cc), 0.f);
    }
}

// ---------------- fused row tail: policy argmax/lse + exact dot + ref lse + KL ----------------
__global__ __launch_bounds__(256) void row_tail_kernel(
    const float4* __restrict__ part, const float4* __restrict__ part2,
    const float* __restrict__ rx, const float* __restrict__ rw,
    float* __restrict__ klrow)
{
    __shared__ float smM[4], smS[4]; __shared__ int smC[4];
    __shared__ float ss[4];
    __shared__ float sTokLogp; __shared__ int sTok;

    const int row = blockIdx.x, t = threadIdx.x;

    // ---- policy: max / argmax / sumexp over 125 partials ----
    float m = -3.0e38f, s = 0.f; int cc = 0x7fffffff;
    if (t < NBLK2) { float4 p = part[(size_t)row * NBLK2 + t]; m = p.x; s = p.y; cc = __float_as_int(p.z); }
    for (int off = 1; off < 64; off <<= 1) {
        float m2 = __shfl_xor(m, off);
        float s2 = __shfl_xor(s, off);
        int   c2 = __shfl_xor(cc, off);
        float nm = fmaxf(m, m2);
        s = s * __expf(m - nm) + s2 * __expf(m2 - nm);
        if (m2 > m || (m2 == m && c2 < cc)) cc = c2;
        m = nm;
    }
    if ((t & 63) == 0) { smM[t>>6] = m; smS[t>>6] = s; smC[t>>6] = cc; }
    __syncthreads();
    if (t == 0) {
        m = smM[0]; s = smS[0]; cc = smC[0];
        for (int i = 1; i < 4; i++) {
            float m2 = smM[i], s2 = smS[i]; int c2 = smC[i];
            float nm = fmaxf(m, m2);
            s = s * __expf(m - nm) + s2 * __expf(m2 - nm);
            if (m2 > m || (m2 == m && c2 < cc)) cc = c2;
            m = nm;
        }
        sTok = cc;
        sTokLogp = -__logf(s);    // token is argmax -> logit[token] == global max
    }
    __syncthreads();
    const int tok = sTok;

    // ---- exact fp32 dot: rx[row] . rw[tok] ----
    const float4* a = (const float4*)(rx + (size_t)row * H_DIM);
    const float4* b = (const float4*)(rw + (size_t)tok * H_DIM);
    float4 a0 = a[t*2], a1 = a[t*2+1], b0 = b[t*2], b1 = b[t*2+1];
    float d = a0.x*b0.x + a0.y*b0.y + a0.z*b0.z + a0.w*b0.w
            + a1.x*b1.x + a1.y*b1.y + a1.z*b1.z + a1.w*b1.w;
    for (int off = 1; off < 64; off <<= 1) d += __shfl_xor(d, off);
    if ((t & 63) == 0) ss[t >> 6] = d;

    // ---- ref: lse over 125 partials ----
    float mr = -3.0e38f, sr = 0.f;
    if (t < NBLK2) { float4 p = part2[(size_t)row * NBLK2 + t]; mr = p.x; sr = p.y; }
    for (int off = 1; off < 64; off <<= 1) {
        float m2 = __shfl_xor(mr, off), s2 = __shfl_xor(sr, off);
        merge_ms(mr, sr, m2, s2);
    }
    __syncthreads();           // seals ss; frees smM/smS for reuse
    if ((t & 63) == 0) { smM[t>>6] = mr; smS[t>>6] = sr; }
    __syncthreads();
    if (t == 0) {
        mr = smM[0]; sr = smS[0];
        for (int i = 1; i < 4; i++) merge_ms(mr, sr, smM[i], smS[i]);
        float lse = mr + __logf(sr);
        float g = ss[0] + ss[1] + ss[2] + ss[3];
        float dd = (g - lse) - sTokLogp;   // ref_tok_logp - tok_logp
        klrow[row] = __expf(dd) - dd - 1.0f;
    }
}

// ---------------- fallback GEMM (round-1, in-kernel convert + gather) ----------------
__global__ __launch_bounds__(256) void gemm_lse_fallback(
    const float* __restrict__ A, const float* __restrict__ Bw,
    float4* __restrict__ part, const int* __restrict__ token,
    float* __restrict__ gather_out)
{
    __shared__ char smem[TM*TK*2 + TN*TK*2];
    ushort* sA = (ushort*)smem;
    ushort* sB = (ushort*)(smem + TM*TK*2);
    float* redM   = (float*)smem;
    float* redS   = (float*)(smem + 1024);
    int*   redC   = (int*)  (smem + 2048);
    int*   tokloc = (int*)  (smem + 3072);

    const int tid  = threadIdx.x;
    const int lane = tid & 63;
    const int wv   = tid >> 6;
    const int wm   = wv >> 1, wn = wv & 1;
    const int q    = lane >> 4, cl = lane & 15;
    const int m0 = blockIdx.x * TM;
    const int n0 = blockIdx.y * TN;
    const int nb = blockIdx.y;

    const int srow = tid >> 1, sseg = tid & 1;
    const float4* gA = (const float4*)(A  + (size_t)(m0 + srow) * H_DIM) + sseg * 4;
    const float4* gB = (const float4*)(Bw + (size_t)(n0 + srow) * H_DIM) + sseg * 4;
    uint4* wA = (uint4*)sA + srow * 4 + sseg * 2;
    uint4* wB = (uint4*)sB + srow * 4 + sseg * 2;

    f32x4 acc[4][4];
    const f32x4 zero = {0.f, 0.f, 0.f, 0.f};
    #pragma unroll
    for (int i = 0; i < 4; i++)
        #pragma unroll
        for (int j = 0; j < 4; j++) acc[i][j] = zero;

    float4 ra0 = gA[0], ra1 = gA[1], ra2 = gA[2], ra3 = gA[3];
    float4 rb0 = gB[0], rb1 = gB[1], rb2 = gB[2], rb3 = gB[3];

    for (int kt = 0; kt < H_DIM; kt += TK) {
        wA[0] = make_uint4(pack_bf16x2(ra0.x,ra0.y), pack_bf16x2(ra0.z,ra0.w),
                           pack_bf16x2(ra1.x,ra1.y), pack_bf16x2(ra1.z,ra1.w));
        wA[1] = make_uint4(pack_bf16x2(ra2.x,ra2.y), pack_bf16x2(ra2.z,ra2.w),
                           pack_bf16x2(ra3.x,ra3.y), pack_bf16x2(ra3.z,ra3.w));
        wB[0] = make_uint4(pack_bf16x2(rb0.x,rb0.y), pack_bf16x2(rb0.z,rb0.w),
                           pack_bf16x2(rb1.x,rb1.y), pack_bf16x2(rb1.z,rb1.w));
        wB[1] = make_uint4(pack_bf16x2(rb2.x,rb2.y), pack_bf16x2(rb2.z,rb2.w),
                           pack_bf16x2(rb3.x,rb3.y), pack_bf16x2(rb3.z,rb3.w));
        __syncthreads();
        if (kt + TK < H_DIM) {
            int kq = (kt + TK) >> 2;
            ra0 = gA[kq]; ra1 = gA[kq+1]; ra2 = gA[kq+2]; ra3 = gA[kq+3];
            rb0 = gB[kq]; rb1 = gB[kq+1]; rb2 = gB[kq+2]; rb3 = gB[kq+3];
        }
        bf16x8 af[4], bfr[4];
        #pragma unroll
        for (int i = 0; i < 4; i++) {
            af[i]  = *(const bf16x8*)(sA + (wm*64 + i*16 + cl) * TK + q*8);
            bfr[i] = *(const bf16x8*)(sB + (wn*64 + i*16 + cl) * TK + q*8);
        }
        #pragma unroll
        for (int i = 0; i < 4; i++)
            #pragma unroll
            for (int j = 0; j < 4; j++)
                acc[i][j] = __builtin_amdgcn_mfma_f32_16x16x32_bf16(af[i], bfr[j], acc[i][j], 0, 0, 0);
        __syncthreads();
    }

    #pragma unroll
    for (int ti = 0; ti < 4; ti++) {
        #pragma unroll
        for (int r = 0; r < 4; r++) {
            float vals[4];
            #pragma unroll
            for (int j = 0; j < 4; j++) vals[j] = acc[ti][j][r];
            float m = vals[0]; int cj = 0;
            #pragma unroll
            for (int j = 1; j < 4; j++) if (vals[j] > m) { m = vals[j]; cj = j; }
            float s = 0.f;
            #pragma unroll
            for (int j = 0; j < 4; j++) s += __expf(vals[j] - m);
            int cidx = wn*64 + cj*16 + cl;
            #pragma unroll
            for (int off = 1; off < 16; off <<= 1) {
                float m2 = __shfl_xor(m, off);
                float s2 = __shfl_xor(s, off);
                int   c2 = __shfl_xor(cidx, off);
                float nm = fmaxf(m, m2);
                s = s * __expf(m - nm) + s2 * __expf(m2 - nm);
                if (m2 > m || (m2 == m && c2 < cidx)) cidx = c2;
                m = nm;
            }
            int rloc = wm*64 + ti*16 + q*4 + r;
            if (cl == 0) { redM[rloc*2+wn] = m; redS[rloc*2+wn] = s; redC[rloc*2+wn] = cidx; }
        }
    }
    __syncthreads();
    if (tid < TM) {
        float ma = redM[tid*2+0], mb = redM[tid*2+1];
        float sa = redS[tid*2+0], sb = redS[tid*2+1];
        int   ca = redC[tid*2+0], cb = redC[tid*2+1];
        float nm = fmaxf(ma, mb);
        float s  = sa * __expf(ma - nm) + sb * __expf(mb - nm);
        int   cc = (mb > ma || (mb == ma && cb < ca)) ? cb : ca;
        part[(size_t)(m0 + tid) * NBLK_FB + nb] = make_float4(nm, s, __int_as_float(n0 + cc), 0.f);
    }

    if (token != nullptr) {
        if (tid < TM) tokloc[tid] = token[m0 + tid] - n0;
        __syncthreads();
        #pragma unroll
        for (int ti = 0; ti < 4; ti++) {
            #pragma unroll
            for (int r = 0; r < 4; r++) {
                int rloc = wm*64 + ti*16 + q*4 + r;
                int tl = tokloc[rloc];
                if (tl >= 0 && tl < TN && ((tl >> 6) & 1) == wn && (tl & 15) == cl) {
                    int tjm = (tl >> 4) & 3;
                    float v = acc[ti][0][r];
                    if (tjm == 1) v = acc[ti][1][r];
                    if (tjm == 2) v = acc[ti][2][r];
                    if (tjm == 3) v = acc[ti][3][r];
                    gather_out[m0 + rloc] = v;
                }
            }
        }
    }
}

// ---------------- fallback reductions ----------------

__global__ __launch_bounds__(256) void reduce_policy_kernel(
    const float4* __restrict__ part, int* __restrict__ token, float* __restrict__ tok_logp,
    int nblk)
{
    int row = blockIdx.x, t = threadIdx.x;
    float m = -3.0e38f, s = 0.f; int cc = 0x7fffffff;
    if (t < nblk) { float4 p = part[(size_t)row * nblk + t]; m = p.x; s = p.y; cc = __float_as_int(p.z); }
    for (int off = 1; off < 64; off <<= 1) {
        float m2 = __shfl_xor(m, off);
        float s2 = __shfl_xor(s, off);
        int   c2 = __shfl_xor(cc, off);
        float nm = fmaxf(m, m2);
        s = s * __expf(m - nm) + s2 * __expf(m2 - nm);
        if (m2 > m || (m2 == m && c2 < cc)) cc = c2;
        m = nm;
    }
    __shared__ float smM[4], smS[4]; __shared__ int smC[4];
    if ((t & 63) == 0) { smM[t>>6] = m; smS[t>>6] = s; smC[t>>6] = cc; }
    __syncthreads();
    if (t == 0) {
        m = smM[0]; s = smS[0]; cc = smC[0];
        for (int i = 1; i < 4; i++) {
            float m2 = smM[i], s2 = smS[i]; int c2 = smC[i];
            float nm = fmaxf(m, m2);
            s = s * __expf(m - nm) + s2 * __expf(m2 - nm);
            if (m2 > m || (m2 == m && c2 < cc)) cc = c2;
            m = nm;
        }
        token[row] = cc;
        tok_logp[row] = -__logf(s);
    }
}

__global__ __launch_bounds__(256) void dot_gather_kernel(
    const float* __restrict__ rx, const float* __restrict__ rw,
    const int* __restrict__ token, float* __restrict__ out)
{
    int row = blockIdx.x, t = threadIdx.x;
    const float4* a = (const float4*)(rx + (size_t)row * H_DIM);
    const float4* b = (const float4*)(rw + (size_t)token[row] * H_DIM);
    float4 a0 = a[t*2], a1 = a[t*2+1], b0 = b[t*2], b1 = b[t*2+1];
    float s = a0.x*b0.x + a0.y*b0.y + a0.z*b0.z + a0.w*b0.w
            + a1.x*b1.x + a1.y*b1.y + a1.z*b1.z + a1.w*b1.w;
    for (int off = 1; off < 64; off <<= 1) s += __shfl_xor(s, off);
    __shared__ float ss[4];
    if ((t & 63) == 0) ss[t >> 6] = s;
    __syncthreads();
    if (t == 0) out[row] = ss[0] + ss[1] + ss[2] + ss[3];
}

__global__ __launch_bounds__(256) void reduce_ref_kernel(
    const float4* __restrict__ part, const float* __restrict__ tok_logp,
    const float* __restrict__ gathered, float* __restrict__ klrow, int nblk)
{
    int row = blockIdx.x, t = threadIdx.x;
    float m = -3.0e38f, s = 0.f;
    if (t < nblk) { float4 p = part[(size_t)row * nblk + t]; m = p.x; s = p.y; }
    for (int off = 1; off < 64; off <<= 1) {
        float m2 = __shfl_xor(m, off), s2 = __shfl_xor(s, off);
        merge_ms(m, s, m2, s2);
    }
    __shared__ float smM[4], smS[4];
    if ((t & 63) == 0) { smM[t>>6] = m; smS[t>>6] = s; }
    __syncthreads();
    if (t == 0) {
        m = smM[0]; s = smS[0];
        for (int i = 1; i < 4; i++) merge_ms(m, s, smM[i], smS[i]);
        float lse = m + __logf(s);
        float d = (gathered[row] - lse) - tok_logp[row];
        klrow[row] = __expf(d) - d - 1.0f;
    }
}

__global__ __launch_bounds__(256) void final_kernel(
    const int* __restrict__ amask, const float* __restrict__ rewards,
    const float* __restrict__ klrow, float* __restrict__ out)
{
    int t = threadIdx.x;
    int b = t >> 5;
    int g = b >> 2;
    float r0 = rewards[g*4+0], r1 = rewards[g*4+1], r2 = rewards[g*4+2], r3 = rewards[g*4+3];
    float mean = 0.25f * (r0 + r1 + r2 + r3);
    float var = ((r0-mean)*(r0-mean) + (r1-mean)*(r1-mean) +
                 (r2-mean)*(r2-mean) + (r3-mean)*(r3-mean)) * (1.0f/3.0f);  // ddof=1
    float adv = (rewards[b] - mean) / (sqrtf(var) + EPSR);

    float ln = 0.f, ms = 0.f, kb = 0.f, mb = 0.f;
    for (int i = 0; i < 8; i++) {
        int row = t*8 + i;
        float mk = (float)amask[row];
        float kl = klrow[row];
        ln += (adv - BETA * kl) * mk;
        ms += mk;
        kb += kl * mk;
        mb += mk;
    }
    __shared__ float sLN[256], sMS[256], sKB[256], sMB[256], sKLb[8];
    sLN[t] = ln; sMS[t] = ms; sKB[t] = kb; sMB[t] = mb;
    __syncthreads();
    if (t < 8) {
        float skb = 0.f, smb = 0.f;
        for (int i = 0; i < 32; i++) { skb += sKB[t*32+i]; smb += sMB[t*32+i]; }
        sKLb[t] = skb / smb;
    }
    __syncthreads();
    if (t == 0) {
        float lnt = 0.f, mst = 0.f;
        for (int i = 0; i < 256; i++) { lnt += sLN[i]; mst += sMS[i]; }
        float mkl = 0.f;
        for (int i = 0; i < 8; i++) mkl += sKLb[i];
        out[0] = -lnt / mst;
        out[1] = mkl * 0.125f;
    }
}

// ---------------- launch ----------------

extern "C" void kernel_launch(void* const* d_in, const int* in_sizes, int n_in,
                              void* d_out, int out_size, void* d_ws, size_t ws_size,
                              hipStream_t stream)
{
    const float* x       = (const float*)d_in[0];
    const float* w       = (const float*)d_in[1];
    const int*   amask   = (const int*)  d_in[2];
    const float* rewards = (const float*)d_in[3];
    const float* rx      = (const float*)d_in[4];
    const float* rw      = (const float*)d_in[5];
    float* out = (float*)d_out;
    char* ws = (char*)d_ws;

    const size_t W_P  = (size_t)V_DIM * H_DIM * 2;   // 131,072,000 bf16 bytes
    const size_t A_P  = (size_t)BT * H_DIM * 2;      //   8,388,608
    const size_t PART = (size_t)BT * NBLK2 * 16;     //   4,096,000
    const size_t NEED = 2*W_P + 2*A_P + 2*PART + 4*8192;

    if (ws_size >= NEED) {
        // ---- fast path: pack to bf16 slabs, XCD-swizzled 8-phase GEMM, fused row tail ----
        ushort* Wp   = (ushort*)(ws);
        ushort* RWp  = (ushort*)(ws + W_P);
        ushort* Ap   = (ushort*)(ws + 2*W_P);
        ushort* Rp   = (ushort*)(ws + 2*W_P + A_P);
        float4* part  = (float4*)(ws + 2*W_P + 2*A_P);
        float4* part2 = (float4*)(ws + 2*W_P + 2*A_P + PART);
        char*   tail  =          ws + 2*W_P + 2*A_P + 2*PART;
        float* klrow    = (float*)(tail);

        pack_all_kernel<<<dim3(532, NT), 256, 0, stream>>>(
            x, w, rx, rw, (uint4*)Ap, (uint4*)Wp, (uint4*)Rp, (uint4*)RWp);

        gemm_lse_swz<<<dim3(2000), 512, 0, stream>>>(Ap, Wp, Rp, RWp, part, part2);

        row_tail_kernel<<<BT, 256, 0, stream>>>(part, part2, rx, rw, klrow);
        final_kernel<<<1, 256, 0, stream>>>(amask, rewards, klrow, out);
    } else {
        // ---- fallback: round-1 path (ws too small for packed weights) ----
        const size_t PART_FB = (size_t)BT * NBLK_FB * 16;
        float4* part     = (float4*)ws;
        int*    token    = (int*)  (ws + PART_FB);
        float*  tok_logp = (float*)(ws + PART_FB + 8192);
        float*  gathered = (float*)(ws + PART_FB + 16384);
        float*  klrow    = (float*)(ws + PART_FB + 24576);

        dim3 g(BT / TM, NBLK_FB), blk(256);
        gemm_lse_fallback<<<g, blk, 0, stream>>>(x, w, part, nullptr, nullptr);
        reduce_policy_kernel<<<BT, 256, 0, stream>>>(part, token, tok_logp, NBLK_FB);
        gemm_lse_fallback<<<g, blk, 0, stream>>>(rx, rw, part, token, gathered);
        reduce_ref_kernel<<<BT, 256, 0, stream>>>(part, tok_logp, gathered, klrow, NBLK_FB);
        final_kernel<<<1, 256, 0, stream>>>(amask, rewards, klrow, out);
    }
}

// Round 4
// 1097.552 us; speedup vs baseline: 1.1836x; 1.0339x over previous
//
#include <hip/hip_runtime.h>
#include <hip/hip_bf16.h>
#include <math.h>

// Problem constants (fixed by the reference: H=2048, V=32000, B=8, T=256, G=4).
#define H_DIM 2048
#define V_DIM 32000
#define BT    2048            // B*T rows
#define BETA  0.1f
#define EPSR  1e-4f

// ---- fast-path GEMM geometry: 256x256 tile, BK=64, 8 waves (2M x 4N) ----
#define NT    32              // K tiles of 64 (H/64)
#define NBLK2 125             // V / 256
// ---- fallback geometry (round-1 kernel, unchanged) ----
#define TM 128
#define TN 128
#define TK 32
#define NBLK_FB 250

typedef __attribute__((ext_vector_type(8))) short bf16x8;   // 8 bf16 = 4 VGPRs
typedef __attribute__((ext_vector_type(4))) float f32x4;

// ---------------- helpers ----------------

// Pack two fp32 -> bf16x2 (round-half-up via +0x8000, take high 16 bits each).
__device__ __forceinline__ unsigned pack_bf16x2(float a, float b) {
    unsigned ua = __float_as_uint(a) + 0x8000u;
    unsigned ub = __float_as_uint(b) + 0x8000u;
    return __builtin_amdgcn_perm(ub, ua, 0x07060302u);
}

__device__ __forceinline__ void merge_ms(float& m, float& s, float m2, float s2) {
    float nm = fmaxf(m, m2);
    s = s * __expf(m - nm) + s2 * __expf(m2 - nm);
    m = nm;
}

// Async global->LDS, 16 B per lane. LDS dest = wave-uniform base + lane*16.
__device__ __forceinline__ void gl_lds16(const void* g, void* l) {
    __builtin_amdgcn_global_load_lds(
        (const __attribute__((address_space(1))) void*)g,
        (__attribute__((address_space(3))) void*)l, 16, 0, 0);
}

// ---------------- linear pack: fp32 [R,2048] -> bf16 slabs per (256-row, 64-K) tile --------
// Slab (rt,kt) is 32 KB: chunk (kk*256+row) holds src[rt*256+row][kt*64+kk*8..+8] as 8 bf16.
// This block design reads FULLY LINEAR global memory (16 rows x 8KB = 128KB contiguous per
// block), converts to bf16 in LDS (row stride 2056 bf16: +16B pad so the b128 readout hits
// the 8-start-group LDS floor, no serialization beyond it), then writes 16B chunks in 256B
// contiguous segments. Reads (2/3 of traffic) are at copy-peak pattern.
// blockIdx.x spans {x:128, w:2000, rx:128, rw:2000} 16-row groups.
#define PROWS 16
__global__ __launch_bounds__(256) void pack_lin_kernel(
    const float* __restrict__ x,  const float* __restrict__ w,
    const float* __restrict__ rx, const float* __restrict__ rw,
    uint4* __restrict__ Ap, uint4* __restrict__ Wp,
    uint4* __restrict__ Rp, uint4* __restrict__ RWp)
{
    __shared__ __align__(16) ushort tile[PROWS][2056];   // 65,792 B -> 2 blocks/CU
    const int t  = threadIdx.x;
    const int bx = blockIdx.x;

    const float* src; uint4* dst; int rb;
    if (bx < 128)       { src = x;  dst = Ap;  rb = bx; }
    else if (bx < 2128) { src = w;  dst = Wp;  rb = bx - 128; }
    else if (bx < 2256) { src = rx; dst = Rp;  rb = bx - 2128; }
    else                { src = rw; dst = RWp; rb = bx - 2256; }

    const int r0    = rb * PROWS;          // first global row of this block
    const int rt    = r0 >> 8;             // slab row-tile (256-row units)
    const int rbase = r0 & 255;            // row offset within the slab

    // Fully linear read: 16 rows x 2048 floats = 8192 float4 = 128KB contiguous.
    const float4* s4 = (const float4*)(src + (size_t)r0 * H_DIM);
    #pragma unroll
    for (int i = 0; i < 32; i++) {
        int flat = i * 256 + t;                        // 0..8191
        int row  = flat >> 9;                          // 512 float4 per row
        int c4   = flat & 511;
        float4 v = s4[flat];
        uint2 b;
        b.x = pack_bf16x2(v.x, v.y);
        b.y = pack_bf16x2(v.z, v.w);
        *(uint2*)&tile[row][c4 * 4] = b;               // 8B store, 2-way bank alias = free
    }
    __syncthreads();

    // Write out: 4096 x 16B chunks; c = (kt<<7) | (kk<<4) | row -> row fastest for 256B
    // contiguous global segments per (kt,kk).
    #pragma unroll
    for (int i = 0; i < 16; i++) {
        int c   = i * 256 + t;                         // 0..4095
        int kt  = c >> 7, kk = (c >> 4) & 7, row = c & 15;
        uint4 v = *(const uint4*)&tile[row][kt * 64 + kk * 8];
        dst[(((size_t)rt * NT + kt) << 11) + kk * 256 + rbase + row] = v;
    }
}

// ---------------- 256^2 8-phase GEMM (XCD-swizzled, single-barrier phases) ----------------
// 2000 blocks, 1/CU. Work index l = (bid%8)*250 + bid/8; mb = l&7 fastest, so ~32
// co-resident blocks per XCD span ~4 consecutive (z,nb) B-panels (~4MB = L2): B staging is
// L2-served (proven R3: FETCH 1.06GB -> 0.42GB).
//
// Barrier structure (v4): barrier 1 is PURE LOAD-PUBLICATION and is only needed at the
// vmcnt(6) phases p4/p8. The other 6 phases keep only barrier 2 (the read-vs-overwrite
// fence). Safety argument per phase (read set vs next phase's stage target):
//   p1 rd buf0.A[F0-1] | p1 st buf1.Aht3   p2 st buf0.Blo (prev B sealed by p1 MFMA wait)
//   p2 rd buf0.A[F2-3] | p3 st buf0.Bhi    p4 st buf0.Aht2=F0-3 (p2's reads sealed @p2.bar)
//   p3 rd buf0.A[F4-5] | p5 st buf0.Aht3=F4-7 (p4's reads sealed @p4.bar)  ... etc.
// Every ds_read's value is consumed by an MFMA before that phase's barrier, so the
// compiler's dependence waits drain reads before the fence. No explicit lgkmcnt(0):
// values flow through C++ loads, the compiler emits fine-grained waits.

#define MF(a,b,c) __builtin_amdgcn_mfma_f32_16x16x32_bf16(a, b, c, 0, 0, 0)

#define LDA(dst, BUF, F, KS) \
    dst = *(const bf16x8*)(smem + (BUF)*65536 + (KS)*16384 + (F)*256 + aoff)
#define LDB(dst, BUF, CF, KS) \
    dst = *(const bf16x8*)(smem + (BUF)*65536 + (KS)*16384 + (CF)*256 + boff)

#define STAGE(SG, SHT, SBUF) do { \
    const char* s_ = ((SHT) < 2 ? Bbase : Abase) + ((size_t)(SG) << 15); \
    char* l_ = smem + (SBUF)*65536 + ((SHT) < 2 ? 32768 : 0); \
    gl_lds16(s_ + soff[SHT][0], l_ + soff[SHT][0]); \
    gl_lds16(s_ + soff[SHT][1], l_ + soff[SHT][1]); \
} while (0)

#define MFMA_PH(F0, A0, A1, A2, A3) do { \
    acc[F0][0]   = MF(A0, bfr[0][0], acc[F0][0]); \
    acc[F0][1]   = MF(A0, bfr[1][0], acc[F0][1]); \
    acc[F0][2]   = MF(A0, bfr[2][0], acc[F0][2]); \
    acc[F0][3]   = MF(A0, bfr[3][0], acc[F0][3]); \
    acc[F0+1][0] = MF(A2, bfr[0][0], acc[F0+1][0]); \
    acc[F0+1][1] = MF(A2, bfr[1][0], acc[F0+1][1]); \
    acc[F0+1][2] = MF(A2, bfr[2][0], acc[F0+1][2]); \
    acc[F0+1][3] = MF(A2, bfr[3][0], acc[F0+1][3]); \
    acc[F0][0]   = MF(A1, bfr[0][1], acc[F0][0]); \
    acc[F0][1]   = MF(A1, bfr[1][1], acc[F0][1]); \
    acc[F0][2]   = MF(A1, bfr[2][1], acc[F0][2]); \
    acc[F0][3]   = MF(A1, bfr[3][1], acc[F0][3]); \
    acc[F0+1][0] = MF(A3, bfr[0][1], acc[F0+1][0]); \
    acc[F0+1][1] = MF(A3, bfr[1][1], acc[F0+1][1]); \
    acc[F0+1][2] = MF(A3, bfr[2][1], acc[F0+1][2]); \
    acc[F0+1][3] = MF(A3, bfr[3][1], acc[F0+1][3]); \
} while (0)

// One phase. VM: vmcnt(6) + publication barrier (p4/p8 only). POSTB: after the MFMA
// cluster, reload the 8 B-frags from buffer PBUF for the NEXT 4 phases (that tile's B
// landed by this phase's vmcnt(6); first consumed next phase, so the compiler's wait
// drains them before next phase's barrier).
#define PHASE(BUF, F0, SG, SHT, SBUF, VM, POSTB, PBUF) do { \
    bf16x8 a0_, a1_, a2_, a3_; \
    LDA(a0_, BUF, F0, 0);   LDA(a1_, BUF, F0, 1); \
    LDA(a2_, BUF, F0+1, 0); LDA(a3_, BUF, F0+1, 1); \
    STAGE(SG, SHT, SBUF); \
    if (VM) { \
        asm volatile("s_waitcnt vmcnt(6)" ::: "memory"); \
        __builtin_amdgcn_s_barrier(); \
        asm volatile("" ::: "memory"); \
    } \
    __builtin_amdgcn_s_setprio(1); \
    MFMA_PH(F0, a0_, a1_, a2_, a3_); \
    __builtin_amdgcn_s_setprio(0); \
    if (POSTB) { \
        LDB(bfr[0][0], PBUF, 0, 0); LDB(bfr[0][1], PBUF, 0, 1); \
        LDB(bfr[1][0], PBUF, 1, 0); LDB(bfr[1][1], PBUF, 1, 1); \
        LDB(bfr[2][0], PBUF, 2, 0); LDB(bfr[2][1], PBUF, 2, 1); \
        LDB(bfr[3][0], PBUF, 3, 0); LDB(bfr[3][1], PBUF, 3, 1); \
    } \
    asm volatile("" ::: "memory"); \
    __builtin_amdgcn_s_barrier(); \
    asm volatile("" ::: "memory"); \
} while (0)

__global__ __launch_bounds__(512, 2) void gemm_lse_v4(
    const ushort* __restrict__ Ap, const ushort* __restrict__ Wp,
    const ushort* __restrict__ Rp, const ushort* __restrict__ RWp,
    float4* __restrict__ part, float4* __restrict__ part2)
{
    __shared__ __align__(16) char smem_raw[131072 + 12288];  // tiles | epilogue scratch
    char* smem = smem_raw;
    float* redM = (float*)(smem_raw + 131072);               // 256 rows x 4 wn-segments
    float* redS = (float*)(smem_raw + 131072 + 4096);
    int*   redC = (int*)  (smem_raw + 131072 + 8192);

    const int tid  = threadIdx.x;
    const int lane = tid & 63;
    const int wv   = tid >> 6;                          // 0..7
    const int wm   = wv >> 2, wn = wv & 3;              // 2 x 4 wave grid: 128x64 per wave
    const int q    = lane >> 4, cl = lane & 15;

    // XCD-chunked work mapping: bid%8 ~ XCD (dispatch round-robin heuristic; speed-only).
    const int bid = blockIdx.x;                         // 0..1999
    const int l   = (bid & 7) * 250 + (bid >> 3);       // bijective
    const int mb  = l & 7;                              // varies fastest: 8 blocks share panel
    const int pn  = l >> 3;                             // 0..249 = (z, nb) panel
    const int z   = pn >= 125 ? 1 : 0;
    const int nb  = z ? pn - 125 : pn;

    const char* Abase = (const char*)(z ? Rp  : Ap) + ((size_t)(mb * NT) << 15);
    const char* Bbase = (const char*)(z ? RWp : Wp) + ((size_t)(nb * NT) << 15);
    float4* pp = z ? part2 : part;

    // Fragment-read base offsets (within a 64 KB tile-buffer).
    const int aoff = q * 4096 + (wm * 128 + cl) * 16;
    const int boff = 32768 + q * 4096 + (wn * 64 + cl) * 16;

    // Staging offsets: chunk c = wv*2 + li covers (kk, row-group), 64 rows/lane.
    int soff[4][2];
    #pragma unroll
    for (int li = 0; li < 2; li++) {
        int c = wv * 2 + li;
        int kko = (((c >> 3) << 2) + ((c >> 1) & 3)) * 4096;
        int rg = c & 1;
        soff[0][li] = kko + (rg * 64 + lane) * 16;            // B rows 0..128
        soff[1][li] = kko + (128 + rg * 64 + lane) * 16;      // B rows 128..256
        soff[2][li] = kko + (rg * 128 + lane) * 16;           // A rows {0-64, 128-192}
        soff[3][li] = kko + (rg * 128 + 64 + lane) * 16;      // A rows {64-128, 192-256}
    }

    f32x4 acc[8][4];
    const f32x4 zero = {0.f, 0.f, 0.f, 0.f};
    #pragma unroll
    for (int i = 0; i < 8; i++)
        #pragma unroll
        for (int j = 0; j < 4; j++) acc[i][j] = zero;

    bf16x8 bfr[4][2];

    // Prologue: tile0 (4 HTs) -> buf0, tile1 (ht0..2) -> buf1; 14 loads, keep 6 in flight.
    // vmcnt(6) completes exactly tile0's 8 loads; barrier publishes.
    STAGE(0, 0, 0); STAGE(0, 1, 0); STAGE(0, 2, 0); STAGE(0, 3, 0);
    STAGE(1, 0, 1); STAGE(1, 1, 1); STAGE(1, 2, 1);
    asm volatile("s_waitcnt vmcnt(6)" ::: "memory");
    __builtin_amdgcn_s_barrier();
    asm volatile("" ::: "memory");
    // Initial B frags (tile 0, buf0); consumed at p1's MFMAs (compiler waits there).
    LDB(bfr[0][0], 0, 0, 0); LDB(bfr[0][1], 0, 0, 1);
    LDB(bfr[1][0], 0, 1, 0); LDB(bfr[1][1], 0, 1, 1);
    LDB(bfr[2][0], 0, 2, 0); LDB(bfr[2][1], 0, 2, 1);
    LDB(bfr[3][0], 0, 3, 0); LDB(bfr[3][1], 0, 3, 1);

    #pragma unroll 1
    for (int ii = 0; ii < 16; ii++) {
        int t1 = 2 * ii + 1;
        int t2 = 2 * ii + 2; if (t2 > NT - 1) t2 = NT - 1;  // tail: dummy (valid) stages,
        int t3 = 2 * ii + 3; if (t3 > NT - 1) t3 = NT - 1;  // keeps the vmcnt ledger exact
        PHASE(0, 0, t1, 3, 1, 0, 0, 0);
        PHASE(0, 2, t2, 0, 0, 0, 0, 0);
        PHASE(0, 4, t2, 1, 0, 0, 0, 0);
        PHASE(0, 6, t2, 2, 0, 1, 1, 1);   // vmcnt(6)+pub; postload B(t1) from buf1
        PHASE(1, 0, t2, 3, 0, 0, 0, 0);
        PHASE(1, 2, t3, 0, 1, 0, 0, 0);
        PHASE(1, 4, t3, 1, 1, 0, 0, 0);
        PHASE(1, 6, t3, 2, 1, 1, 1, 0);   // vmcnt(6)+pub; postload B(t2) from buf0
    }

    // ---- epilogue: per-row {max, argmax col, sumexp} over this block's 256 cols ----
    // C layout (m89): col = cf*16 + cl (+ wn*64), row = f*16 + q*4 + reg (+ wm*128).
    // Remaining in-flight dummy loads target the tile buffers (<128KB); scratch is above.
    #pragma unroll
    for (int f = 0; f < 8; f++) {
        #pragma unroll
        for (int r = 0; r < 4; r++) {
            float v0 = acc[f][0][r], v1 = acc[f][1][r], v2 = acc[f][2][r], v3 = acc[f][3][r];
            float m = v0; int cj = 0;
            if (v1 > m) { m = v1; cj = 1; }
            if (v2 > m) { m = v2; cj = 2; }
            if (v3 > m) { m = v3; cj = 3; }
            float s = __expf(v0 - m) + __expf(v1 - m) + __expf(v2 - m) + __expf(v3 - m);
            int cidx = wn * 64 + cj * 16 + cl;
            #pragma unroll
            for (int off = 1; off < 16; off <<= 1) {
                float m2 = __shfl_xor(m, off);
                float s2 = __shfl_xor(s, off);
                int   c2 = __shfl_xor(cidx, off);
                float nm = fmaxf(m, m2);
                s = s * __expf(m - nm) + s2 * __expf(m2 - nm);
                if (m2 > m || (m2 == m && c2 < cidx)) cidx = c2;   // first-occurrence ties
                m = nm;
            }
            int rloc = wm * 128 + f * 16 + q * 4 + r;
            if (cl == 0) { redM[rloc*4+wn] = m; redS[rloc*4+wn] = s; redC[rloc*4+wn] = cidx; }
        }
    }
    asm volatile("s_waitcnt lgkmcnt(0)" ::: "memory");   // seal scratch writes (cross-wave)
    __builtin_amdgcn_s_barrier();
    asm volatile("" ::: "memory");
    if (tid < 256) {
        float m = redM[tid*4+0], s = redS[tid*4+0];
        int   cc = redC[tid*4+0];
        #pragma unroll
        for (int i2 = 1; i2 < 4; i2++) {
            float m2 = redM[tid*4+i2], s2 = redS[tid*4+i2];
            int   c2 = redC[tid*4+i2];
            float nm = fmaxf(m, m2);
            s = s * __expf(m - nm) + s2 * __expf(m2 - nm);
            if (m2 > m) cc = c2;                 // ascending col order; ties keep lower col
            m = nm;
        }
        pp[(size_t)(mb * 256 + tid) * NBLK2 + nb] =
            make_float4(m, s, __int_as_float(nb * 256 + cc), 0.f);
    }
}

// ---------------- fused row tail: policy argmax/lse + exact dot + ref lse + KL ----------------
__global__ __launch_bounds__(256) void row_tail_kernel(
    const float4* __restrict__ part, const float4* __restrict__ part2,
    const float* __restrict__ rx, const float* __restrict__ rw,
    float* __restrict__ klrow)
{
    __shared__ float smM[4], smS[4]; __shared__ int smC[4];
    __shared__ float ss[4];
    __shared__ float sTokLogp; __shared__ int sTok;

    const int row = blockIdx.x, t = threadIdx.x;

    // ---- policy: max / argmax / sumexp over 125 partials ----
    float m = -3.0e38f, s = 0.f; int cc = 0x7fffffff;
    if (t < NBLK2) { float4 p = part[(size_t)row * NBLK2 + t]; m = p.x; s = p.y; cc = __float_as_int(p.z); }
    for (int off = 1; off < 64; off <<= 1) {
        float m2 = __shfl_xor(m, off);
        float s2 = __shfl_xor(s, off);
        int   c2 = __shfl_xor(cc, off);
        float nm = fmaxf(m, m2);
        s = s * __expf(m - nm) + s2 * __expf(m2 - nm);
        if (m2 > m || (m2 == m && c2 < cc)) cc = c2;
        m = nm;
    }
    if ((t & 63) == 0) { smM[t>>6] = m; smS[t>>6] = s; smC[t>>6] = cc; }
    __syncthreads();
    if (t == 0) {
        m = smM[0]; s = smS[0]; cc = smC[0];
        for (int i = 1; i < 4; i++) {
            float m2 = smM[i], s2 = smS[i]; int c2 = smC[i];
            float nm = fmaxf(m, m2);
            s = s * __expf(m - nm) + s2 * __expf(m2 - nm);
            if (m2 > m || (m2 == m && c2 < cc)) cc = c2;
            m = nm;
        }
        sTok = cc;
        sTokLogp = -__logf(s);    // token is argmax -> logit[token] == global max
    }
    __syncthreads();
    const int tok = sTok;

    // ---- exact fp32 dot: rx[row] . rw[tok] ----
    const float4* a = (const float4*)(rx + (size_t)row * H_DIM);
    const float4* b = (const float4*)(rw + (size_t)tok * H_DIM);
    float4 a0 = a[t*2], a1 = a[t*2+1], b0 = b[t*2], b1 = b[t*2+1];
    float d = a0.x*b0.x + a0.y*b0.y + a0.z*b0.z + a0.w*b0.w
            + a1.x*b1.x + a1.y*b1.y + a1.z*b1.z + a1.w*b1.w;
    for (int off = 1; off < 64; off <<= 1) d += __shfl_xor(d, off);
    if ((t & 63) == 0) ss[t >> 6] = d;

    // ---- ref: lse over 125 partials ----
    float mr = -3.0e38f, sr = 0.f;
    if (t < NBLK2) { float4 p = part2[(size_t)row * NBLK2 + t]; mr = p.x; sr = p.y; }
    for (int off = 1; off < 64; off <<= 1) {
        float m2 = __shfl_xor(mr, off), s2 = __shfl_xor(sr, off);
        merge_ms(mr, sr, m2, s2);
    }
    __syncthreads();           // seals ss; frees smM/smS for reuse
    if ((t & 63) == 0) { smM[t>>6] = mr; smS[t>>6] = sr; }
    __syncthreads();
    if (t == 0) {
        mr = smM[0]; sr = smS[0];
        for (int i = 1; i < 4; i++) merge_ms(mr, sr, smM[i], smS[i]);
        float lse = mr + __logf(sr);
        float g = ss[0] + ss[1] + ss[2] + ss[3];
        float dd = (g - lse) - sTokLogp;   // ref_tok_logp - tok_logp
        klrow[row] = __expf(dd) - dd - 1.0f;
    }
}

// ---------------- fallback GEMM (round-1, in-kernel convert + gather) ----------------
__global__ __launch_bounds__(256) void gemm_lse_fallback(
    const float* __restrict__ A, const float* __restrict__ Bw,
    float4* __restrict__ part, const int* __restrict__ token,
    float* __restrict__ gather_out)
{
    __shared__ char smem[TM*TK*2 + TN*TK*2];
    ushort* sA = (ushort*)smem;
    ushort* sB = (ushort*)(smem + TM*TK*2);
    float* redM   = (float*)smem;
    float* redS   = (float*)(smem + 1024);
    int*   redC   = (int*)  (smem + 2048);
    int*   tokloc = (int*)  (smem + 3072);

    const int tid  = threadIdx.x;
    const int lane = tid & 63;
    const int wv   = tid >> 6;
    const int wm   = wv >> 1, wn = wv & 1;
    const int q    = lane >> 4, cl = lane & 15;
    const int m0 = blockIdx.x * TM;
    const int n0 = blockIdx.y * TN;
    const int nb = blockIdx.y;

    const int srow = tid >> 1, sseg = tid & 1;
    const float4* gA = (const float4*)(A  + (size_t)(m0 + srow) * H_DIM) + sseg * 4;
    const float4* gB = (const float4*)(Bw + (size_t)(n0 + srow) * H_DIM) + sseg * 4;
    uint4* wA = (uint4*)sA + srow * 4 + sseg * 2;
    uint4* wB = (uint4*)sB + srow * 4 + sseg * 2;

    f32x4 acc[4][4];
    const f32x4 zero = {0.f, 0.f, 0.f, 0.f};
    #pragma unroll
    for (int i = 0; i < 4; i++)
        #pragma unroll
        for (int j = 0; j < 4; j++) acc[i][j] = zero;

    float4 ra0 = gA[0], ra1 = gA[1], ra2 = gA[2], ra3 = gA[3];
    float4 rb0 = gB[0], rb1 = gB[1], rb2 = gB[2], rb3 = gB[3];

    for (int kt = 0; kt < H_DIM; kt += TK) {
        wA[0] = make_uint4(pack_bf16x2(ra0.x,ra0.y), pack_bf16x2(ra0.z,ra0.w),
                           pack_bf16x2(ra1.x,ra1.y), pack_bf16x2(ra1.z,ra1.w));
        wA[1] = make_uint4(pack_bf16x2(ra2.x,ra2.y), pack_bf16x2(ra2.z,ra2.w),
                           pack_bf16x2(ra3.x,ra3.y), pack_bf16x2(ra3.z,ra3.w));
        wB[0] = make_uint4(pack_bf16x2(rb0.x,rb0.y), pack_bf16x2(rb0.z,rb0.w),
                           pack_bf16x2(rb1.x,rb1.y), pack_bf16x2(rb1.z,rb1.w));
        wB[1] = make_uint4(pack_bf16x2(rb2.x,rb2.y), pack_bf16x2(rb2.z,rb2.w),
                           pack_bf16x2(rb3.x,rb3.y), pack_bf16x2(rb3.z,rb3.w));
        __syncthreads();
        if (kt + TK < H_DIM) {
            int kq = (kt + TK) >> 2;
            ra0 = gA[kq]; ra1 = gA[kq+1]; ra2 = gA[kq+2]; ra3 = gA[kq+3];
            rb0 = gB[kq]; rb1 = gB[kq+1]; rb2 = gB[kq+2]; rb3 = gB[kq+3];
        }
        bf16x8 af[4], bfr[4];
        #pragma unroll
        for (int i = 0; i < 4; i++) {
            af[i]  = *(const bf16x8*)(sA + (wm*64 + i*16 + cl) * TK + q*8);
            bfr[i] = *(const bf16x8*)(sB + (wn*64 + i*16 + cl) * TK + q*8);
        }
        #pragma unroll
        for (int i = 0; i < 4; i++)
            #pragma unroll
            for (int j = 0; j < 4; j++)
                acc[i][j] = __builtin_amdgcn_mfma_f32_16x16x32_bf16(af[i], bfr[j], acc[i][j], 0, 0, 0);
        __syncthreads();
    }

    #pragma unroll
    for (int ti = 0; ti < 4; ti++) {
        #pragma unroll
        for (int r = 0; r < 4; r++) {
            float vals[4];
            #pragma unroll
            for (int j = 0; j < 4; j++) vals[j] = acc[ti][j][r];
            float m = vals[0]; int cj = 0;
            #pragma unroll
            for (int j = 1; j < 4; j++) if (vals[j] > m) { m = vals[j]; cj = j; }
            float s = 0.f;
            #pragma unroll
            for (int j = 0; j < 4; j++) s += __expf(vals[j] - m);
            int cidx = wn*64 + cj*16 + cl;
            #pragma unroll
            for (int off = 1; off < 16; off <<= 1) {
                float m2 = __shfl_xor(m, off);
                float s2 = __shfl_xor(s, off);
                int   c2 = __shfl_xor(cidx, off);
                float nm = fmaxf(m, m2);
                s = s * __expf(m - nm) + s2 * __expf(m2 - nm);
                if (m2 > m || (m2 == m && c2 < cidx)) cidx = c2;
                m = nm;
            }
            int rloc = wm*64 + ti*16 + q*4 + r;
            if (cl == 0) { redM[rloc*2+wn] = m; redS[rloc*2+wn] = s; redC[rloc*2+wn] = cidx; }
        }
    }
    __syncthreads();
    if (tid < TM) {
        float ma = redM[tid*2+0], mb = redM[tid*2+1];
        float sa = redS[tid*2+0], sb = redS[tid*2+1];
        int   ca = redC[tid*2+0], cb = redC[tid*2+1];
        float nm = fmaxf(ma, mb);
        float s  = sa * __expf(ma - nm) + sb * __expf(mb - nm);
        int   cc = (mb > ma || (mb == ma && cb < ca)) ? cb : ca;
        part[(size_t)(m0 + tid) * NBLK_FB + nb] = make_float4(nm, s, __int_as_float(n0 + cc), 0.f);
    }

    if (token != nullptr) {
        if (tid < TM) tokloc[tid] = token[m0 + tid] - n0;
        __syncthreads();
        #pragma unroll
        for (int ti = 0; ti < 4; ti++) {
            #pragma unroll
            for (int r = 0; r < 4; r++) {
                int rloc = wm*64 + ti*16 + q*4 + r;
                int tl = tokloc[rloc];
                if (tl >= 0 && tl < TN && ((tl >> 6) & 1) == wn && (tl & 15) == cl) {
                    int tjm = (tl >> 4) & 3;
                    float v = acc[ti][0][r];
                    if (tjm == 1) v = acc[ti][1][r];
                    if (tjm == 2) v = acc[ti][2][r];
                    if (tjm == 3) v = acc[ti][3][r];
                    gather_out[m0 + rloc] = v;
                }
            }
        }
    }
}

// ---------------- fallback reductions ----------------

__global__ __launch_bounds__(256) void reduce_policy_kernel(
    const float4* __restrict__ part, int* __restrict__ token, float* __restrict__ tok_logp,
    int nblk)
{
    int row = blockIdx.x, t = threadIdx.x;
    float m = -3.0e38f, s = 0.f; int cc = 0x7fffffff;
    if (t < nblk) { float4 p = part[(size_t)row * nblk + t]; m = p.x; s = p.y; cc = __float_as_int(p.z); }
    for (int off = 1; off < 64; off <<= 1) {
        float m2 = __shfl_xor(m, off);
        float s2 = __shfl_xor(s, off);
        int   c2 = __shfl_xor(cc, off);
        float nm = fmaxf(m, m2);
        s = s * __expf(m - nm) + s2 * __expf(m2 - nm);
        if (m2 > m || (m2 == m && c2 < cc)) cc = c2;
        m = nm;
    }
    __shared__ float smM[4], smS[4]; __shared__ int smC[4];
    if ((t & 63) == 0) { smM[t>>6] = m; smS[t>>6] = s; smC[t>>6] = cc; }
    __syncthreads();
    if (t == 0) {
        m = smM[0]; s = smS[0]; cc = smC[0];
        for (int i = 1; i < 4; i++) {
            float m2 = smM[i], s2 = smS[i]; int c2 = smC[i];
            float nm = fmaxf(m, m2);
            s = s * __expf(m - nm) + s2 * __expf(m2 - nm);
            if (m2 > m || (m2 == m && c2 < cc)) cc = c2;
            m = nm;
        }
        token[row] = cc;
        tok_logp[row] = -__logf(s);
    }
}

__global__ __launch_bounds__(256) void dot_gather_kernel(
    const float* __restrict__ rx, const float* __restrict__ rw,
    const int* __restrict__ token, float* __restrict__ out)
{
    int row = blockIdx.x, t = threadIdx.x;
    const float4* a = (const float4*)(rx + (size_t)row * H_DIM);
    const float4* b = (const float4*)(rw + (size_t)token[row] * H_DIM);
    float4 a0 = a[t*2], a1 = a[t*2+1], b0 = b[t*2], b1 = b[t*2+1];
    float s = a0.x*b0.x + a0.y*b0.y + a0.z*b0.z + a0.w*b0.w
            + a1.x*b1.x + a1.y*b1.y + a1.z*b1.z + a1.w*b1.w;
    for (int off = 1; off < 64; off <<= 1) s += __shfl_xor(s, off);
    __shared__ float ss[4];
    if ((t & 63) == 0) ss[t >> 6] = s;
    __syncthreads();
    if (t == 0) out[row] = ss[0] + ss[1] + ss[2] + ss[3];
}

__global__ __launch_bounds__(256) void reduce_ref_kernel(
    const float4* __restrict__ part, const float* __restrict__ tok_logp,
    const float* __restrict__ gathered, float* __restrict__ klrow, int nblk)
{
    int row = blockIdx.x, t = threadIdx.x;
    float m = -3.0e38f, s = 0.f;
    if (t < nblk) { float4 p = part[(size_t)row * nblk + t]; m = p.x; s = p.y; }
    for (int off = 1; off < 64; off <<= 1) {
        float m2 = __shfl_xor(m, off), s2 = __shfl_xor(s, off);
        merge_ms(m, s, m2, s2);
    }
    __shared__ float smM[4], smS[4];
    if ((t & 63) == 0) { smM[t>>6] = m; smS[t>>6] = s; }
    __syncthreads();
    if (t == 0) {
        m = smM[0]; s = smS[0];
        for (int i = 1; i < 4; i++) merge_ms(m, s, smM[i], smS[i]);
        float lse = m + __logf(s);
        float d = (gathered[row] - lse) - tok_logp[row];
        klrow[row] = __expf(d) - d - 1.0f;
    }
}

__global__ __launch_bounds__(256) void final_kernel(
    const int* __restrict__ amask, const float* __restrict__ rewards,
    const float* __restrict__ klrow, float* __restrict__ out)
{
    int t = threadIdx.x;
    int b = t >> 5;
    int g = b >> 2;
    float r0 = rewards[g*4+0], r1 = rewards[g*4+1], r2 = rewards[g*4+2], r3 = rewards[g*4+3];
    float mean = 0.25f * (r0 + r1 + r2 + r3);
    float var = ((r0-mean)*(r0-mean) + (r1-mean)*(r1-mean) +
                 (r2-mean)*(r2-mean) + (r3-mean)*(r3-mean)) * (1.0f/3.0f);  // ddof=1
    float adv = (rewards[b] - mean) / (sqrtf(var) + EPSR);

    float ln = 0.f, ms = 0.f, kb = 0.f, mb = 0.f;
    for (int i = 0; i < 8; i++) {
        int row = t*8 + i;
        float mk = (float)amask[row];
        float kl = klrow[row];
        ln += (adv - BETA * kl) * mk;
        ms += mk;
        kb += kl * mk;
        mb += mk;
    }
    __shared__ float sLN[256], sMS[256], sKB[256], sMB[256], sKLb[8];
    sLN[t] = ln; sMS[t] = ms; sKB[t] = kb; sMB[t] = mb;
    __syncthreads();
    if (t < 8) {
        float skb = 0.f, smb = 0.f;
        for (int i = 0; i < 32; i++) { skb += sKB[t*32+i]; smb += sMB[t*32+i]; }
        sKLb[t] = skb / smb;
    }
    __syncthreads();
    if (t == 0) {
        float lnt = 0.f, mst = 0.f;
        for (int i = 0; i < 256; i++) { lnt += sLN[i]; mst += sMS[i]; }
        float mkl = 0.f;
        for (int i = 0; i < 8; i++) mkl += sKLb[i];
        out[0] = -lnt / mst;
        out[1] = mkl * 0.125f;
    }
}

// ---------------- launch ----------------

extern "C" void kernel_launch(void* const* d_in, const int* in_sizes, int n_in,
                              void* d_out, int out_size, void* d_ws, size_t ws_size,
                              hipStream_t stream)
{
    const float* x       = (const float*)d_in[0];
    const float* w       = (const float*)d_in[1];
    const int*   amask   = (const int*)  d_in[2];
    const float* rewards = (const float*)d_in[3];
    const float* rx      = (const float*)d_in[4];
    const float* rw      = (const float*)d_in[5];
    float* out = (float*)d_out;
    char* ws = (char*)d_ws;

    const size_t W_P  = (size_t)V_DIM * H_DIM * 2;   // 131,072,000 bf16 bytes
    const size_t A_P  = (size_t)BT * H_DIM * 2;      //   8,388,608
    const size_t PART = (size_t)BT * NBLK2 * 16;     //   4,096,000
    const size_t NEED = 2*W_P + 2*A_P + 2*PART + 4*8192;

    if (ws_size >= NEED) {
        // ---- fast path: linear pack, XCD-swizzled single-barrier 8-phase GEMM, fused tail ----
        ushort* Wp   = (ushort*)(ws);
        ushort* RWp  = (ushort*)(ws + W_P);
        ushort* Ap   = (ushort*)(ws + 2*W_P);
        ushort* Rp   = (ushort*)(ws + 2*W_P + A_P);
        float4* part  = (float4*)(ws + 2*W_P + 2*A_P);
        float4* part2 = (float4*)(ws + 2*W_P + 2*A_P + PART);
        char*   tail  =          ws + 2*W_P + 2*A_P + 2*PART;
        float* klrow    = (float*)(tail);

        pack_lin_kernel<<<dim3(4256), 256, 0, stream>>>(
            x, w, rx, rw, (uint4*)Ap, (uint4*)Wp, (uint4*)Rp, (uint4*)RWp);

        gemm_lse_v4<<<dim3(2000), 512, 0, stream>>>(Ap, Wp, Rp, RWp, part, part2);

        row_tail_kernel<<<BT, 256, 0, stream>>>(part, part2, rx, rw, klrow);
        final_kernel<<<1, 256, 0, stream>>>(amask, rewards, klrow, out);
    } else {
        // ---- fallback: round-1 path (ws too small for packed weights) ----
        const size_t PART_FB = (size_t)BT * NBLK_FB * 16;
        float4* part     = (float4*)ws;
        int*    token    = (int*)  (ws + PART_FB);
        float*  tok_logp = (float*)(ws + PART_FB + 8192);
        float*  gathered = (float*)(ws + PART_FB + 16384);
        float*  klrow    = (float*)(ws + PART_FB + 24576);

        dim3 g(BT / TM, NBLK_FB), blk(256);
        gemm_lse_fallback<<<g, blk, 0, stream>>>(x, w, part, nullptr, nullptr);
        reduce_policy_kernel<<<BT, 256, 0, stream>>>(part, token, tok_logp, NBLK_FB);
        gemm_lse_fallback<<<g, blk, 0, stream>>>(rx, rw, part, token, gathered);
        reduce_ref_kernel<<<BT, 256, 0, stream>>>(part, tok_logp, gathered, klrow, NBLK_FB);
        final_kernel<<<1, 256, 0, stream>>>(amask, rewards, klrow, out);
    }
}

// Round 5
// 1085.150 us; speedup vs baseline: 1.1971x; 1.0114x over previous
//
#include <hip/hip_runtime.h>
#include <hip/hip_bf16.h>
#include <math.h>

// Problem constants (fixed by the reference: H=2048, V=32000, B=8, T=256, G=4).
#define H_DIM 2048
#define V_DIM 32000
#define BT    2048            // B*T rows
#define BETA  0.1f
#define EPSR  1e-4f

// ---- fast-path GEMM geometry: 256x256 tile, BK=64, 8 waves (2M x 4N) ----
#define NT    32              // K tiles of 64 (H/64)
#define NBLK2 125             // V / 256
// ---- fallback geometry (round-1 kernel, unchanged) ----
#define TM 128
#define TN 128
#define TK 32
#define NBLK_FB 250

typedef __attribute__((ext_vector_type(8))) short bf16x8;   // 8 bf16 = 4 VGPRs
typedef __attribute__((ext_vector_type(4))) float f32x4;

// ---------------- helpers ----------------

// Pack two fp32 -> bf16x2 (round-half-up via +0x8000, take high 16 bits each).
__device__ __forceinline__ unsigned pack_bf16x2(float a, float b) {
    unsigned ua = __float_as_uint(a) + 0x8000u;
    unsigned ub = __float_as_uint(b) + 0x8000u;
    return __builtin_amdgcn_perm(ub, ua, 0x07060302u);
}

__device__ __forceinline__ void merge_ms(float& m, float& s, float m2, float s2) {
    float nm = fmaxf(m, m2);
    s = s * __expf(m - nm) + s2 * __expf(m2 - nm);
    m = nm;
}

// Async global->LDS, 16 B per lane. LDS dest = wave-uniform base + lane*16.
__device__ __forceinline__ void gl_lds16(const void* g, void* l) {
    __builtin_amdgcn_global_load_lds(
        (const __attribute__((address_space(1))) void*)g,
        (__attribute__((address_space(3))) void*)l, 16, 0, 0);
}

// ---------------- linear pack: fp32 [R,2048] -> bf16 slabs per (256-row, 64-K) tile --------
// Slab (rt,kt) is 32 KB: chunk (kk*256+row) holds src[rt*256+row][kt*64+kk*8..+8] as 8 bf16.
// v5: 512 threads/block, 16 loads/thread (was 256t/32 loads) -> 16 waves/CU at 2 blocks/CU,
// deeper memory parallelism. Reads fully linear (16 rows x 8KB contiguous per block);
// LDS row-per-iteration conversion; writes in 256B contiguous segments per (kt,kk).
// blockIdx.x spans {x:128, w:2000, rx:128, rw:2000} 16-row groups.
#define PROWS 16
__global__ __launch_bounds__(512) void pack_lin_kernel(
    const float* __restrict__ x,  const float* __restrict__ w,
    const float* __restrict__ rx, const float* __restrict__ rw,
    uint4* __restrict__ Ap, uint4* __restrict__ Wp,
    uint4* __restrict__ Rp, uint4* __restrict__ RWp)
{
    __shared__ __align__(16) ushort tile[PROWS][2056];   // 65,792 B -> 2 blocks/CU
    const int t  = threadIdx.x;                          // 0..511
    const int bx = blockIdx.x;

    const float* src; uint4* dst; int rb;
    if (bx < 128)       { src = x;  dst = Ap;  rb = bx; }
    else if (bx < 2128) { src = w;  dst = Wp;  rb = bx - 128; }
    else if (bx < 2256) { src = rx; dst = Rp;  rb = bx - 2128; }
    else                { src = rw; dst = RWp; rb = bx - 2256; }

    const int r0    = rb * PROWS;          // first global row of this block
    const int rt    = r0 >> 8;             // slab row-tile (256-row units)
    const int rbase = r0 & 255;            // row offset within the slab

    // Fully linear read: iteration i covers exactly row i (512 float4 = one 8KB row).
    const float4* s4 = (const float4*)(src + (size_t)r0 * H_DIM);
    #pragma unroll
    for (int i = 0; i < PROWS; i++) {
        float4 v = s4[i * 512 + t];
        uint2 b;
        b.x = pack_bf16x2(v.x, v.y);
        b.y = pack_bf16x2(v.z, v.w);
        *(uint2*)&tile[i][t * 4] = b;                  // 8B store
    }
    __syncthreads();

    // Write out: 4096 x 16B chunks; c = (kt<<7)|(kk<<4)|row -> row fastest for 256B
    // contiguous global segments per (kt,kk). kt wave-uniform (64 | 128).
    #pragma unroll
    for (int i = 0; i < 8; i++) {
        int c   = i * 512 + t;                         // 0..4095
        int kt  = c >> 7, kk = (c >> 4) & 7, row = c & 15;
        uint4 v = *(const uint4*)&tile[row][kt * 64 + kk * 8];
        dst[(((size_t)rt * NT + kt) << 11) + kk * 256 + rbase + row] = v;
    }
}

// ---------------- 256^2 8-phase GEMM (XCD-swizzled, single-barrier phases) ----------------
// v5: one dispatch per model (policy / ref), grid 1000. Work index l = (bid%8)*125 + bid/8;
// mb = l&7 fastest, nb = l>>3 in [0,125): 8 co-resident same-XCD blocks share one B-panel
// (L2-served; proven R3: FETCH 1.06GB -> 0.42GB). Splitting by z keeps only one 131MB
// weight matrix active per dispatch (LLC-resident) and halves per-dispatch duration for
// rocprof top-k visibility.
//
// Barrier structure (R4, verified): one barrier per phase; vmcnt(6) + publication barrier
// only at p4/p8. POSTB B-frag reloads run post-MFMA for the next 4 phases.

#define MF(a,b,c) __builtin_amdgcn_mfma_f32_16x16x32_bf16(a, b, c, 0, 0, 0)

#define LDA(dst, BUF, F, KS) \
    dst = *(const bf16x8*)(smem + (BUF)*65536 + (KS)*16384 + (F)*256 + aoff)
#define LDB(dst, BUF, CF, KS) \
    dst = *(const bf16x8*)(smem + (BUF)*65536 + (KS)*16384 + (CF)*256 + boff)

#define STAGE(SG, SHT, SBUF) do { \
    const char* s_ = ((SHT) < 2 ? Bbase : Abase) + ((size_t)(SG) << 15); \
    char* l_ = smem + (SBUF)*65536 + ((SHT) < 2 ? 32768 : 0); \
    gl_lds16(s_ + soff[SHT][0], l_ + soff[SHT][0]); \
    gl_lds16(s_ + soff[SHT][1], l_ + soff[SHT][1]); \
} while (0)

#define MFMA_PH(F0, A0, A1, A2, A3) do { \
    acc[F0][0]   = MF(A0, bfr[0][0], acc[F0][0]); \
    acc[F0][1]   = MF(A0, bfr[1][0], acc[F0][1]); \
    acc[F0][2]   = MF(A0, bfr[2][0], acc[F0][2]); \
    acc[F0][3]   = MF(A0, bfr[3][0], acc[F0][3]); \
    acc[F0+1][0] = MF(A2, bfr[0][0], acc[F0+1][0]); \
    acc[F0+1][1] = MF(A2, bfr[1][0], acc[F0+1][1]); \
    acc[F0+1][2] = MF(A2, bfr[2][0], acc[F0+1][2]); \
    acc[F0+1][3] = MF(A2, bfr[3][0], acc[F0+1][3]); \
    acc[F0][0]   = MF(A1, bfr[0][1], acc[F0][0]); \
    acc[F0][1]   = MF(A1, bfr[1][1], acc[F0][1]); \
    acc[F0][2]   = MF(A1, bfr[2][1], acc[F0][2]); \
    acc[F0][3]   = MF(A1, bfr[3][1], acc[F0][3]); \
    acc[F0+1][0] = MF(A3, bfr[0][1], acc[F0+1][0]); \
    acc[F0+1][1] = MF(A3, bfr[1][1], acc[F0+1][1]); \
    acc[F0+1][2] = MF(A3, bfr[2][1], acc[F0+1][2]); \
    acc[F0+1][3] = MF(A3, bfr[3][1], acc[F0+1][3]); \
} while (0)

#define PHASE(BUF, F0, SG, SHT, SBUF, VM, POSTB, PBUF) do { \
    bf16x8 a0_, a1_, a2_, a3_; \
    LDA(a0_, BUF, F0, 0);   LDA(a1_, BUF, F0, 1); \
    LDA(a2_, BUF, F0+1, 0); LDA(a3_, BUF, F0+1, 1); \
    STAGE(SG, SHT, SBUF); \
    if (VM) { \
        asm volatile("s_waitcnt vmcnt(6)" ::: "memory"); \
        __builtin_amdgcn_s_barrier(); \
        asm volatile("" ::: "memory"); \
    } \
    __builtin_amdgcn_s_setprio(1); \
    MFMA_PH(F0, a0_, a1_, a2_, a3_); \
    __builtin_amdgcn_s_setprio(0); \
    if (POSTB) { \
        LDB(bfr[0][0], PBUF, 0, 0); LDB(bfr[0][1], PBUF, 0, 1); \
        LDB(bfr[1][0], PBUF, 1, 0); LDB(bfr[1][1], PBUF, 1, 1); \
        LDB(bfr[2][0], PBUF, 2, 0); LDB(bfr[2][1], PBUF, 2, 1); \
        LDB(bfr[3][0], PBUF, 3, 0); LDB(bfr[3][1], PBUF, 3, 1); \
    } \
    asm volatile("" ::: "memory"); \
    __builtin_amdgcn_s_barrier(); \
    asm volatile("" ::: "memory"); \
} while (0)

__global__ __launch_bounds__(512, 2) void gemm_lse_v4(
    const ushort* __restrict__ Apk, const ushort* __restrict__ Bpk,
    float4* __restrict__ pp)
{
    __shared__ __align__(16) char smem_raw[131072 + 12288];  // tiles | epilogue scratch
    char* smem = smem_raw;
    float* redM = (float*)(smem_raw + 131072);               // 256 rows x 4 wn-segments
    float* redS = (float*)(smem_raw + 131072 + 4096);
    int*   redC = (int*)  (smem_raw + 131072 + 8192);

    const int tid  = threadIdx.x;
    const int lane = tid & 63;
    const int wv   = tid >> 6;                          // 0..7
    const int wm   = wv >> 2, wn = wv & 3;              // 2 x 4 wave grid: 128x64 per wave
    const int q    = lane >> 4, cl = lane & 15;

    // XCD-chunked work mapping: bid%8 ~ XCD (dispatch round-robin heuristic; speed-only).
    const int bid = blockIdx.x;                         // 0..999
    const int l   = (bid & 7) * 125 + (bid >> 3);       // bijective
    const int mb  = l & 7;                              // varies fastest: 8 blocks share panel
    const int nb  = l >> 3;                             // 0..124 = B-panel

    const char* Abase = (const char*)Apk + ((size_t)(mb * NT) << 15);
    const char* Bbase = (const char*)Bpk + ((size_t)(nb * NT) << 15);

    // Fragment-read base offsets (within a 64 KB tile-buffer).
    const int aoff = q * 4096 + (wm * 128 + cl) * 16;
    const int boff = 32768 + q * 4096 + (wn * 64 + cl) * 16;

    // Staging offsets: chunk c = wv*2 + li covers (kk, row-group), 64 rows/lane.
    int soff[4][2];
    #pragma unroll
    for (int li = 0; li < 2; li++) {
        int c = wv * 2 + li;
        int kko = (((c >> 3) << 2) + ((c >> 1) & 3)) * 4096;
        int rg = c & 1;
        soff[0][li] = kko + (rg * 64 + lane) * 16;            // B rows 0..128
        soff[1][li] = kko + (128 + rg * 64 + lane) * 16;      // B rows 128..256
        soff[2][li] = kko + (rg * 128 + lane) * 16;           // A rows {0-64, 128-192}
        soff[3][li] = kko + (rg * 128 + 64 + lane) * 16;      // A rows {64-128, 192-256}
    }

    f32x4 acc[8][4];
    const f32x4 zero = {0.f, 0.f, 0.f, 0.f};
    #pragma unroll
    for (int i = 0; i < 8; i++)
        #pragma unroll
        for (int j = 0; j < 4; j++) acc[i][j] = zero;

    bf16x8 bfr[4][2];

    // Prologue: tile0 (4 HTs) -> buf0, tile1 (ht0..2) -> buf1; 14 loads, keep 6 in flight.
    STAGE(0, 0, 0); STAGE(0, 1, 0); STAGE(0, 2, 0); STAGE(0, 3, 0);
    STAGE(1, 0, 1); STAGE(1, 1, 1); STAGE(1, 2, 1);
    asm volatile("s_waitcnt vmcnt(6)" ::: "memory");
    __builtin_amdgcn_s_barrier();
    asm volatile("" ::: "memory");
    // Initial B frags (tile 0, buf0); consumed at p1's MFMAs (compiler waits there).
    LDB(bfr[0][0], 0, 0, 0); LDB(bfr[0][1], 0, 0, 1);
    LDB(bfr[1][0], 0, 1, 0); LDB(bfr[1][1], 0, 1, 1);
    LDB(bfr[2][0], 0, 2, 0); LDB(bfr[2][1], 0, 2, 1);
    LDB(bfr[3][0], 0, 3, 0); LDB(bfr[3][1], 0, 3, 1);

    #pragma unroll 1
    for (int ii = 0; ii < 16; ii++) {
        int t1 = 2 * ii + 1;
        int t2 = 2 * ii + 2; if (t2 > NT - 1) t2 = NT - 1;  // tail: dummy (valid) stages,
        int t3 = 2 * ii + 3; if (t3 > NT - 1) t3 = NT - 1;  // keeps the vmcnt ledger exact
        PHASE(0, 0, t1, 3, 1, 0, 0, 0);
        PHASE(0, 2, t2, 0, 0, 0, 0, 0);
        PHASE(0, 4, t2, 1, 0, 0, 0, 0);
        PHASE(0, 6, t2, 2, 0, 1, 1, 1);   // vmcnt(6)+pub; postload B(t1) from buf1
        PHASE(1, 0, t2, 3, 0, 0, 0, 0);
        PHASE(1, 2, t3, 0, 1, 0, 0, 0);
        PHASE(1, 4, t3, 1, 1, 0, 0, 0);
        PHASE(1, 6, t3, 2, 1, 1, 1, 0);   // vmcnt(6)+pub; postload B(t2) from buf0
    }

    // ---- epilogue: per-row {max, argmax col, sumexp} over this block's 256 cols ----
    // C layout (m89): col = cf*16 + cl (+ wn*64), row = f*16 + q*4 + reg (+ wm*128).
    // Remaining in-flight dummy loads target the tile buffers (<128KB); scratch is above.
    #pragma unroll
    for (int f = 0; f < 8; f++) {
        #pragma unroll
        for (int r = 0; r < 4; r++) {
            float v0 = acc[f][0][r], v1 = acc[f][1][r], v2 = acc[f][2][r], v3 = acc[f][3][r];
            float m = v0; int cj = 0;
            if (v1 > m) { m = v1; cj = 1; }
            if (v2 > m) { m = v2; cj = 2; }
            if (v3 > m) { m = v3; cj = 3; }
            float s = __expf(v0 - m) + __expf(v1 - m) + __expf(v2 - m) + __expf(v3 - m);
            int cidx = wn * 64 + cj * 16 + cl;
            #pragma unroll
            for (int off = 1; off < 16; off <<= 1) {
                float m2 = __shfl_xor(m, off);
                float s2 = __shfl_xor(s, off);
                int   c2 = __shfl_xor(cidx, off);
                float nm = fmaxf(m, m2);
                s = s * __expf(m - nm) + s2 * __expf(m2 - nm);
                if (m2 > m || (m2 == m && c2 < cidx)) cidx = c2;   // first-occurrence ties
                m = nm;
            }
            int rloc = wm * 128 + f * 16 + q * 4 + r;
            if (cl == 0) { redM[rloc*4+wn] = m; redS[rloc*4+wn] = s; redC[rloc*4+wn] = cidx; }
        }
    }
    asm volatile("s_waitcnt lgkmcnt(0)" ::: "memory");   // seal scratch writes (cross-wave)
    __builtin_amdgcn_s_barrier();
    asm volatile("" ::: "memory");
    if (tid < 256) {
        float m = redM[tid*4+0], s = redS[tid*4+0];
        int   cc = redC[tid*4+0];
        #pragma unroll
        for (int i2 = 1; i2 < 4; i2++) {
            float m2 = redM[tid*4+i2], s2 = redS[tid*4+i2];
            int   c2 = redC[tid*4+i2];
            float nm = fmaxf(m, m2);
            s = s * __expf(m - nm) + s2 * __expf(m2 - nm);
            if (m2 > m) cc = c2;                 // ascending col order; ties keep lower col
            m = nm;
        }
        pp[(size_t)(mb * 256 + tid) * NBLK2 + nb] =
            make_float4(m, s, __int_as_float(nb * 256 + cc), 0.f);
    }
}

// ---------------- fused row tail: policy argmax/lse + exact dot + ref lse + KL ----------------
__global__ __launch_bounds__(256) void row_tail_kernel(
    const float4* __restrict__ part, const float4* __restrict__ part2,
    const float* __restrict__ rx, const float* __restrict__ rw,
    float* __restrict__ klrow)
{
    __shared__ float smM[4], smS[4]; __shared__ int smC[4];
    __shared__ float ss[4];
    __shared__ float sTokLogp; __shared__ int sTok;

    const int row = blockIdx.x, t = threadIdx.x;

    // ---- policy: max / argmax / sumexp over 125 partials ----
    float m = -3.0e38f, s = 0.f; int cc = 0x7fffffff;
    if (t < NBLK2) { float4 p = part[(size_t)row * NBLK2 + t]; m = p.x; s = p.y; cc = __float_as_int(p.z); }
    for (int off = 1; off < 64; off <<= 1) {
        float m2 = __shfl_xor(m, off);
        float s2 = __shfl_xor(s, off);
        int   c2 = __shfl_xor(cc, off);
        float nm = fmaxf(m, m2);
        s = s * __expf(m - nm) + s2 * __expf(m2 - nm);
        if (m2 > m || (m2 == m && c2 < cc)) cc = c2;
        m = nm;
    }
    if ((t & 63) == 0) { smM[t>>6] = m; smS[t>>6] = s; smC[t>>6] = cc; }
    __syncthreads();
    if (t == 0) {
        m = smM[0]; s = smS[0]; cc = smC[0];
        for (int i = 1; i < 4; i++) {
            float m2 = smM[i], s2 = smS[i]; int c2 = smC[i];
            float nm = fmaxf(m, m2);
            s = s * __expf(m - nm) + s2 * __expf(m2 - nm);
            if (m2 > m || (m2 == m && c2 < cc)) cc = c2;
            m = nm;
        }
        sTok = cc;
        sTokLogp = -__logf(s);    // token is argmax -> logit[token] == global max
    }
    __syncthreads();
    const int tok = sTok;

    // ---- exact fp32 dot: rx[row] . rw[tok] ----
    const float4* a = (const float4*)(rx + (size_t)row * H_DIM);
    const float4* b = (const float4*)(rw + (size_t)tok * H_DIM);
    float4 a0 = a[t*2], a1 = a[t*2+1], b0 = b[t*2], b1 = b[t*2+1];
    float d = a0.x*b0.x + a0.y*b0.y + a0.z*b0.z + a0.w*b0.w
            + a1.x*b1.x + a1.y*b1.y + a1.z*b1.z + a1.w*b1.w;
    for (int off = 1; off < 64; off <<= 1) d += __shfl_xor(d, off);
    if ((t & 63) == 0) ss[t >> 6] = d;

    // ---- ref: lse over 125 partials ----
    float mr = -3.0e38f, sr = 0.f;
    if (t < NBLK2) { float4 p = part2[(size_t)row * NBLK2 + t]; mr = p.x; sr = p.y; }
    for (int off = 1; off < 64; off <<= 1) {
        float m2 = __shfl_xor(mr, off), s2 = __shfl_xor(sr, off);
        merge_ms(mr, sr, m2, s2);
    }
    __syncthreads();           // seals ss; frees smM/smS for reuse
    if ((t & 63) == 0) { smM[t>>6] = mr; smS[t>>6] = sr; }
    __syncthreads();
    if (t == 0) {
        mr = smM[0]; sr = smS[0];
        for (int i = 1; i < 4; i++) merge_ms(mr, sr, smM[i], smS[i]);
        float lse = mr + __logf(sr);
        float g = ss[0] + ss[1] + ss[2] + ss[3];
        float dd = (g - lse) - sTokLogp;   // ref_tok_logp - tok_logp
        klrow[row] = __expf(dd) - dd - 1.0f;
    }
}

// ---------------- fallback GEMM (round-1, in-kernel convert + gather) ----------------
__global__ __launch_bounds__(256) void gemm_lse_fallback(
    const float* __restrict__ A, const float* __restrict__ Bw,
    float4* __restrict__ part, const int* __restrict__ token,
    float* __restrict__ gather_out)
{
    __shared__ char smem[TM*TK*2 + TN*TK*2];
    ushort* sA = (ushort*)smem;
    ushort* sB = (ushort*)(smem + TM*TK*2);
    float* redM   = (float*)smem;
    float* redS   = (float*)(smem + 1024);
    int*   redC   = (int*)  (smem + 2048);
    int*   tokloc = (int*)  (smem + 3072);

    const int tid  = threadIdx.x;
    const int lane = tid & 63;
    const int wv   = tid >> 6;
    const int wm   = wv >> 1, wn = wv & 1;
    const int q    = lane >> 4, cl = lane & 15;
    const int m0 = blockIdx.x * TM;
    const int n0 = blockIdx.y * TN;
    const int nb = blockIdx.y;

    const int srow = tid >> 1, sseg = tid & 1;
    const float4* gA = (const float4*)(A  + (size_t)(m0 + srow) * H_DIM) + sseg * 4;
    const float4* gB = (const float4*)(Bw + (size_t)(n0 + srow) * H_DIM) + sseg * 4;
    uint4* wA = (uint4*)sA + srow * 4 + sseg * 2;
    uint4* wB = (uint4*)sB + srow * 4 + sseg * 2;

    f32x4 acc[4][4];
    const f32x4 zero = {0.f, 0.f, 0.f, 0.f};
    #pragma unroll
    for (int i = 0; i < 4; i++)
        #pragma unroll
        for (int j = 0; j < 4; j++) acc[i][j] = zero;

    float4 ra0 = gA[0], ra1 = gA[1], ra2 = gA[2], ra3 = gA[3];
    float4 rb0 = gB[0], rb1 = gB[1], rb2 = gB[2], rb3 = gB[3];

    for (int kt = 0; kt < H_DIM; kt += TK) {
        wA[0] = make_uint4(pack_bf16x2(ra0.x,ra0.y), pack_bf16x2(ra0.z,ra0.w),
                           pack_bf16x2(ra1.x,ra1.y), pack_bf16x2(ra1.z,ra1.w));
        wA[1] = make_uint4(pack_bf16x2(ra2.x,ra2.y), pack_bf16x2(ra2.z,ra2.w),
                           pack_bf16x2(ra3.x,ra3.y), pack_bf16x2(ra3.z,ra3.w));
        wB[0] = make_uint4(pack_bf16x2(rb0.x,rb0.y), pack_bf16x2(rb0.z,rb0.w),
                           pack_bf16x2(rb1.x,rb1.y), pack_bf16x2(rb1.z,rb1.w));
        wB[1] = make_uint4(pack_bf16x2(rb2.x,rb2.y), pack_bf16x2(rb2.z,rb2.w),
                           pack_bf16x2(rb3.x,rb3.y), pack_bf16x2(rb3.z,rb3.w));
        __syncthreads();
        if (kt + TK < H_DIM) {
            int kq = (kt + TK) >> 2;
            ra0 = gA[kq]; ra1 = gA[kq+1]; ra2 = gA[kq+2]; ra3 = gA[kq+3];
            rb0 = gB[kq]; rb1 = gB[kq+1]; rb2 = gB[kq+2]; rb3 = gB[kq+3];
        }
        bf16x8 af[4], bfr[4];
        #pragma unroll
        for (int i = 0; i < 4; i++) {
            af[i]  = *(const bf16x8*)(sA + (wm*64 + i*16 + cl) * TK + q*8);
            bfr[i] = *(const bf16x8*)(sB + (wn*64 + i*16 + cl) * TK + q*8);
        }
        #pragma unroll
        for (int i = 0; i < 4; i++)
            #pragma unroll
            for (int j = 0; j < 4; j++)
                acc[i][j] = __builtin_amdgcn_mfma_f32_16x16x32_bf16(af[i], bfr[j], acc[i][j], 0, 0, 0);
        __syncthreads();
    }

    #pragma unroll
    for (int ti = 0; ti < 4; ti++) {
        #pragma unroll
        for (int r = 0; r < 4; r++) {
            float vals[4];
            #pragma unroll
            for (int j = 0; j < 4; j++) vals[j] = acc[ti][j][r];
            float m = vals[0]; int cj = 0;
            #pragma unroll
            for (int j = 1; j < 4; j++) if (vals[j] > m) { m = vals[j]; cj = j; }
            float s = 0.f;
            #pragma unroll
            for (int j = 0; j < 4; j++) s += __expf(vals[j] - m);
            int cidx = wn*64 + cj*16 + cl;
            #pragma unroll
            for (int off = 1; off < 16; off <<= 1) {
                float m2 = __shfl_xor(m, off);
                float s2 = __shfl_xor(s, off);
                int   c2 = __shfl_xor(cidx, off);
                float nm = fmaxf(m, m2);
                s = s * __expf(m - nm) + s2 * __expf(m2 - nm);
                if (m2 > m || (m2 == m && c2 < cidx)) cidx = c2;
                m = nm;
            }
            int rloc = wm*64 + ti*16 + q*4 + r;
            if (cl == 0) { redM[rloc*2+wn] = m; redS[rloc*2+wn] = s; redC[rloc*2+wn] = cidx; }
        }
    }
    __syncthreads();
    if (tid < TM) {
        float ma = redM[tid*2+0], mb = redM[tid*2+1];
        float sa = redS[tid*2+0], sb = redS[tid*2+1];
        int   ca = redC[tid*2+0], cb = redC[tid*2+1];
        float nm = fmaxf(ma, mb);
        float s  = sa * __expf(ma - nm) + sb * __expf(mb - nm);
        int   cc = (mb > ma || (mb == ma && cb < ca)) ? cb : ca;
        part[(size_t)(m0 + tid) * NBLK_FB + nb] = make_float4(nm, s, __int_as_float(n0 + cc), 0.f);
    }

    if (token != nullptr) {
        if (tid < TM) tokloc[tid] = token[m0 + tid] - n0;
        __syncthreads();
        #pragma unroll
        for (int ti = 0; ti < 4; ti++) {
            #pragma unroll
            for (int r = 0; r < 4; r++) {
                int rloc = wm*64 + ti*16 + q*4 + r;
                int tl = tokloc[rloc];
                if (tl >= 0 && tl < TN && ((tl >> 6) & 1) == wn && (tl & 15) == cl) {
                    int tjm = (tl >> 4) & 3;
                    float v = acc[ti][0][r];
                    if (tjm == 1) v = acc[ti][1][r];
                    if (tjm == 2) v = acc[ti][2][r];
                    if (tjm == 3) v = acc[ti][3][r];
                    gather_out[m0 + rloc] = v;
                }
            }
        }
    }
}

// ---------------- fallback reductions ----------------

__global__ __launch_bounds__(256) void reduce_policy_kernel(
    const float4* __restrict__ part, int* __restrict__ token, float* __restrict__ tok_logp,
    int nblk)
{
    int row = blockIdx.x, t = threadIdx.x;
    float m = -3.0e38f, s = 0.f; int cc = 0x7fffffff;
    if (t < nblk) { float4 p = part[(size_t)row * nblk + t]; m = p.x; s = p.y; cc = __float_as_int(p.z); }
    for (int off = 1; off < 64; off <<= 1) {
        float m2 = __shfl_xor(m, off);
        float s2 = __shfl_xor(s, off);
        int   c2 = __shfl_xor(cc, off);
        float nm = fmaxf(m, m2);
        s = s * __expf(m - nm) + s2 * __expf(m2 - nm);
        if (m2 > m || (m2 == m && c2 < cc)) cc = c2;
        m = nm;
    }
    __shared__ float smM[4], smS[4]; __shared__ int smC[4];
    if ((t & 63) == 0) { smM[t>>6] = m; smS[t>>6] = s; smC[t>>6] = cc; }
    __syncthreads();
    if (t == 0) {
        m = smM[0]; s = smS[0]; cc = smC[0];
        for (int i = 1; i < 4; i++) {
            float m2 = smM[i], s2 = smS[i]; int c2 = smC[i];
            float nm = fmaxf(m, m2);
            s = s * __expf(m - nm) + s2 * __expf(m2 - nm);
            if (m2 > m || (m2 == m && c2 < cc)) cc = c2;
            m = nm;
        }
        token[row] = cc;
        tok_logp[row] = -__logf(s);
    }
}

__global__ __launch_bounds__(256) void dot_gather_kernel(
    const float* __restrict__ rx, const float* __restrict__ rw,
    const int* __restrict__ token, float* __restrict__ out)
{
    int row = blockIdx.x, t = threadIdx.x;
    const float4* a = (const float4*)(rx + (size_t)row * H_DIM);
    const float4* b = (const float4*)(rw + (size_t)token[row] * H_DIM);
    float4 a0 = a[t*2], a1 = a[t*2+1], b0 = b[t*2], b1 = b[t*2+1];
    float s = a0.x*b0.x + a0.y*b0.y + a0.z*b0.z + a0.w*b0.w
            + a1.x*b1.x + a1.y*b1.y + a1.z*b1.z + a1.w*b1.w;
    for (int off = 1; off < 64; off <<= 1) s += __shfl_xor(s, off);
    __shared__ float ss[4];
    if ((t & 63) == 0) ss[t >> 6] = s;
    __syncthreads();
    if (t == 0) out[row] = ss[0] + ss[1] + ss[2] + ss[3];
}

__global__ __launch_bounds__(256) void reduce_ref_kernel(
    const float4* __restrict__ part, const float* __restrict__ tok_logp,
    const float* __restrict__ gathered, float* __restrict__ klrow, int nblk)
{
    int row = blockIdx.x, t = threadIdx.x;
    float m = -3.0e38f, s = 0.f;
    if (t < nblk) { float4 p = part[(size_t)row * nblk + t]; m = p.x; s = p.y; }
    for (int off = 1; off < 64; off <<= 1) {
        float m2 = __shfl_xor(m, off), s2 = __shfl_xor(s, off);
        merge_ms(m, s, m2, s2);
    }
    __shared__ float smM[4], smS[4];
    if ((t & 63) == 0) { smM[t>>6] = m; smS[t>>6] = s; }
    __syncthreads();
    if (t == 0) {
        m = smM[0]; s = smS[0];
        for (int i = 1; i < 4; i++) merge_ms(m, s, smM[i], smS[i]);
        float lse = m + __logf(s);
        float d = (gathered[row] - lse) - tok_logp[row];
        klrow[row] = __expf(d) - d - 1.0f;
    }
}

__global__ __launch_bounds__(256) void final_kernel(
    const int* __restrict__ amask, const float* __restrict__ rewards,
    const float* __restrict__ klrow, float* __restrict__ out)
{
    int t = threadIdx.x;
    int b = t >> 5;
    int g = b >> 2;
    float r0 = rewards[g*4+0], r1 = rewards[g*4+1], r2 = rewards[g*4+2], r3 = rewards[g*4+3];
    float mean = 0.25f * (r0 + r1 + r2 + r3);
    float var = ((r0-mean)*(r0-mean) + (r1-mean)*(r1-mean) +
                 (r2-mean)*(r2-mean) + (r3-mean)*(r3-mean)) * (1.0f/3.0f);  // ddof=1
    float adv = (rewards[b] - mean) / (sqrtf(var) + EPSR);

    float ln = 0.f, ms = 0.f, kb = 0.f, mb = 0.f;
    for (int i = 0; i < 8; i++) {
        int row = t*8 + i;
        float mk = (float)amask[row];
        float kl = klrow[row];
        ln += (adv - BETA * kl) * mk;
        ms += mk;
        kb += kl * mk;
        mb += mk;
    }
    __shared__ float sLN[256], sMS[256], sKB[256], sMB[256], sKLb[8];
    sLN[t] = ln; sMS[t] = ms; sKB[t] = kb; sMB[t] = mb;
    __syncthreads();
    if (t < 8) {
        float skb = 0.f, smb = 0.f;
        for (int i = 0; i < 32; i++) { skb += sKB[t*32+i]; smb += sMB[t*32+i]; }
        sKLb[t] = skb / smb;
    }
    __syncthreads();
    if (t == 0) {
        float lnt = 0.f, mst = 0.f;
        for (int i = 0; i < 256; i++) { lnt += sLN[i]; mst += sMS[i]; }
        float mkl = 0.f;
        for (int i = 0; i < 8; i++) mkl += sKLb[i];
        out[0] = -lnt / mst;
        out[1] = mkl * 0.125f;
    }
}

// ---------------- launch ----------------

extern "C" void kernel_launch(void* const* d_in, const int* in_sizes, int n_in,
                              void* d_out, int out_size, void* d_ws, size_t ws_size,
                              hipStream_t stream)
{
    const float* x       = (const float*)d_in[0];
    const float* w       = (const float*)d_in[1];
    const int*   amask   = (const int*)  d_in[2];
    const float* rewards = (const float*)d_in[3];
    const float* rx      = (const float*)d_in[4];
    const float* rw      = (const float*)d_in[5];
    float* out = (float*)d_out;
    char* ws = (char*)d_ws;

    const size_t W_P  = (size_t)V_DIM * H_DIM * 2;   // 131,072,000 bf16 bytes
    const size_t A_P  = (size_t)BT * H_DIM * 2;      //   8,388,608
    const size_t PART = (size_t)BT * NBLK2 * 16;     //   4,096,000
    const size_t NEED = 2*W_P + 2*A_P + 2*PART + 4*8192;

    if (ws_size >= NEED) {
        // ---- fast path: linear pack, z-split XCD-swizzled 8-phase GEMM, fused tail ----
        ushort* Wp   = (ushort*)(ws);
        ushort* RWp  = (ushort*)(ws + W_P);
        ushort* Ap   = (ushort*)(ws + 2*W_P);
        ushort* Rp   = (ushort*)(ws + 2*W_P + A_P);
        float4* part  = (float4*)(ws + 2*W_P + 2*A_P);
        float4* part2 = (float4*)(ws + 2*W_P + 2*A_P + PART);
        char*   tail  =          ws + 2*W_P + 2*A_P + 2*PART;
        float* klrow    = (float*)(tail);

        pack_lin_kernel<<<dim3(4256), 512, 0, stream>>>(
            x, w, rx, rw, (uint4*)Ap, (uint4*)Wp, (uint4*)Rp, (uint4*)RWp);

        gemm_lse_v4<<<dim3(1000), 512, 0, stream>>>(Ap, Wp, part);    // policy
        gemm_lse_v4<<<dim3(1000), 512, 0, stream>>>(Rp, RWp, part2);  // reference

        row_tail_kernel<<<BT, 256, 0, stream>>>(part, part2, rx, rw, klrow);
        final_kernel<<<1, 256, 0, stream>>>(amask, rewards, klrow, out);
    } else {
        // ---- fallback: round-1 path (ws too small for packed weights) ----
        const size_t PART_FB = (size_t)BT * NBLK_FB * 16;
        float4* part     = (float4*)ws;
        int*    token    = (int*)  (ws + PART_FB);
        float*  tok_logp = (float*)(ws + PART_FB + 8192);
        float*  gathered = (float*)(ws + PART_FB + 16384);
        float*  klrow    = (float*)(ws + PART_FB + 24576);

        dim3 g(BT / TM, NBLK_FB), blk(256);
        gemm_lse_fallback<<<g, blk, 0, stream>>>(x, w, part, nullptr, nullptr);
        reduce_policy_kernel<<<BT, 256, 0, stream>>>(part, token, tok_logp, NBLK_FB);
        gemm_lse_fallback<<<g, blk, 0, stream>>>(rx, rw, part, token, gathered);
        reduce_ref_kernel<<<BT, 256, 0, stream>>>(part, tok_logp, gathered, klrow, NBLK_FB);
        final_kernel<<<1, 256, 0, stream>>>(amask, rewards, klrow, out);
    }
}

// Round 6
// 1080.575 us; speedup vs baseline: 1.2022x; 1.0042x over previous
//
#include <hip/hip_runtime.h>
#include <hip/hip_bf16.h>
#include <math.h>

// Problem constants (fixed by the reference: H=2048, V=32000, B=8, T=256, G=4).
#define H_DIM 2048
#define V_DIM 32000
#define BT    2048            // B*T rows
#define BETA  0.1f
#define EPSR  1e-4f

// ---- fast-path GEMM geometry: 256x256 tile, BK=64, 8 waves (2M x 4N) ----
#define NT    32              // K tiles of 64 (H/64)
#define NBLK2 125             // V / 256
// ---- fallback geometry (round-1 kernel, unchanged) ----
#define TM 128
#define TN 128
#define TK 32
#define NBLK_FB 250

typedef __attribute__((ext_vector_type(8))) short bf16x8;   // 8 bf16 = 4 VGPRs
typedef __attribute__((ext_vector_type(4))) float f32x4;

// ---------------- helpers ----------------

// Pack two fp32 -> bf16x2 (round-half-up via +0x8000, take high 16 bits each).
__device__ __forceinline__ unsigned pack_bf16x2(float a, float b) {
    unsigned ua = __float_as_uint(a) + 0x8000u;
    unsigned ub = __float_as_uint(b) + 0x8000u;
    return __builtin_amdgcn_perm(ub, ua, 0x07060302u);
}

__device__ __forceinline__ void merge_ms(float& m, float& s, float m2, float s2) {
    float nm = fmaxf(m, m2);
    s = s * __expf(m - nm) + s2 * __expf(m2 - nm);
    m = nm;
}

// Async global->LDS, 16 B per lane. LDS dest = wave-uniform base + lane*16.
__device__ __forceinline__ void gl_lds16(const void* g, void* l) {
    __builtin_amdgcn_global_load_lds(
        (const __attribute__((address_space(1))) void*)g,
        (__attribute__((address_space(3))) void*)l, 16, 0, 0);
}

// ---------------- linear pack: fp32 [R,2048] -> bf16 slabs per (256-row, 64-K) tile --------
// Slab (rt,kt) is 32 KB: chunk (kk*256+row) holds src[rt*256+row][kt*64+kk*8..+8] as 8 bf16.
// 512 threads/block; reads fully linear (16 rows x 8KB contiguous per block); LDS
// row-per-iteration conversion; writes in 256B contiguous segments per (kt,kk).
#define PROWS 16

__device__ __forceinline__ void pack_rows(
    const float* __restrict__ src, uint4* __restrict__ dst, int rb, int t,
    ushort (*tile)[2056])
{
    const int r0    = rb * PROWS;          // first global row of this block
    const int rt    = r0 >> 8;             // slab row-tile (256-row units)
    const int rbase = r0 & 255;            // row offset within the slab

    // Fully linear read: iteration i covers exactly row i (512 float4 = one 8KB row).
    const float4* s4 = (const float4*)(src + (size_t)r0 * H_DIM);
    #pragma unroll
    for (int i = 0; i < PROWS; i++) {
        float4 v = s4[i * 512 + t];
        uint2 b;
        b.x = pack_bf16x2(v.x, v.y);
        b.y = pack_bf16x2(v.z, v.w);
        *(uint2*)&tile[i][t * 4] = b;                  // 8B store
    }
    __syncthreads();

    // Write out: 4096 x 16B chunks; c = (kt<<7)|(kk<<4)|row -> row fastest for 256B
    // contiguous global segments per (kt,kk). kt wave-uniform.
    #pragma unroll
    for (int i = 0; i < 8; i++) {
        int c   = i * 512 + t;                         // 0..4095
        int kt  = c >> 7, kk = (c >> 4) & 7, row = c & 15;
        uint4 v = *(const uint4*)&tile[row][kt * 64 + kk * 8];
        dst[(((size_t)rt * NT + kt) << 11) + kk * 256 + rbase + row] = v;
    }
}

// Activations: x (blocks 0..127) and rx (blocks 128..255).
__global__ __launch_bounds__(512) void pack_act_kernel(
    const float* __restrict__ x, const float* __restrict__ rx,
    uint4* __restrict__ Ap, uint4* __restrict__ Rp)
{
    __shared__ __align__(16) ushort tile[PROWS][2056];   // 65,792 B -> 2 blocks/CU
    const int bx = blockIdx.x;
    if (bx < 128) pack_rows(x,  Ap, bx,       threadIdx.x, tile);
    else          pack_rows(rx, Rp, bx - 128, threadIdx.x, tile);
}

// One weight matrix -> the SHARED weight slab buffer (called twice, stream-serialized
// around gemm1 so w's slabs are consumed before rw overwrites them).
__global__ __launch_bounds__(512) void pack_w_kernel(
    const float* __restrict__ src, uint4* __restrict__ dst)
{
    __shared__ __align__(16) ushort tile[PROWS][2056];
    pack_rows(src, dst, blockIdx.x, threadIdx.x, tile);
}

// ---------------- 256^2 8-phase GEMM (XCD-swizzled, single-barrier phases) ----------------
// One dispatch per model (policy / ref), grid 1000. Work index l = (bid%8)*125 + bid/8;
// mb = l&7 fastest, nb = l>>3 in [0,125): 8 co-resident same-XCD blocks share one B-panel
// (L2-served; proven R3: FETCH 1.06GB -> 0.42GB).
// Barrier structure (R4, verified): one barrier per phase; vmcnt(6) + publication barrier
// only at p4/p8. POSTB B-frag reloads run post-MFMA for the next 4 phases.

#define MF(a,b,c) __builtin_amdgcn_mfma_f32_16x16x32_bf16(a, b, c, 0, 0, 0)

#define LDA(dst, BUF, F, KS) \
    dst = *(const bf16x8*)(smem + (BUF)*65536 + (KS)*16384 + (F)*256 + aoff)
#define LDB(dst, BUF, CF, KS) \
    dst = *(const bf16x8*)(smem + (BUF)*65536 + (KS)*16384 + (CF)*256 + boff)

#define STAGE(SG, SHT, SBUF) do { \
    const char* s_ = ((SHT) < 2 ? Bbase : Abase) + ((size_t)(SG) << 15); \
    char* l_ = smem + (SBUF)*65536 + ((SHT) < 2 ? 32768 : 0); \
    gl_lds16(s_ + soff[SHT][0], l_ + soff[SHT][0]); \
    gl_lds16(s_ + soff[SHT][1], l_ + soff[SHT][1]); \
} while (0)

#define MFMA_PH(F0, A0, A1, A2, A3) do { \
    acc[F0][0]   = MF(A0, bfr[0][0], acc[F0][0]); \
    acc[F0][1]   = MF(A0, bfr[1][0], acc[F0][1]); \
    acc[F0][2]   = MF(A0, bfr[2][0], acc[F0][2]); \
    acc[F0][3]   = MF(A0, bfr[3][0], acc[F0][3]); \
    acc[F0+1][0] = MF(A2, bfr[0][0], acc[F0+1][0]); \
    acc[F0+1][1] = MF(A2, bfr[1][0], acc[F0+1][1]); \
    acc[F0+1][2] = MF(A2, bfr[2][0], acc[F0+1][2]); \
    acc[F0+1][3] = MF(A2, bfr[3][0], acc[F0+1][3]); \
    acc[F0][0]   = MF(A1, bfr[0][1], acc[F0][0]); \
    acc[F0][1]   = MF(A1, bfr[1][1], acc[F0][1]); \
    acc[F0][2]   = MF(A1, bfr[2][1], acc[F0][2]); \
    acc[F0][3]   = MF(A1, bfr[3][1], acc[F0][3]); \
    acc[F0+1][0] = MF(A3, bfr[0][1], acc[F0+1][0]); \
    acc[F0+1][1] = MF(A3, bfr[1][1], acc[F0+1][1]); \
    acc[F0+1][2] = MF(A3, bfr[2][1], acc[F0+1][2]); \
    acc[F0+1][3] = MF(A3, bfr[3][1], acc[F0+1][3]); \
} while (0)

#define PHASE(BUF, F0, SG, SHT, SBUF, VM, POSTB, PBUF) do { \
    bf16x8 a0_, a1_, a2_, a3_; \
    LDA(a0_, BUF, F0, 0);   LDA(a1_, BUF, F0, 1); \
    LDA(a2_, BUF, F0+1, 0); LDA(a3_, BUF, F0+1, 1); \
    STAGE(SG, SHT, SBUF); \
    if (VM) { \
        asm volatile("s_waitcnt vmcnt(6)" ::: "memory"); \
        __builtin_amdgcn_s_barrier(); \
        asm volatile("" ::: "memory"); \
    } \
    __builtin_amdgcn_s_setprio(1); \
    MFMA_PH(F0, a0_, a1_, a2_, a3_); \
    __builtin_amdgcn_s_setprio(0); \
    if (POSTB) { \
        LDB(bfr[0][0], PBUF, 0, 0); LDB(bfr[0][1], PBUF, 0, 1); \
        LDB(bfr[1][0], PBUF, 1, 0); LDB(bfr[1][1], PBUF, 1, 1); \
        LDB(bfr[2][0], PBUF, 2, 0); LDB(bfr[2][1], PBUF, 2, 1); \
        LDB(bfr[3][0], PBUF, 3, 0); LDB(bfr[3][1], PBUF, 3, 1); \
    } \
    asm volatile("" ::: "memory"); \
    __builtin_amdgcn_s_barrier(); \
    asm volatile("" ::: "memory"); \
} while (0)

__global__ __launch_bounds__(512, 2) void gemm_lse_v4(
    const ushort* __restrict__ Apk, const ushort* __restrict__ Bpk,
    float4* __restrict__ pp)
{
    __shared__ __align__(16) char smem_raw[131072 + 12288];  // tiles | epilogue scratch
    char* smem = smem_raw;
    float* redM = (float*)(smem_raw + 131072);               // 256 rows x 4 wn-segments
    float* redS = (float*)(smem_raw + 131072 + 4096);
    int*   redC = (int*)  (smem_raw + 131072 + 8192);

    const int tid  = threadIdx.x;
    const int lane = tid & 63;
    const int wv   = tid >> 6;                          // 0..7
    const int wm   = wv >> 2, wn = wv & 3;              // 2 x 4 wave grid: 128x64 per wave
    const int q    = lane >> 4, cl = lane & 15;

    // XCD-chunked work mapping: bid%8 ~ XCD (dispatch round-robin heuristic; speed-only).
    const int bid = blockIdx.x;                         // 0..999
    const int l   = (bid & 7) * 125 + (bid >> 3);       // bijective
    const int mb  = l & 7;                              // varies fastest: 8 blocks share panel
    const int nb  = l >> 3;                             // 0..124 = B-panel

    const char* Abase = (const char*)Apk + ((size_t)(mb * NT) << 15);
    const char* Bbase = (const char*)Bpk + ((size_t)(nb * NT) << 15);

    // Fragment-read base offsets (within a 64 KB tile-buffer).
    const int aoff = q * 4096 + (wm * 128 + cl) * 16;
    const int boff = 32768 + q * 4096 + (wn * 64 + cl) * 16;

    // Staging offsets: chunk c = wv*2 + li covers (kk, row-group), 64 rows/lane.
    int soff[4][2];
    #pragma unroll
    for (int li = 0; li < 2; li++) {
        int c = wv * 2 + li;
        int kko = (((c >> 3) << 2) + ((c >> 1) & 3)) * 4096;
        int rg = c & 1;
        soff[0][li] = kko + (rg * 64 + lane) * 16;            // B rows 0..128
        soff[1][li] = kko + (128 + rg * 64 + lane) * 16;      // B rows 128..256
        soff[2][li] = kko + (rg * 128 + lane) * 16;           // A rows {0-64, 128-192}
        soff[3][li] = kko + (rg * 128 + 64 + lane) * 16;      // A rows {64-128, 192-256}
    }

    f32x4 acc[8][4];
    const f32x4 zero = {0.f, 0.f, 0.f, 0.f};
    #pragma unroll
    for (int i = 0; i < 8; i++)
        #pragma unroll
        for (int j = 0; j < 4; j++) acc[i][j] = zero;

    bf16x8 bfr[4][2];

    // Prologue: tile0 (4 HTs) -> buf0, tile1 (ht0..2) -> buf1; 14 loads, keep 6 in flight.
    STAGE(0, 0, 0); STAGE(0, 1, 0); STAGE(0, 2, 0); STAGE(0, 3, 0);
    STAGE(1, 0, 1); STAGE(1, 1, 1); STAGE(1, 2, 1);
    asm volatile("s_waitcnt vmcnt(6)" ::: "memory");
    __builtin_amdgcn_s_barrier();
    asm volatile("" ::: "memory");
    // Initial B frags (tile 0, buf0); consumed at p1's MFMAs (compiler waits there).
    LDB(bfr[0][0], 0, 0, 0); LDB(bfr[0][1], 0, 0, 1);
    LDB(bfr[1][0], 0, 1, 0); LDB(bfr[1][1], 0, 1, 1);
    LDB(bfr[2][0], 0, 2, 0); LDB(bfr[2][1], 0, 2, 1);
    LDB(bfr[3][0], 0, 3, 0); LDB(bfr[3][1], 0, 3, 1);

    #pragma unroll 1
    for (int ii = 0; ii < 16; ii++) {
        int t1 = 2 * ii + 1;
        int t2 = 2 * ii + 2; if (t2 > NT - 1) t2 = NT - 1;  // tail: dummy (valid) stages,
        int t3 = 2 * ii + 3; if (t3 > NT - 1) t3 = NT - 1;  // keeps the vmcnt ledger exact
        PHASE(0, 0, t1, 3, 1, 0, 0, 0);
        PHASE(0, 2, t2, 0, 0, 0, 0, 0);
        PHASE(0, 4, t2, 1, 0, 0, 0, 0);
        PHASE(0, 6, t2, 2, 0, 1, 1, 1);   // vmcnt(6)+pub; postload B(t1) from buf1
        PHASE(1, 0, t2, 3, 0, 0, 0, 0);
        PHASE(1, 2, t3, 0, 1, 0, 0, 0);
        PHASE(1, 4, t3, 1, 1, 0, 0, 0);
        PHASE(1, 6, t3, 2, 1, 1, 1, 0);   // vmcnt(6)+pub; postload B(t2) from buf0
    }

    // ---- epilogue: per-row {max, argmax col, sumexp} over this block's 256 cols ----
    // C layout (m89): col = cf*16 + cl (+ wn*64), row = f*16 + q*4 + reg (+ wm*128).
    // Remaining in-flight dummy loads target the tile buffers (<128KB); scratch is above.
    #pragma unroll
    for (int f = 0; f < 8; f++) {
        #pragma unroll
        for (int r = 0; r < 4; r++) {
            float v0 = acc[f][0][r], v1 = acc[f][1][r], v2 = acc[f][2][r], v3 = acc[f][3][r];
            float m = v0; int cj = 0;
            if (v1 > m) { m = v1; cj = 1; }
            if (v2 > m) { m = v2; cj = 2; }
            if (v3 > m) { m = v3; cj = 3; }
            float s = __expf(v0 - m) + __expf(v1 - m) + __expf(v2 - m) + __expf(v3 - m);
            int cidx = wn * 64 + cj * 16 + cl;
            #pragma unroll
            for (int off = 1; off < 16; off <<= 1) {
                float m2 = __shfl_xor(m, off);
                float s2 = __shfl_xor(s, off);
                int   c2 = __shfl_xor(cidx, off);
                float nm = fmaxf(m, m2);
                s = s * __expf(m - nm) + s2 * __expf(m2 - nm);
                if (m2 > m || (m2 == m && c2 < cidx)) cidx = c2;   // first-occurrence ties
                m = nm;
            }
            int rloc = wm * 128 + f * 16 + q * 4 + r;
            if (cl == 0) { redM[rloc*4+wn] = m; redS[rloc*4+wn] = s; redC[rloc*4+wn] = cidx; }
        }
    }
    asm volatile("s_waitcnt lgkmcnt(0)" ::: "memory");   // seal scratch writes (cross-wave)
    __builtin_amdgcn_s_barrier();
    asm volatile("" ::: "memory");
    if (tid < 256) {
        float m = redM[tid*4+0], s = redS[tid*4+0];
        int   cc = redC[tid*4+0];
        #pragma unroll
        for (int i2 = 1; i2 < 4; i2++) {
            float m2 = redM[tid*4+i2], s2 = redS[tid*4+i2];
            int   c2 = redC[tid*4+i2];
            float nm = fmaxf(m, m2);
            s = s * __expf(m - nm) + s2 * __expf(m2 - nm);
            if (m2 > m) cc = c2;                 // ascending col order; ties keep lower col
            m = nm;
        }
        pp[(size_t)(mb * 256 + tid) * NBLK2 + nb] =
            make_float4(m, s, __int_as_float(nb * 256 + cc), 0.f);
    }
}

// ---------------- fused row tail: policy argmax/lse + exact dot + ref lse + KL ----------------
__global__ __launch_bounds__(256) void row_tail_kernel(
    const float4* __restrict__ part, const float4* __restrict__ part2,
    const float* __restrict__ rx, const float* __restrict__ rw,
    float* __restrict__ klrow)
{
    __shared__ float smM[4], smS[4]; __shared__ int smC[4];
    __shared__ float ss[4];
    __shared__ float sTokLogp; __shared__ int sTok;

    const int row = blockIdx.x, t = threadIdx.x;

    // ---- policy: max / argmax / sumexp over 125 partials ----
    float m = -3.0e38f, s = 0.f; int cc = 0x7fffffff;
    if (t < NBLK2) { float4 p = part[(size_t)row * NBLK2 + t]; m = p.x; s = p.y; cc = __float_as_int(p.z); }
    for (int off = 1; off < 64; off <<= 1) {
        float m2 = __shfl_xor(m, off);
        float s2 = __shfl_xor(s, off);
        int   c2 = __shfl_xor(cc, off);
        float nm = fmaxf(m, m2);
        s = s * __expf(m - nm) + s2 * __expf(m2 - nm);
        if (m2 > m || (m2 == m && c2 < cc)) cc = c2;
        m = nm;
    }
    if ((t & 63) == 0) { smM[t>>6] = m; smS[t>>6] = s; smC[t>>6] = cc; }
    __syncthreads();
    if (t == 0) {
        m = smM[0]; s = smS[0]; cc = smC[0];
        for (int i = 1; i < 4; i++) {
            float m2 = smM[i], s2 = smS[i]; int c2 = smC[i];
            float nm = fmaxf(m, m2);
            s = s * __expf(m - nm) + s2 * __expf(m2 - nm);
            if (m2 > m || (m2 == m && c2 < cc)) cc = c2;
            m = nm;
        }
        sTok = cc;
        sTokLogp = -__logf(s);    // token is argmax -> logit[token] == global max
    }
    __syncthreads();
    const int tok = sTok;

    // ---- exact fp32 dot: rx[row] . rw[tok] ----
    const float4* a = (const float4*)(rx + (size_t)row * H_DIM);
    const float4* b = (const float4*)(rw + (size_t)tok * H_DIM);
    float4 a0 = a[t*2], a1 = a[t*2+1], b0 = b[t*2], b1 = b[t*2+1];
    float d = a0.x*b0.x + a0.y*b0.y + a0.z*b0.z + a0.w*b0.w
            + a1.x*b1.x + a1.y*b1.y + a1.z*b1.z + a1.w*b1.w;
    for (int off = 1; off < 64; off <<= 1) d += __shfl_xor(d, off);
    if ((t & 63) == 0) ss[t >> 6] = d;

    // ---- ref: lse over 125 partials ----
    float mr = -3.0e38f, sr = 0.f;
    if (t < NBLK2) { float4 p = part2[(size_t)row * NBLK2 + t]; mr = p.x; sr = p.y; }
    for (int off = 1; off < 64; off <<= 1) {
        float m2 = __shfl_xor(mr, off), s2 = __shfl_xor(sr, off);
        merge_ms(mr, sr, m2, s2);
    }
    __syncthreads();           // seals ss; frees smM/smS for reuse
    if ((t & 63) == 0) { smM[t>>6] = mr; smS[t>>6] = sr; }
    __syncthreads();
    if (t == 0) {
        mr = smM[0]; sr = smS[0];
        for (int i = 1; i < 4; i++) merge_ms(mr, sr, smM[i], smS[i]);
        float lse = mr + __logf(sr);
        float g = ss[0] + ss[1] + ss[2] + ss[3];
        float dd = (g - lse) - sTokLogp;   // ref_tok_logp - tok_logp
        klrow[row] = __expf(dd) - dd - 1.0f;
    }
}

// ---------------- fallback GEMM (round-1, in-kernel convert + gather) ----------------
__global__ __launch_bounds__(256) void gemm_lse_fallback(
    const float* __restrict__ A, const float* __restrict__ Bw,
    float4* __restrict__ part, const int* __restrict__ token,
    float* __restrict__ gather_out)
{
    __shared__ char smem[TM*TK*2 + TN*TK*2];
    ushort* sA = (ushort*)smem;
    ushort* sB = (ushort*)(smem + TM*TK*2);
    float* redM   = (float*)smem;
    float* redS   = (float*)(smem + 1024);
    int*   redC   = (int*)  (smem + 2048);
    int*   tokloc = (int*)  (smem + 3072);

    const int tid  = threadIdx.x;
    const int lane = tid & 63;
    const int wv   = tid >> 6;
    const int wm   = wv >> 1, wn = wv & 1;
    const int q    = lane >> 4, cl = lane & 15;
    const int m0 = blockIdx.x * TM;
    const int n0 = blockIdx.y * TN;
    const int nb = blockIdx.y;

    const int srow = tid >> 1, sseg = tid & 1;
    const float4* gA = (const float4*)(A  + (size_t)(m0 + srow) * H_DIM) + sseg * 4;
    const float4* gB = (const float4*)(Bw + (size_t)(n0 + srow) * H_DIM) + sseg * 4;
    uint4* wA = (uint4*)sA + srow * 4 + sseg * 2;
    uint4* wB = (uint4*)sB + srow * 4 + sseg * 2;

    f32x4 acc[4][4];
    const f32x4 zero = {0.f, 0.f, 0.f, 0.f};
    #pragma unroll
    for (int i = 0; i < 4; i++)
        #pragma unroll
        for (int j = 0; j < 4; j++) acc[i][j] = zero;

    float4 ra0 = gA[0], ra1 = gA[1], ra2 = gA[2], ra3 = gA[3];
    float4 rb0 = gB[0], rb1 = gB[1], rb2 = gB[2], rb3 = gB[3];

    for (int kt = 0; kt < H_DIM; kt += TK) {
        wA[0] = make_uint4(pack_bf16x2(ra0.x,ra0.y), pack_bf16x2(ra0.z,ra0.w),
                           pack_bf16x2(ra1.x,ra1.y), pack_bf16x2(ra1.z,ra1.w));
        wA[1] = make_uint4(pack_bf16x2(ra2.x,ra2.y), pack_bf16x2(ra2.z,ra2.w),
                           pack_bf16x2(ra3.x,ra3.y), pack_bf16x2(ra3.z,ra3.w));
        wB[0] = make_uint4(pack_bf16x2(rb0.x,rb0.y), pack_bf16x2(rb0.z,rb0.w),
                           pack_bf16x2(rb1.x,rb1.y), pack_bf16x2(rb1.z,rb1.w));
        wB[1] = make_uint4(pack_bf16x2(rb2.x,rb2.y), pack_bf16x2(rb2.z,rb2.w),
                           pack_bf16x2(rb3.x,rb3.y), pack_bf16x2(rb3.z,rb3.w));
        __syncthreads();
        if (kt + TK < H_DIM) {
            int kq = (kt + TK) >> 2;
            ra0 = gA[kq]; ra1 = gA[kq+1]; ra2 = gA[kq+2]; ra3 = gA[kq+3];
            rb0 = gB[kq]; rb1 = gB[kq+1]; rb2 = gB[kq+2]; rb3 = gB[kq+3];
        }
        bf16x8 af[4], bfr[4];
        #pragma unroll
        for (int i = 0; i < 4; i++) {
            af[i]  = *(const bf16x8*)(sA + (wm*64 + i*16 + cl) * TK + q*8);
            bfr[i] = *(const bf16x8*)(sB + (wn*64 + i*16 + cl) * TK + q*8);
        }
        #pragma unroll
        for (int i = 0; i < 4; i++)
            #pragma unroll
            for (int j = 0; j < 4; j++)
                acc[i][j] = __builtin_amdgcn_mfma_f32_16x16x32_bf16(af[i], bfr[j], acc[i][j], 0, 0, 0);
        __syncthreads();
    }

    #pragma unroll
    for (int ti = 0; ti < 4; ti++) {
        #pragma unroll
        for (int r = 0; r < 4; r++) {
            float vals[4];
            #pragma unroll
            for (int j = 0; j < 4; j++) vals[j] = acc[ti][j][r];
            float m = vals[0]; int cj = 0;
            #pragma unroll
            for (int j = 1; j < 4; j++) if (vals[j] > m) { m = vals[j]; cj = j; }
            float s = 0.f;
            #pragma unroll
            for (int j = 0; j < 4; j++) s += __expf(vals[j] - m);
            int cidx = wn*64 + cj*16 + cl;
            #pragma unroll
            for (int off = 1; off < 16; off <<= 1) {
                float m2 = __shfl_xor(m, off);
                float s2 = __shfl_xor(s, off);
                int   c2 = __shfl_xor(cidx, off);
                float nm = fmaxf(m, m2);
                s = s * __expf(m - nm) + s2 * __expf(m2 - nm);
                if (m2 > m || (m2 == m && c2 < cidx)) cidx = c2;
                m = nm;
            }
            int rloc = wm*64 + ti*16 + q*4 + r;
            if (cl == 0) { redM[rloc*2+wn] = m; redS[rloc*2+wn] = s; redC[rloc*2+wn] = cidx; }
        }
    }
    __syncthreads();
    if (tid < TM) {
        float ma = redM[tid*2+0], mb = redM[tid*2+1];
        float sa = redS[tid*2+0], sb = redS[tid*2+1];
        int   ca = redC[tid*2+0], cb = redC[tid*2+1];
        float nm = fmaxf(ma, mb);
        float s  = sa * __expf(ma - nm) + sb * __expf(mb - nm);
        int   cc = (mb > ma || (mb == ma && cb < ca)) ? cb : ca;
        part[(size_t)(m0 + tid) * NBLK_FB + nb] = make_float4(nm, s, __int_as_float(n0 + cc), 0.f);
    }

    if (token != nullptr) {
        if (tid < TM) tokloc[tid] = token[m0 + tid] - n0;
        __syncthreads();
        #pragma unroll
        for (int ti = 0; ti < 4; ti++) {
            #pragma unroll
            for (int r = 0; r < 4; r++) {
                int rloc = wm*64 + ti*16 + q*4 + r;
                int tl = tokloc[rloc];
                if (tl >= 0 && tl < TN && ((tl >> 6) & 1) == wn && (tl & 15) == cl) {
                    int tjm = (tl >> 4) & 3;
                    float v = acc[ti][0][r];
                    if (tjm == 1) v = acc[ti][1][r];
                    if (tjm == 2) v = acc[ti][2][r];
                    if (tjm == 3) v = acc[ti][3][r];
                    gather_out[m0 + rloc] = v;
                }
            }
        }
    }
}

// ---------------- fallback reductions ----------------

__global__ __launch_bounds__(256) void reduce_policy_kernel(
    const float4* __restrict__ part, int* __restrict__ token, float* __restrict__ tok_logp,
    int nblk)
{
    int row = blockIdx.x, t = threadIdx.x;
    float m = -3.0e38f, s = 0.f; int cc = 0x7fffffff;
    if (t < nblk) { float4 p = part[(size_t)row * nblk + t]; m = p.x; s = p.y; cc = __float_as_int(p.z); }
    for (int off = 1; off < 64; off <<= 1) {
        float m2 = __shfl_xor(m, off);
        float s2 = __shfl_xor(s, off);
        int   c2 = __shfl_xor(cc, off);
        float nm = fmaxf(m, m2);
        s = s * __expf(m - nm) + s2 * __expf(m2 - nm);
        if (m2 > m || (m2 == m && c2 < cc)) cc = c2;
        m = nm;
    }
    __shared__ float smM[4], smS[4]; __shared__ int smC[4];
    if ((t & 63) == 0) { smM[t>>6] = m; smS[t>>6] = s; smC[t>>6] = cc; }
    __syncthreads();
    if (t == 0) {
        m = smM[0]; s = smS[0]; cc = smC[0];
        for (int i = 1; i < 4; i++) {
            float m2 = smM[i], s2 = smS[i]; int c2 = smC[i];
            float nm = fmaxf(m, m2);
            s = s * __expf(m - nm) + s2 * __expf(m2 - nm);
            if (m2 > m || (m2 == m && c2 < cc)) cc = c2;
            m = nm;
        }
        token[row] = cc;
        tok_logp[row] = -__logf(s);
    }
}

__global__ __launch_bounds__(256) void dot_gather_kernel(
    const float* __restrict__ rx, const float* __restrict__ rw,
    const int* __restrict__ token, float* __restrict__ out)
{
    int row = blockIdx.x, t = threadIdx.x;
    const float4* a = (const float4*)(rx + (size_t)row * H_DIM);
    const float4* b = (const float4*)(rw + (size_t)token[row] * H_DIM);
    float4 a0 = a[t*2], a1 = a[t*2+1], b0 = b[t*2], b1 = b[t*2+1];
    float s = a0.x*b0.x + a0.y*b0.y + a0.z*b0.z + a0.w*b0.w
            + a1.x*b1.x + a1.y*b1.y + a1.z*b1.z + a1.w*b1.w;
    for (int off = 1; off < 64; off <<= 1) s += __shfl_xor(s, off);
    __shared__ float ss[4];
    if ((t & 63) == 0) ss[t >> 6] = s;
    __syncthreads();
    if (t == 0) out[row] = ss[0] + ss[1] + ss[2] + ss[3];
}

__global__ __launch_bounds__(256) void reduce_ref_kernel(
    const float4* __restrict__ part, const float* __restrict__ tok_logp,
    const float* __restrict__ gathered, float* __restrict__ klrow, int nblk)
{
    int row = blockIdx.x, t = threadIdx.x;
    float m = -3.0e38f, s = 0.f;
    if (t < nblk) { float4 p = part[(size_t)row * nblk + t]; m = p.x; s = p.y; }
    for (int off = 1; off < 64; off <<= 1) {
        float m2 = __shfl_xor(m, off), s2 = __shfl_xor(s, off);
        merge_ms(m, s, m2, s2);
    }
    __shared__ float smM[4], smS[4];
    if ((t & 63) == 0) { smM[t>>6] = m; smS[t>>6] = s; }
    __syncthreads();
    if (t == 0) {
        m = smM[0]; s = smS[0];
        for (int i = 1; i < 4; i++) merge_ms(m, s, smM[i], smS[i]);
        float lse = m + __logf(s);
        float d = (gathered[row] - lse) - tok_logp[row];
        klrow[row] = __expf(d) - d - 1.0f;
    }
}

__global__ __launch_bounds__(256) void final_kernel(
    const int* __restrict__ amask, const float* __restrict__ rewards,
    const float* __restrict__ klrow, float* __restrict__ out)
{
    int t = threadIdx.x;
    int b = t >> 5;
    int g = b >> 2;
    float r0 = rewards[g*4+0], r1 = rewards[g*4+1], r2 = rewards[g*4+2], r3 = rewards[g*4+3];
    float mean = 0.25f * (r0 + r1 + r2 + r3);
    float var = ((r0-mean)*(r0-mean) + (r1-mean)*(r1-mean) +
                 (r2-mean)*(r2-mean) + (r3-mean)*(r3-mean)) * (1.0f/3.0f);  // ddof=1
    float adv = (rewards[b] - mean) / (sqrtf(var) + EPSR);

    float ln = 0.f, ms = 0.f, kb = 0.f, mb = 0.f;
    for (int i = 0; i < 8; i++) {
        int row = t*8 + i;
        float mk = (float)amask[row];
        float kl = klrow[row];
        ln += (adv - BETA * kl) * mk;
        ms += mk;
        kb += kl * mk;
        mb += mk;
    }
    __shared__ float sLN[256], sMS[256], sKB[256], sMB[256], sKLb[8];
    sLN[t] = ln; sMS[t] = ms; sKB[t] = kb; sMB[t] = mb;
    __syncthreads();
    if (t < 8) {
        float skb = 0.f, smb = 0.f;
        for (int i = 0; i < 32; i++) { skb += sKB[t*32+i]; smb += sMB[t*32+i]; }
        sKLb[t] = skb / smb;
    }
    __syncthreads();
    if (t == 0) {
        float lnt = 0.f, mst = 0.f;
        for (int i = 0; i < 256; i++) { lnt += sLN[i]; mst += sMS[i]; }
        float mkl = 0.f;
        for (int i = 0; i < 8; i++) mkl += sKLb[i];
        out[0] = -lnt / mst;
        out[1] = mkl * 0.125f;
    }
}

// ---------------- launch ----------------

extern "C" void kernel_launch(void* const* d_in, const int* in_sizes, int n_in,
                              void* d_out, int out_size, void* d_ws, size_t ws_size,
                              hipStream_t stream)
{
    const float* x       = (const float*)d_in[0];
    const float* w       = (const float*)d_in[1];
    const int*   amask   = (const int*)  d_in[2];
    const float* rewards = (const float*)d_in[3];
    const float* rx      = (const float*)d_in[4];
    const float* rw      = (const float*)d_in[5];
    float* out = (float*)d_out;
    char* ws = (char*)d_ws;

    const size_t W_P  = (size_t)V_DIM * H_DIM * 2;   // 131,072,000 bf16 bytes (ONE buffer)
    const size_t A_P  = (size_t)BT * H_DIM * 2;      //   8,388,608
    const size_t PART = (size_t)BT * NBLK2 * 16;     //   4,096,000
    const size_t NEED = W_P + 2*A_P + 2*PART + 32768;   // 156 MB (was 287 MB)

    if (ws_size >= NEED) {
        // ---- fast path: shared weight slab buffer, packed twice (w, then rw after gemm1).
        // Stream order serializes pack_w(rw) behind gemm1, so no overwrite race.
        ushort* Wp   = (ushort*)(ws);                 // shared slab buffer (w, then rw)
        ushort* Ap   = (ushort*)(ws + W_P);
        ushort* Rp   = (ushort*)(ws + W_P + A_P);
        float4* part  = (float4*)(ws + W_P + 2*A_P);
        float4* part2 = (float4*)(ws + W_P + 2*A_P + PART);
        char*   tail  =          ws + W_P + 2*A_P + 2*PART;
        float* klrow    = (float*)(tail);

        pack_act_kernel<<<dim3(256),  512, 0, stream>>>(x, rx, (uint4*)Ap, (uint4*)Rp);
        pack_w_kernel  <<<dim3(2000), 512, 0, stream>>>(w, (uint4*)Wp);

        gemm_lse_v4<<<dim3(1000), 512, 0, stream>>>(Ap, Wp, part);    // policy

        pack_w_kernel  <<<dim3(2000), 512, 0, stream>>>(rw, (uint4*)Wp);

        gemm_lse_v4<<<dim3(1000), 512, 0, stream>>>(Rp, Wp, part2);   // reference

        row_tail_kernel<<<BT, 256, 0, stream>>>(part, part2, rx, rw, klrow);
        final_kernel<<<1, 256, 0, stream>>>(amask, rewards, klrow, out);
    } else {
        // ---- fallback: round-1 path (ws too small for packed weights) ----
        const size_t PART_FB = (size_t)BT * NBLK_FB * 16;
        float4* part     = (float4*)ws;
        int*    token    = (int*)  (ws + PART_FB);
        float*  tok_logp = (float*)(ws + PART_FB + 8192);
        float*  gathered = (float*)(ws + PART_FB + 16384);
        float*  klrow    = (float*)(ws + PART_FB + 24576);

        dim3 g(BT / TM, NBLK_FB), blk(256);
        gemm_lse_fallback<<<g, blk, 0, stream>>>(x, w, part, nullptr, nullptr);
        reduce_policy_kernel<<<BT, 256, 0, stream>>>(part, token, tok_logp, NBLK_FB);
        gemm_lse_fallback<<<g, blk, 0, stream>>>(rx, rw, part, token, gathered);
        reduce_ref_kernel<<<BT, 256, 0, stream>>>(part, tok_logp, gathered, klrow, NBLK_FB);
        final_kernel<<<1, 256, 0, stream>>>(amask, rewards, klrow, out);
    }
}

// Round 7
// 1078.014 us; speedup vs baseline: 1.2050x; 1.0024x over previous
//
#include <hip/hip_runtime.h>
#include <hip/hip_bf16.h>
#include <math.h>

// Problem constants (fixed by the reference: H=2048, V=32000, B=8, T=256, G=4).
#define H_DIM 2048
#define V_DIM 32000
#define BT    2048            // B*T rows
#define BETA  0.1f
#define EPSR  1e-4f

// ---- fast-path GEMM geometry: 256x256 tile, BK=64, 8 waves (2M x 4N) ----
#define NT    32              // K tiles of 64 (H/64)
#define NBLK2 125             // V / 256
// ---- fallback geometry (round-1 kernel, unchanged) ----
#define TM 128
#define TN 128
#define TK 32
#define NBLK_FB 250

typedef __attribute__((ext_vector_type(8))) short bf16x8;   // 8 bf16 = 4 VGPRs
typedef __attribute__((ext_vector_type(4))) float f32x4;

// ---------------- helpers ----------------

// Pack two fp32 -> bf16x2 (round-half-up via +0x8000, take high 16 bits each).
__device__ __forceinline__ unsigned pack_bf16x2(float a, float b) {
    unsigned ua = __float_as_uint(a) + 0x8000u;
    unsigned ub = __float_as_uint(b) + 0x8000u;
    return __builtin_amdgcn_perm(ub, ua, 0x07060302u);
}

__device__ __forceinline__ void merge_ms(float& m, float& s, float m2, float s2) {
    float nm = fmaxf(m, m2);
    s = s * __expf(m - nm) + s2 * __expf(m2 - nm);
    m = nm;
}

// Async global->LDS, 16 B per lane. LDS dest = wave-uniform base + lane*16.
__device__ __forceinline__ void gl_lds16(const void* g, void* l) {
    __builtin_amdgcn_global_load_lds(
        (const __attribute__((address_space(1))) void*)g,
        (__attribute__((address_space(3))) void*)l, 16, 0, 0);
}

// ---------------- linear pack: fp32 [R,2048] -> bf16 slabs per (256-row, 64-K) tile --------
// Slab (rt,kt) is 32 KB: chunk (kk*256+row) holds src[rt*256+row][kt*64+kk*8..+8] as 8 bf16.
// 512 threads/block; reads fully linear (16 rows x 8KB contiguous per block); LDS
// row-per-iteration conversion; writes in 256B contiguous segments per (kt,kk).
#define PROWS 16

__device__ __forceinline__ void pack_rows(
    const float* __restrict__ src, uint4* __restrict__ dst, int rb, int t,
    ushort (*tile)[2056])
{
    const int r0    = rb * PROWS;          // first global row of this block
    const int rt    = r0 >> 8;             // slab row-tile (256-row units)
    const int rbase = r0 & 255;            // row offset within the slab

    // Fully linear read: iteration i covers exactly row i (512 float4 = one 8KB row).
    const float4* s4 = (const float4*)(src + (size_t)r0 * H_DIM);
    #pragma unroll
    for (int i = 0; i < PROWS; i++) {
        float4 v = s4[i * 512 + t];
        uint2 b;
        b.x = pack_bf16x2(v.x, v.y);
        b.y = pack_bf16x2(v.z, v.w);
        *(uint2*)&tile[i][t * 4] = b;                  // 8B store
    }
    __syncthreads();

    // Write out: 4096 x 16B chunks; c = (kt<<7)|(kk<<4)|row -> row fastest for 256B
    // contiguous global segments per (kt,kk). kt wave-uniform.
    #pragma unroll
    for (int i = 0; i < 8; i++) {
        int c   = i * 512 + t;                         // 0..4095
        int kt  = c >> 7, kk = (c >> 4) & 7, row = c & 15;
        uint4 v = *(const uint4*)&tile[row][kt * 64 + kk * 8];
        dst[(((size_t)rt * NT + kt) << 11) + kk * 256 + rbase + row] = v;
    }
}

// Activations: x (blocks 0..127) and rx (blocks 128..255).
__global__ __launch_bounds__(512) void pack_act_kernel(
    const float* __restrict__ x, const float* __restrict__ rx,
    uint4* __restrict__ Ap, uint4* __restrict__ Rp)
{
    __shared__ __align__(16) ushort tile[PROWS][2056];   // 65,792 B -> 2 blocks/CU
    const int bx = blockIdx.x;
    if (bx < 128) pack_rows(x,  Ap, bx,       threadIdx.x, tile);
    else          pack_rows(rx, Rp, bx - 128, threadIdx.x, tile);
}

// One weight matrix -> the SHARED weight slab buffer (called twice, stream-serialized
// around gemm1 so w's slabs are consumed before rw overwrites them).
__global__ __launch_bounds__(512) void pack_w_kernel(
    const float* __restrict__ src, uint4* __restrict__ dst)
{
    __shared__ __align__(16) ushort tile[PROWS][2056];
    pack_rows(src, dst, blockIdx.x, threadIdx.x, tile);
}

// ---------------- 256^2 8-phase GEMM v7: registered A-frag prefetch pipeline -------------
// One dispatch per model, grid 1000. Work index l = (bid%8)*125 + bid/8; mb = l&7 fastest:
// 8 co-resident same-XCD blocks share one B-panel (L2-served; proven R3).
//
// v7 change (R6 post-mortem: phase = 1350 cyc ~= 621 MFMA + ~700 LDS run SERIALLY):
// A-fragments for phase p+1 are ds_read-ISSUED during phase p into a second register set,
// so the MFMA cluster of phase p waits only on reads issued at p-1 (already landed) and the
// compiler emits a counted lgkmcnt(4) leaving the prefetch in flight -> LDS pipe drains
// under the MFMA region. Barrier positions and the vmcnt ledger are UNCHANGED from the
// R4-verified structure. Hazard audit: every prefetch source region is sealed >=1 barrier
// before any stage overwrites it (same read/write-set argument as R4, shifted one phase).

#define MF(a,b,c) __builtin_amdgcn_mfma_f32_16x16x32_bf16(a, b, c, 0, 0, 0)

#define LDA(dst, BUF, F, KS) \
    dst = *(const bf16x8*)(smem + (BUF)*65536 + (KS)*16384 + (F)*256 + aoff)
#define LDB(dst, BUF, CF, KS) \
    dst = *(const bf16x8*)(smem + (BUF)*65536 + (KS)*16384 + (CF)*256 + boff)

#define STAGE(SG, SHT, SBUF) do { \
    const char* s_ = ((SHT) < 2 ? Bbase : Abase) + ((size_t)(SG) << 15); \
    char* l_ = smem + (SBUF)*65536 + ((SHT) < 2 ? 32768 : 0); \
    gl_lds16(s_ + soff[SHT][0], l_ + soff[SHT][0]); \
    gl_lds16(s_ + soff[SHT][1], l_ + soff[SHT][1]); \
} while (0)

#define MFMA_PH(F0, A0, A1, A2, A3) do { \
    acc[F0][0]   = MF(A0, bfr[0][0], acc[F0][0]); \
    acc[F0][1]   = MF(A0, bfr[1][0], acc[F0][1]); \
    acc[F0][2]   = MF(A0, bfr[2][0], acc[F0][2]); \
    acc[F0][3]   = MF(A0, bfr[3][0], acc[F0][3]); \
    acc[F0+1][0] = MF(A2, bfr[0][0], acc[F0+1][0]); \
    acc[F0+1][1] = MF(A2, bfr[1][0], acc[F0+1][1]); \
    acc[F0+1][2] = MF(A2, bfr[2][0], acc[F0+1][2]); \
    acc[F0+1][3] = MF(A2, bfr[3][0], acc[F0+1][3]); \
    acc[F0][0]   = MF(A1, bfr[0][1], acc[F0][0]); \
    acc[F0][1]   = MF(A1, bfr[1][1], acc[F0][1]); \
    acc[F0][2]   = MF(A1, bfr[2][1], acc[F0][2]); \
    acc[F0][3]   = MF(A1, bfr[3][1], acc[F0][3]); \
    acc[F0+1][0] = MF(A3, bfr[0][1], acc[F0+1][0]); \
    acc[F0+1][1] = MF(A3, bfr[1][1], acc[F0+1][1]); \
    acc[F0+1][2] = MF(A3, bfr[2][1], acc[F0+1][2]); \
    acc[F0+1][3] = MF(A3, bfr[3][1], acc[F0+1][3]); \
} while (0)

// One phase. FC: acc row / current frags AFC (ds_read-issued LAST phase). AFN: register
// set receiving NEXT phase's frags from (BUFN, FN) -- issued here, consumed next phase.
// VM: vmcnt(6)+publication barrier FIRST (p4/p8) so cross-buffer prefetch reads sealed
// data. POSTB: B-frag reloads post-MFMA from PBUF for the next 4 phases.
#define PHASEP(FC, AFC, AFN, BUFN, FN, SG, SHT, SBUF, VM, POSTB, PBUF) do { \
    if (VM) { \
        asm volatile("s_waitcnt vmcnt(6)" ::: "memory"); \
        __builtin_amdgcn_s_barrier(); \
        asm volatile("" ::: "memory"); \
    } \
    LDA(AFN[0], BUFN, FN,   0); LDA(AFN[1], BUFN, FN,   1); \
    LDA(AFN[2], BUFN, FN+1, 0); LDA(AFN[3], BUFN, FN+1, 1); \
    STAGE(SG, SHT, SBUF); \
    __builtin_amdgcn_s_setprio(1); \
    MFMA_PH(FC, AFC[0], AFC[1], AFC[2], AFC[3]); \
    __builtin_amdgcn_s_setprio(0); \
    if (POSTB) { \
        LDB(bfr[0][0], PBUF, 0, 0); LDB(bfr[0][1], PBUF, 0, 1); \
        LDB(bfr[1][0], PBUF, 1, 0); LDB(bfr[1][1], PBUF, 1, 1); \
        LDB(bfr[2][0], PBUF, 2, 0); LDB(bfr[2][1], PBUF, 2, 1); \
        LDB(bfr[3][0], PBUF, 3, 0); LDB(bfr[3][1], PBUF, 3, 1); \
    } \
    asm volatile("" ::: "memory"); \
    __builtin_amdgcn_s_barrier(); \
    asm volatile("" ::: "memory"); \
} while (0)

__global__ __launch_bounds__(512, 2) void gemm_lse_v7(
    const ushort* __restrict__ Apk, const ushort* __restrict__ Bpk,
    float4* __restrict__ pp)
{
    __shared__ __align__(16) char smem_raw[131072 + 12288];  // tiles | epilogue scratch
    char* smem = smem_raw;
    float* redM = (float*)(smem_raw + 131072);               // 256 rows x 4 wn-segments
    float* redS = (float*)(smem_raw + 131072 + 4096);
    int*   redC = (int*)  (smem_raw + 131072 + 8192);

    const int tid  = threadIdx.x;
    const int lane = tid & 63;
    const int wv   = tid >> 6;                          // 0..7
    const int wm   = wv >> 2, wn = wv & 3;              // 2 x 4 wave grid: 128x64 per wave
    const int q    = lane >> 4, cl = lane & 15;

    // XCD-chunked work mapping: bid%8 ~ XCD (dispatch round-robin heuristic; speed-only).
    const int bid = blockIdx.x;                         // 0..999
    const int l   = (bid & 7) * 125 + (bid >> 3);       // bijective
    const int mb  = l & 7;                              // varies fastest: 8 blocks share panel
    const int nb  = l >> 3;                             // 0..124 = B-panel

    const char* Abase = (const char*)Apk + ((size_t)(mb * NT) << 15);
    const char* Bbase = (const char*)Bpk + ((size_t)(nb * NT) << 15);

    // Fragment-read base offsets (within a 64 KB tile-buffer).
    const int aoff = q * 4096 + (wm * 128 + cl) * 16;
    const int boff = 32768 + q * 4096 + (wn * 64 + cl) * 16;

    // Staging offsets: chunk c = wv*2 + li covers (kk, row-group), 64 rows/lane.
    int soff[4][2];
    #pragma unroll
    for (int li = 0; li < 2; li++) {
        int c = wv * 2 + li;
        int kko = (((c >> 3) << 2) + ((c >> 1) & 3)) * 4096;
        int rg = c & 1;
        soff[0][li] = kko + (rg * 64 + lane) * 16;            // B rows 0..128
        soff[1][li] = kko + (128 + rg * 64 + lane) * 16;      // B rows 128..256
        soff[2][li] = kko + (rg * 128 + lane) * 16;           // A rows {0-64, 128-192}
        soff[3][li] = kko + (rg * 128 + 64 + lane) * 16;      // A rows {64-128, 192-256}
    }

    f32x4 acc[8][4];
    const f32x4 zero = {0.f, 0.f, 0.f, 0.f};
    #pragma unroll
    for (int i = 0; i < 8; i++)
        #pragma unroll
        for (int j = 0; j < 4; j++) acc[i][j] = zero;

    bf16x8 bfr[4][2];
    bf16x8 afX[4], afY[4];      // double-buffered A-frag register sets

    // Prologue: tile0 (4 HTs) -> buf0, tile1 (ht0..2) -> buf1; 14 loads, keep 6 in flight.
    STAGE(0, 0, 0); STAGE(0, 1, 0); STAGE(0, 2, 0); STAGE(0, 3, 0);
    STAGE(1, 0, 1); STAGE(1, 1, 1); STAGE(1, 2, 1);
    asm volatile("s_waitcnt vmcnt(6)" ::: "memory");
    __builtin_amdgcn_s_barrier();
    asm volatile("" ::: "memory");
    // Initial B frags (tile 0, buf0) + p1's A frags (buf0, F0-1) into set X.
    LDB(bfr[0][0], 0, 0, 0); LDB(bfr[0][1], 0, 0, 1);
    LDB(bfr[1][0], 0, 1, 0); LDB(bfr[1][1], 0, 1, 1);
    LDB(bfr[2][0], 0, 2, 0); LDB(bfr[2][1], 0, 2, 1);
    LDB(bfr[3][0], 0, 3, 0); LDB(bfr[3][1], 0, 3, 1);
    LDA(afX[0], 0, 0, 0); LDA(afX[1], 0, 0, 1);
    LDA(afX[2], 0, 1, 0); LDA(afX[3], 0, 1, 1);

    #pragma unroll 1
    for (int ii = 0; ii < 16; ii++) {
        int t1 = 2 * ii + 1;
        int t2 = 2 * ii + 2; if (t2 > NT - 1) t2 = NT - 1;  // tail: dummy (valid) stages,
        int t3 = 2 * ii + 3; if (t3 > NT - 1) t3 = NT - 1;  // keeps the vmcnt ledger exact
        //      FC  cur  nxt  BUFN FN  SG  HT  SB  VM PB PBUF
        PHASEP( 0, afX, afY, 0,   2, t1, 3,  1,  0, 0, 0);   // p1
        PHASEP( 2, afY, afX, 0,   4, t2, 0,  0,  0, 0, 0);   // p2
        PHASEP( 4, afX, afY, 0,   6, t2, 1,  0,  0, 0, 0);   // p3
        PHASEP( 6, afY, afX, 1,   0, t2, 2,  0,  1, 1, 1);   // p4: vm+pub; postB(buf1)
        PHASEP( 0, afX, afY, 1,   2, t2, 3,  0,  0, 0, 0);   // p5
        PHASEP( 2, afY, afX, 1,   4, t3, 0,  1,  0, 0, 0);   // p6
        PHASEP( 4, afX, afY, 1,   6, t3, 1,  1,  0, 0, 0);   // p7
        PHASEP( 6, afY, afX, 0,   0, t3, 2,  1,  1, 1, 0);   // p8: vm+pub; postB(buf0)
    }

    // ---- epilogue: per-row {max, argmax col, sumexp} over this block's 256 cols ----
    // C layout (m89): col = cf*16 + cl (+ wn*64), row = f*16 + q*4 + reg (+ wm*128).
    // Remaining in-flight dummy loads target the tile buffers (<128KB); scratch is above.
    #pragma unroll
    for (int f = 0; f < 8; f++) {
        #pragma unroll
        for (int r = 0; r < 4; r++) {
            float v0 = acc[f][0][r], v1 = acc[f][1][r], v2 = acc[f][2][r], v3 = acc[f][3][r];
            float m = v0; int cj = 0;
            if (v1 > m) { m = v1; cj = 1; }
            if (v2 > m) { m = v2; cj = 2; }
            if (v3 > m) { m = v3; cj = 3; }
            float s = __expf(v0 - m) + __expf(v1 - m) + __expf(v2 - m) + __expf(v3 - m);
            int cidx = wn * 64 + cj * 16 + cl;
            #pragma unroll
            for (int off = 1; off < 16; off <<= 1) {
                float m2 = __shfl_xor(m, off);
                float s2 = __shfl_xor(s, off);
                int   c2 = __shfl_xor(cidx, off);
                float nm = fmaxf(m, m2);
                s = s * __expf(m - nm) + s2 * __expf(m2 - nm);
                if (m2 > m || (m2 == m && c2 < cidx)) cidx = c2;   // first-occurrence ties
                m = nm;
            }
            int rloc = wm * 128 + f * 16 + q * 4 + r;
            if (cl == 0) { redM[rloc*4+wn] = m; redS[rloc*4+wn] = s; redC[rloc*4+wn] = cidx; }
        }
    }
    asm volatile("s_waitcnt lgkmcnt(0)" ::: "memory");   // seal scratch writes (cross-wave)
    __builtin_amdgcn_s_barrier();
    asm volatile("" ::: "memory");
    if (tid < 256) {
        float m = redM[tid*4+0], s = redS[tid*4+0];
        int   cc = redC[tid*4+0];
        #pragma unroll
        for (int i2 = 1; i2 < 4; i2++) {
            float m2 = redM[tid*4+i2], s2 = redS[tid*4+i2];
            int   c2 = redC[tid*4+i2];
            float nm = fmaxf(m, m2);
            s = s * __expf(m - nm) + s2 * __expf(m2 - nm);
            if (m2 > m) cc = c2;                 // ascending col order; ties keep lower col
            m = nm;
        }
        pp[(size_t)(mb * 256 + tid) * NBLK2 + nb] =
            make_float4(m, s, __int_as_float(nb * 256 + cc), 0.f);
    }
}

// ---------------- fused row tail: policy argmax/lse + exact dot + ref lse + KL ----------------
__global__ __launch_bounds__(256) void row_tail_kernel(
    const float4* __restrict__ part, const float4* __restrict__ part2,
    const float* __restrict__ rx, const float* __restrict__ rw,
    float* __restrict__ klrow)
{
    __shared__ float smM[4], smS[4]; __shared__ int smC[4];
    __shared__ float ss[4];
    __shared__ float sTokLogp; __shared__ int sTok;

    const int row = blockIdx.x, t = threadIdx.x;

    // ---- policy: max / argmax / sumexp over 125 partials ----
    float m = -3.0e38f, s = 0.f; int cc = 0x7fffffff;
    if (t < NBLK2) { float4 p = part[(size_t)row * NBLK2 + t]; m = p.x; s = p.y; cc = __float_as_int(p.z); }
    for (int off = 1; off < 64; off <<= 1) {
        float m2 = __shfl_xor(m, off);
        float s2 = __shfl_xor(s, off);
        int   c2 = __shfl_xor(cc, off);
        float nm = fmaxf(m, m2);
        s = s * __expf(m - nm) + s2 * __expf(m2 - nm);
        if (m2 > m || (m2 == m && c2 < cc)) cc = c2;
        m = nm;
    }
    if ((t & 63) == 0) { smM[t>>6] = m; smS[t>>6] = s; smC[t>>6] = cc; }
    __syncthreads();
    if (t == 0) {
        m = smM[0]; s = smS[0]; cc = smC[0];
        for (int i = 1; i < 4; i++) {
            float m2 = smM[i], s2 = smS[i]; int c2 = smC[i];
            float nm = fmaxf(m, m2);
            s = s * __expf(m - nm) + s2 * __expf(m2 - nm);
            if (m2 > m || (m2 == m && c2 < cc)) cc = c2;
            m = nm;
        }
        sTok = cc;
        sTokLogp = -__logf(s);    // token is argmax -> logit[token] == global max
    }
    __syncthreads();
    const int tok = sTok;

    // ---- exact fp32 dot: rx[row] . rw[tok] ----
    const float4* a = (const float4*)(rx + (size_t)row * H_DIM);
    const float4* b = (const float4*)(rw + (size_t)tok * H_DIM);
    float4 a0 = a[t*2], a1 = a[t*2+1], b0 = b[t*2], b1 = b[t*2+1];
    float d = a0.x*b0.x + a0.y*b0.y + a0.z*b0.z + a0.w*b0.w
            + a1.x*b1.x + a1.y*b1.y + a1.z*b1.z + a1.w*b1.w;
    for (int off = 1; off < 64; off <<= 1) d += __shfl_xor(d, off);
    if ((t & 63) == 0) ss[t >> 6] = d;

    // ---- ref: lse over 125 partials ----
    float mr = -3.0e38f, sr = 0.f;
    if (t < NBLK2) { float4 p = part2[(size_t)row * NBLK2 + t]; mr = p.x; sr = p.y; }
    for (int off = 1; off < 64; off <<= 1) {
        float m2 = __shfl_xor(mr, off), s2 = __shfl_xor(sr, off);
        merge_ms(mr, sr, m2, s2);
    }
    __syncthreads();           // seals ss; frees smM/smS for reuse
    if ((t & 63) == 0) { smM[t>>6] = mr; smS[t>>6] = sr; }
    __syncthreads();
    if (t == 0) {
        mr = smM[0]; sr = smS[0];
        for (int i = 1; i < 4; i++) merge_ms(mr, sr, smM[i], smS[i]);
        float lse = mr + __logf(sr);
        float g = ss[0] + ss[1] + ss[2] + ss[3];
        float dd = (g - lse) - sTokLogp;   // ref_tok_logp - tok_logp
        klrow[row] = __expf(dd) - dd - 1.0f;
    }
}

// ---------------- fallback GEMM (round-1, in-kernel convert + gather) ----------------
__global__ __launch_bounds__(256) void gemm_lse_fallback(
    const float* __restrict__ A, const float* __restrict__ Bw,
    float4* __restrict__ part, const int* __restrict__ token,
    float* __restrict__ gather_out)
{
    __shared__ char smem[TM*TK*2 + TN*TK*2];
    ushort* sA = (ushort*)smem;
    ushort* sB = (ushort*)(smem + TM*TK*2);
    float* redM   = (float*)smem;
    float* redS   = (float*)(smem + 1024);
    int*   redC   = (int*)  (smem + 2048);
    int*   tokloc = (int*)  (smem + 3072);

    const int tid  = threadIdx.x;
    const int lane = tid & 63;
    const int wv   = tid >> 6;
    const int wm   = wv >> 1, wn = wv & 1;
    const int q    = lane >> 4, cl = lane & 15;
    const int m0 = blockIdx.x * TM;
    const int n0 = blockIdx.y * TN;
    const int nb = blockIdx.y;

    const int srow = tid >> 1, sseg = tid & 1;
    const float4* gA = (const float4*)(A  + (size_t)(m0 + srow) * H_DIM) + sseg * 4;
    const float4* gB = (const float4*)(Bw + (size_t)(n0 + srow) * H_DIM) + sseg * 4;
    uint4* wA = (uint4*)sA + srow * 4 + sseg * 2;
    uint4* wB = (uint4*)sB + srow * 4 + sseg * 2;

    f32x4 acc[4][4];
    const f32x4 zero = {0.f, 0.f, 0.f, 0.f};
    #pragma unroll
    for (int i = 0; i < 4; i++)
        #pragma unroll
        for (int j = 0; j < 4; j++) acc[i][j] = zero;

    float4 ra0 = gA[0], ra1 = gA[1], ra2 = gA[2], ra3 = gA[3];
    float4 rb0 = gB[0], rb1 = gB[1], rb2 = gB[2], rb3 = gB[3];

    for (int kt = 0; kt < H_DIM; kt += TK) {
        wA[0] = make_uint4(pack_bf16x2(ra0.x,ra0.y), pack_bf16x2(ra0.z,ra0.w),
                           pack_bf16x2(ra1.x,ra1.y), pack_bf16x2(ra1.z,ra1.w));
        wA[1] = make_uint4(pack_bf16x2(ra2.x,ra2.y), pack_bf16x2(ra2.z,ra2.w),
                           pack_bf16x2(ra3.x,ra3.y), pack_bf16x2(ra3.z,ra3.w));
        wB[0] = make_uint4(pack_bf16x2(rb0.x,rb0.y), pack_bf16x2(rb0.z,rb0.w),
                           pack_bf16x2(rb1.x,rb1.y), pack_bf16x2(rb1.z,rb1.w));
        wB[1] = make_uint4(pack_bf16x2(rb2.x,rb2.y), pack_bf16x2(rb2.z,rb2.w),
                           pack_bf16x2(rb3.x,rb3.y), pack_bf16x2(rb3.z,rb3.w));
        __syncthreads();
        if (kt + TK < H_DIM) {
            int kq = (kt + TK) >> 2;
            ra0 = gA[kq]; ra1 = gA[kq+1]; ra2 = gA[kq+2]; ra3 = gA[kq+3];
            rb0 = gB[kq]; rb1 = gB[kq+1]; rb2 = gB[kq+2]; rb3 = gB[kq+3];
        }
        bf16x8 af[4], bfr[4];
        #pragma unroll
        for (int i = 0; i < 4; i++) {
            af[i]  = *(const bf16x8*)(sA + (wm*64 + i*16 + cl) * TK + q*8);
            bfr[i] = *(const bf16x8*)(sB + (wn*64 + i*16 + cl) * TK + q*8);
        }
        #pragma unroll
        for (int i = 0; i < 4; i++)
            #pragma unroll
            for (int j = 0; j < 4; j++)
                acc[i][j] = __builtin_amdgcn_mfma_f32_16x16x32_bf16(af[i], bfr[j], acc[i][j], 0, 0, 0);
        __syncthreads();
    }

    #pragma unroll
    for (int ti = 0; ti < 4; ti++) {
        #pragma unroll
        for (int r = 0; r < 4; r++) {
            float vals[4];
            #pragma unroll
            for (int j = 0; j < 4; j++) vals[j] = acc[ti][j][r];
            float m = vals[0]; int cj = 0;
            #pragma unroll
            for (int j = 1; j < 4; j++) if (vals[j] > m) { m = vals[j]; cj = j; }
            float s = 0.f;
            #pragma unroll
            for (int j = 0; j < 4; j++) s += __expf(vals[j] - m);
            int cidx = wn*64 + cj*16 + cl;
            #pragma unroll
            for (int off = 1; off < 16; off <<= 1) {
                float m2 = __shfl_xor(m, off);
                float s2 = __shfl_xor(s, off);
                int   c2 = __shfl_xor(cidx, off);
                float nm = fmaxf(m, m2);
                s = s * __expf(m - nm) + s2 * __expf(m2 - nm);
                if (m2 > m || (m2 == m && c2 < cidx)) cidx = c2;
                m = nm;
            }
            int rloc = wm*64 + ti*16 + q*4 + r;
            if (cl == 0) { redM[rloc*2+wn] = m; redS[rloc*2+wn] = s; redC[rloc*2+wn] = cidx; }
        }
    }
    __syncthreads();
    if (tid < TM) {
        float ma = redM[tid*2+0], mb = redM[tid*2+1];
        float sa = redS[tid*2+0], sb = redS[tid*2+1];
        int   ca = redC[tid*2+0], cb = redC[tid*2+1];
        float nm = fmaxf(ma, mb);
        float s  = sa * __expf(ma - nm) + sb * __expf(mb - nm);
        int   cc = (mb > ma || (mb == ma && cb < ca)) ? cb : ca;
        part[(size_t)(m0 + tid) * NBLK_FB + nb] = make_float4(nm, s, __int_as_float(n0 + cc), 0.f);
    }

    if (token != nullptr) {
        if (tid < TM) tokloc[tid] = token[m0 + tid] - n0;
        __syncthreads();
        #pragma unroll
        for (int ti = 0; ti < 4; ti++) {
            #pragma unroll
            for (int r = 0; r < 4; r++) {
                int rloc = wm*64 + ti*16 + q*4 + r;
                int tl = tokloc[rloc];
                if (tl >= 0 && tl < TN && ((tl >> 6) & 1) == wn && (tl & 15) == cl) {
                    int tjm = (tl >> 4) & 3;
                    float v = acc[ti][0][r];
                    if (tjm == 1) v = acc[ti][1][r];
                    if (tjm == 2) v = acc[ti][2][r];
                    if (tjm == 3) v = acc[ti][3][r];
                    gather_out[m0 + rloc] = v;
                }
            }
        }
    }
}

// ---------------- fallback reductions ----------------

__global__ __launch_bounds__(256) void reduce_policy_kernel(
    const float4* __restrict__ part, int* __restrict__ token, float* __restrict__ tok_logp,
    int nblk)
{
    int row = blockIdx.x, t = threadIdx.x;
    float m = -3.0e38f, s = 0.f; int cc = 0x7fffffff;
    if (t < nblk) { float4 p = part[(size_t)row * nblk + t]; m = p.x; s = p.y; cc = __float_as_int(p.z); }
    for (int off = 1; off < 64; off <<= 1) {
        float m2 = __shfl_xor(m, off);
        float s2 = __shfl_xor(s, off);
        int   c2 = __shfl_xor(cc, off);
        float nm = fmaxf(m, m2);
        s = s * __expf(m - nm) + s2 * __expf(m2 - nm);
        if (m2 > m || (m2 == m && c2 < cc)) cc = c2;
        m = nm;
    }
    __shared__ float smM[4], smS[4]; __shared__ int smC[4];
    if ((t & 63) == 0) { smM[t>>6] = m; smS[t>>6] = s; smC[t>>6] = cc; }
    __syncthreads();
    if (t == 0) {
        m = smM[0]; s = smS[0]; cc = smC[0];
        for (int i = 1; i < 4; i++) {
            float m2 = smM[i], s2 = smS[i]; int c2 = smC[i];
            float nm = fmaxf(m, m2);
            s = s * __expf(m - nm) + s2 * __expf(m2 - nm);
            if (m2 > m || (m2 == m && c2 < cc)) cc = c2;
            m = nm;
        }
        token[row] = cc;
        tok_logp[row] = -__logf(s);
    }
}

__global__ __launch_bounds__(256) void dot_gather_kernel(
    const float* __restrict__ rx, const float* __restrict__ rw,
    const int* __restrict__ token, float* __restrict__ out)
{
    int row = blockIdx.x, t = threadIdx.x;
    const float4* a = (const float4*)(rx + (size_t)row * H_DIM);
    const float4* b = (const float4*)(rw + (size_t)token[row] * H_DIM);
    float4 a0 = a[t*2], a1 = a[t*2+1], b0 = b[t*2], b1 = b[t*2+1];
    float s = a0.x*b0.x + a0.y*b0.y + a0.z*b0.z + a0.w*b0.w
            + a1.x*b1.x + a1.y*b1.y + a1.z*b1.z + a1.w*b1.w;
    for (int off = 1; off < 64; off <<= 1) s += __shfl_xor(s, off);
    __shared__ float ss[4];
    if ((t & 63) == 0) ss[t >> 6] = s;
    __syncthreads();
    if (t == 0) out[row] = ss[0] + ss[1] + ss[2] + ss[3];
}

__global__ __launch_bounds__(256) void reduce_ref_kernel(
    const float4* __restrict__ part, const float* __restrict__ tok_logp,
    const float* __restrict__ gathered, float* __restrict__ klrow, int nblk)
{
    int row = blockIdx.x, t = threadIdx.x;
    float m = -3.0e38f, s = 0.f;
    if (t < nblk) { float4 p = part[(size_t)row * nblk + t]; m = p.x; s = p.y; }
    for (int off = 1; off < 64; off <<= 1) {
        float m2 = __shfl_xor(m, off), s2 = __shfl_xor(s, off);
        merge_ms(m, s, m2, s2);
    }
    __shared__ float smM[4], smS[4];
    if ((t & 63) == 0) { smM[t>>6] = m; smS[t>>6] = s; }
    __syncthreads();
    if (t == 0) {
        m = smM[0]; s = smS[0];
        for (int i = 1; i < 4; i++) merge_ms(m, s, smM[i], smS[i]);
        float lse = m + __logf(s);
        float d = (gathered[row] - lse) - tok_logp[row];
        klrow[row] = __expf(d) - d - 1.0f;
    }
}

__global__ __launch_bounds__(256) void final_kernel(
    const int* __restrict__ amask, const float* __restrict__ rewards,
    const float* __restrict__ klrow, float* __restrict__ out)
{
    int t = threadIdx.x;
    int b = t >> 5;
    int g = b >> 2;
    float r0 = rewards[g*4+0], r1 = rewards[g*4+1], r2 = rewards[g*4+2], r3 = rewards[g*4+3];
    float mean = 0.25f * (r0 + r1 + r2 + r3);
    float var = ((r0-mean)*(r0-mean) + (r1-mean)*(r1-mean) +
                 (r2-mean)*(r2-mean) + (r3-mean)*(r3-mean)) * (1.0f/3.0f);  // ddof=1
    float adv = (rewards[b] - mean) / (sqrtf(var) + EPSR);

    float ln = 0.f, ms = 0.f, kb = 0.f, mb = 0.f;
    for (int i = 0; i < 8; i++) {
        int row = t*8 + i;
        float mk = (float)amask[row];
        float kl = klrow[row];
        ln += (adv - BETA * kl) * mk;
        ms += mk;
        kb += kl * mk;
        mb += mk;
    }
    __shared__ float sLN[256], sMS[256], sKB[256], sMB[256], sKLb[8];
    sLN[t] = ln; sMS[t] = ms; sKB[t] = kb; sMB[t] = mb;
    __syncthreads();
    if (t < 8) {
        float skb = 0.f, smb = 0.f;
        for (int i = 0; i < 32; i++) { skb += sKB[t*32+i]; smb += sMB[t*32+i]; }
        sKLb[t] = skb / smb;
    }
    __syncthreads();
    if (t == 0) {
        float lnt = 0.f, mst = 0.f;
        for (int i = 0; i < 256; i++) { lnt += sLN[i]; mst += sMS[i]; }
        float mkl = 0.f;
        for (int i = 0; i < 8; i++) mkl += sKLb[i];
        out[0] = -lnt / mst;
        out[1] = mkl * 0.125f;
    }
}

// ---------------- launch ----------------

extern "C" void kernel_launch(void* const* d_in, const int* in_sizes, int n_in,
                              void* d_out, int out_size, void* d_ws, size_t ws_size,
                              hipStream_t stream)
{
    const float* x       = (const float*)d_in[0];
    const float* w       = (const float*)d_in[1];
    const int*   amask   = (const int*)  d_in[2];
    const float* rewards = (const float*)d_in[3];
    const float* rx      = (const float*)d_in[4];
    const float* rw      = (const float*)d_in[5];
    float* out = (float*)d_out;
    char* ws = (char*)d_ws;

    const size_t W_P  = (size_t)V_DIM * H_DIM * 2;   // 131,072,000 bf16 bytes (ONE buffer)
    const size_t A_P  = (size_t)BT * H_DIM * 2;      //   8,388,608
    const size_t PART = (size_t)BT * NBLK2 * 16;     //   4,096,000
    const size_t NEED = W_P + 2*A_P + 2*PART + 32768;   // 156 MB

    if (ws_size >= NEED) {
        // ---- fast path: shared weight slab buffer, packed twice (w, then rw after gemm1).
        // Stream order serializes pack_w(rw) behind gemm1, so no overwrite race.
        ushort* Wp   = (ushort*)(ws);                 // shared slab buffer (w, then rw)
        ushort* Ap   = (ushort*)(ws + W_P);
        ushort* Rp   = (ushort*)(ws + W_P + A_P);
        float4* part  = (float4*)(ws + W_P + 2*A_P);
        float4* part2 = (float4*)(ws + W_P + 2*A_P + PART);
        char*   tail  =          ws + W_P + 2*A_P + 2*PART;
        float* klrow    = (float*)(tail);

        pack_act_kernel<<<dim3(256),  512, 0, stream>>>(x, rx, (uint4*)Ap, (uint4*)Rp);
        pack_w_kernel  <<<dim3(2000), 512, 0, stream>>>(w, (uint4*)Wp);

        gemm_lse_v7<<<dim3(1000), 512, 0, stream>>>(Ap, Wp, part);    // policy

        pack_w_kernel  <<<dim3(2000), 512, 0, stream>>>(rw, (uint4*)Wp);

        gemm_lse_v7<<<dim3(1000), 512, 0, stream>>>(Rp, Wp, part2);   // reference

        row_tail_kernel<<<BT, 256, 0, stream>>>(part, part2, rx, rw, klrow);
        final_kernel<<<1, 256, 0, stream>>>(amask, rewards, klrow, out);
    } else {
        // ---- fallback: round-1 path (ws too small for packed weights) ----
        const size_t PART_FB = (size_t)BT * NBLK_FB * 16;
        float4* part     = (float4*)ws;
        int*    token    = (int*)  (ws + PART_FB);
        float*  tok_logp = (float*)(ws + PART_FB + 8192);
        float*  gathered = (float*)(ws + PART_FB + 16384);
        float*  klrow    = (float*)(ws + PART_FB + 24576);

        dim3 g(BT / TM, NBLK_FB), blk(256);
        gemm_lse_fallback<<<g, blk, 0, stream>>>(x, w, part, nullptr, nullptr);
        reduce_policy_kernel<<<BT, 256, 0, stream>>>(part, token, tok_logp, NBLK_FB);
        gemm_lse_fallback<<<g, blk, 0, stream>>>(rx, rw, part, token, gathered);
        reduce_ref_kernel<<<BT, 256, 0, stream>>>(part, tok_logp, gathered, klrow, NBLK_FB);
        final_kernel<<<1, 256, 0, stream>>>(amask, rewards, klrow, out);
    }
}